// Round 1
// baseline (1764.619 us; speedup 1.0000x reference)
//
#include <hip/hip_runtime.h>
#include <math.h>

// Problem constants
#define SEQ   2048
#define NROWS 8192   // B*N
#define NHEAD 8

// Workspace offsets (in floats)
#define OFF_CAT   0ull            // 8192*768  (reused as AO after h)
#define OFF_TE1   6291456ull      // 8192*64
#define OFF_H     6815744ull      // 8192*512  (reused as OUT after qkv)
#define OFF_QF    11010048ull     // 8192*520
#define OFF_QN    15269888ull     // 8192*512
#define OFF_K     19464192ull     // 8192*512
#define OFF_V     23658496ull     // 8192*512
#define OFF_TDT   27852800ull     // 512
#define OFF_AO    OFF_CAT
#define OFF_OUT   OFF_H

// d_out offsets (floats): (expr_out, pos_out, tdt) flat
#define DOUT_EXPR 0ull
#define DOUT_POS  4194304ull
#define DOUT_TDT  4218880ull

// ---------------------------------------------------------------------------
// Generic fp32 GEMM: C[M x N] = A[M x K] @ W[K x N] + bias (optional relu)
// BM=128, BN=128, BK=16, 256 threads, 8x8 microtile, transposed-A LDS.
// Requires: M % 128 == 0, K % 16 == 0, N % 4 == 0 (N may be < 128*gridDim.x).
// ---------------------------------------------------------------------------
template <int RELU>
__global__ __launch_bounds__(256) void sgemm128(
    const float* __restrict__ A, int lda,
    const float* __restrict__ W, int ldw,
    const float* __restrict__ bias,
    float* __restrict__ C, int ldc,
    int N, int K)
{
    __shared__ __align__(16) float As[16][128];  // As[k][m] (transposed)
    __shared__ __align__(16) float Bs[16][128];  // Bs[k][n]

    const int tid = threadIdx.x;
    const int tx = tid & 15, ty = tid >> 4;
    const long m0 = (long)blockIdx.y * 128;
    const int n0 = blockIdx.x * 128;

    float acc[8][8];
#pragma unroll
    for (int i = 0; i < 8; ++i)
#pragma unroll
        for (int j = 0; j < 8; ++j) acc[i][j] = 0.f;

    const int am = tid >> 1;          // 0..127 row within tile
    const int ak = (tid & 1) * 8;     // 0 or 8
    const int bk = tid >> 4;          // 0..15
    const int bn = (tid & 15) * 8;    // 0..120
    const int bcol = n0 + bn;

    for (int k0 = 0; k0 < K; k0 += 16) {
        const float* ap = &A[(m0 + am) * (long)lda + k0 + ak];
        float4 a0 = *(const float4*)ap;
        float4 a1 = *(const float4*)(ap + 4);
        As[ak + 0][am] = a0.x; As[ak + 1][am] = a0.y;
        As[ak + 2][am] = a0.z; As[ak + 3][am] = a0.w;
        As[ak + 4][am] = a1.x; As[ak + 5][am] = a1.y;
        As[ak + 6][am] = a1.z; As[ak + 7][am] = a1.w;

        if (bcol + 8 <= N) {
            const float* wp = &W[(long)(k0 + bk) * ldw + bcol];
            *(float4*)&Bs[bk][bn]     = *(const float4*)wp;
            *(float4*)&Bs[bk][bn + 4] = *(const float4*)(wp + 4);
        } else {
#pragma unroll
            for (int e = 0; e < 8; ++e)
                Bs[bk][bn + e] = (bcol + e < N) ? W[(long)(k0 + bk) * ldw + bcol + e] : 0.f;
        }
        __syncthreads();

#pragma unroll
        for (int kk = 0; kk < 16; ++kk) {
            float a[8], b[8];
            *(float4*)&a[0] = *(const float4*)&As[kk][ty * 8];
            *(float4*)&a[4] = *(const float4*)&As[kk][ty * 8 + 4];
            *(float4*)&b[0] = *(const float4*)&Bs[kk][tx * 8];
            *(float4*)&b[4] = *(const float4*)&Bs[kk][tx * 8 + 4];
#pragma unroll
            for (int i = 0; i < 8; ++i)
#pragma unroll
                for (int j = 0; j < 8; ++j)
                    acc[i][j] = fmaf(a[i], b[j], acc[i][j]);
        }
        __syncthreads();
    }

#pragma unroll
    for (int i = 0; i < 8; ++i) {
        long row = m0 + ty * 8 + i;
#pragma unroll
        for (int j4 = 0; j4 < 2; ++j4) {
            int col = n0 + tx * 8 + j4 * 4;
            if (col < N) {
                float4 v;
                v.x = acc[i][j4 * 4 + 0] + bias[col + 0];
                v.y = acc[i][j4 * 4 + 1] + bias[col + 1];
                v.z = acc[i][j4 * 4 + 2] + bias[col + 2];
                v.w = acc[i][j4 * 4 + 3] + bias[col + 3];
                if (RELU) {
                    v.x = fmaxf(v.x, 0.f); v.y = fmaxf(v.y, 0.f);
                    v.z = fmaxf(v.z, 0.f); v.w = fmaxf(v.w, 0.f);
                }
                *(float4*)&C[row * (long)ldc + col] = v;
            }
        }
    }
}

// ---------------------------------------------------------------------------
// Position MLP: pfeat=[dir,nrm] (4) -> relu(@pos_w1+b1) (64) -> @pos_w2+b2 (128)
// writes into cat[:, 640:768]. One thread per row, weights staged in LDS.
// ---------------------------------------------------------------------------
__global__ __launch_bounds__(128) void posmlp_kernel(
    const float* __restrict__ pos,
    const float* __restrict__ w1, const float* __restrict__ b1,
    const float* __restrict__ w2, const float* __restrict__ b2,
    float* __restrict__ cat)
{
    __shared__ __align__(16) float w1s[256];
    __shared__ __align__(16) float b1s[64];
    __shared__ __align__(16) float w2t[128 * 64];  // [o][i] transposed
    __shared__ __align__(16) float b2s[128];

    const int tid = threadIdx.x;
    for (int i = tid; i < 256; i += 128) w1s[i] = w1[i];
    if (tid < 64) b1s[tid] = b1[tid];
    b2s[tid] = b2[tid];
    for (int i = tid; i < 8192; i += 128) {
        int k = i >> 7, o = i & 127;
        w2t[o * 64 + k] = w2[i];
    }
    __syncthreads();

    const long r = (long)blockIdx.x * 128 + tid;
    float px = pos[r * 3 + 0], py = pos[r * 3 + 1], pz = pos[r * 3 + 2];
    float nrm = sqrtf(px * px + py * py + pz * pz);
    float inv = 1.f / (nrm + 1e-7f);
    float pf0 = px * inv, pf1 = py * inv, pf2 = pz * inv, pf3 = nrm;

    float h1[64];
#pragma unroll
    for (int o = 0; o < 64; ++o) {
        float a = b1s[o];
        a = fmaf(pf0, w1s[o], a);
        a = fmaf(pf1, w1s[64 + o], a);
        a = fmaf(pf2, w1s[128 + o], a);
        a = fmaf(pf3, w1s[192 + o], a);
        h1[o] = fmaxf(a, 0.f);
    }
    float* dst = &cat[r * 768 + 640];
    for (int o = 0; o < 128; ++o) {
        float s = b2s[o];
#pragma unroll
        for (int i4 = 0; i4 < 16; ++i4) {
            float4 wv = *(const float4*)&w2t[o * 64 + i4 * 4];
            s = fmaf(h1[i4 * 4 + 0], wv.x, s);
            s = fmaf(h1[i4 * 4 + 1], wv.y, s);
            s = fmaf(h1[i4 * 4 + 2], wv.z, s);
            s = fmaf(h1[i4 * 4 + 3], wv.w, s);
        }
        dst[o] = s;
    }
}

// tdt = diffusion_time @ yy_w + yy_b  (4x128 @ 128x128); writes ws + d_out tail
__global__ __launch_bounds__(512) void tdt_kernel(
    const float* __restrict__ dt, const float* __restrict__ yyw,
    const float* __restrict__ yyb, float* __restrict__ tdt_ws,
    float* __restrict__ out_tail)
{
    const int t = threadIdx.x;       // 512 threads
    const int b = t >> 7, o = t & 127;
    float s = yyb[o];
    for (int k = 0; k < 128; ++k) s = fmaf(dt[b * 128 + k], yyw[k * 128 + o], s);
    tdt_ws[t] = s;
    out_tail[t] = s;
}

// cat[:, 512:640] = tdt[b] broadcast
__global__ __launch_bounds__(256) void cattime_kernel(
    const float* __restrict__ tdt, float* __restrict__ cat)
{
    const long idx = (long)blockIdx.x * 256 + threadIdx.x;  // < 8192*128
    const long r = idx >> 7;
    const int c = (int)(idx & 127);
    const int b = (int)(r >> 11);
    cat[r * 768 + 512 + c] = tdt[b * 128 + c];
}

// Per-(row, head) rmsnorm over HD=64. One wave per (row,h). scale folds 1/sqrt(HD).
__global__ __launch_bounds__(256) void rms_kernel(
    const float* __restrict__ in, int ldi,
    float* __restrict__ out, int ldo,
    const float* __restrict__ w, float scale)
{
    const int lane = threadIdx.x & 63;
    const int p = blockIdx.x * 4 + (threadIdx.x >> 6);  // (row,h) pair id
    const long row = p >> 3;
    const int h = p & 7;
    float x = in[row * (long)ldi + h * 64 + lane];
    float ss = x * x;
#pragma unroll
    for (int o = 32; o >= 1; o >>= 1) ss += __shfl_xor(ss, o);
    float r = rsqrtf(ss * (1.f / 64.f) + 1e-6f);
    out[row * (long)ldo + h * 64 + lane] = w[lane] * x * r * scale;
}

// ---------------------------------------------------------------------------
// Flash attention (fp32, exact online softmax) + gate-sigmoid epilogue.
// grid (B*H, SEQ/256), block 256. Thread owns 4 query rows x 16 dims (quarter).
// Score completed across the 4 dim-quarters with 2 quad-perm shuffles.
// Q is pre-scaled by 1/8 in rms_kernel.
// ---------------------------------------------------------------------------
__global__ __launch_bounds__(256) void flash_attn(
    const float* __restrict__ Qn, const float* __restrict__ Kn,
    const float* __restrict__ V, const float* __restrict__ QF,
    float* __restrict__ AO)
{
    __shared__ __align__(16) float Ks[64 * 64];
    __shared__ __align__(16) float Vs[64 * 64];

    const int tid = threadIdx.x;
    const int b = blockIdx.x >> 3, h = blockIdx.x & 7;
    const int quad = tid & 3;           // dim quarter
    const int rg = tid >> 2;            // row group 0..63
    const int row0 = blockIdx.y * 256 + rg * 4;
    const int d0 = quad * 16;

    float q[4][16], O[4][16];
    float m[4], l[4];
#pragma unroll
    for (int r = 0; r < 4; ++r) {
        const float* qp = &Qn[((long)(b * SEQ + row0 + r)) * 512 + h * 64 + d0];
#pragma unroll
        for (int d4 = 0; d4 < 4; ++d4) {
            float4 t = *(const float4*)(qp + d4 * 4);
            q[r][d4 * 4 + 0] = t.x; q[r][d4 * 4 + 1] = t.y;
            q[r][d4 * 4 + 2] = t.z; q[r][d4 * 4 + 3] = t.w;
            O[r][d4 * 4 + 0] = 0.f; O[r][d4 * 4 + 1] = 0.f;
            O[r][d4 * 4 + 2] = 0.f; O[r][d4 * 4 + 3] = 0.f;
        }
        m[r] = -INFINITY;
        l[r] = 0.f;
    }

    const int lrow = tid >> 2;          // staging: 0..63
    const int lcol = (tid & 3) * 16;

    for (int kt = 0; kt < 32; ++kt) {
        const long src = ((long)(b * SEQ + kt * 64 + lrow)) * 512 + h * 64 + lcol;
#pragma unroll
        for (int j = 0; j < 4; ++j) {
            *(float4*)&Ks[lrow * 64 + lcol + j * 4] = *(const float4*)&Kn[src + j * 4];
            *(float4*)&Vs[lrow * 64 + lcol + j * 4] = *(const float4*)&V[src + j * 4];
        }
        __syncthreads();

        for (int jj = 0; jj < 64; ++jj) {
            float kf[16], vf[16];
#pragma unroll
            for (int d4 = 0; d4 < 4; ++d4) {
                float4 t = *(const float4*)&Ks[jj * 64 + d0 + d4 * 4];
                kf[d4 * 4 + 0] = t.x; kf[d4 * 4 + 1] = t.y;
                kf[d4 * 4 + 2] = t.z; kf[d4 * 4 + 3] = t.w;
            }
            float s[4];
#pragma unroll
            for (int r = 0; r < 4; ++r) {
                float acc = 0.f;
#pragma unroll
                for (int d = 0; d < 16; ++d) acc = fmaf(q[r][d], kf[d], acc);
                s[r] = acc;
            }
#pragma unroll
            for (int r = 0; r < 4; ++r) {
                s[r] += __shfl_xor(s[r], 1);
                s[r] += __shfl_xor(s[r], 2);
            }
#pragma unroll
            for (int d4 = 0; d4 < 4; ++d4) {
                float4 t = *(const float4*)&Vs[jj * 64 + d0 + d4 * 4];
                vf[d4 * 4 + 0] = t.x; vf[d4 * 4 + 1] = t.y;
                vf[d4 * 4 + 2] = t.z; vf[d4 * 4 + 3] = t.w;
            }
#pragma unroll
            for (int r = 0; r < 4; ++r) {
                if (s[r] <= m[r]) {
                    float p = __expf(s[r] - m[r]);
                    l[r] += p;
#pragma unroll
                    for (int d = 0; d < 16; ++d) O[r][d] = fmaf(p, vf[d], O[r][d]);
                } else {
                    float corr = __expf(m[r] - s[r]);
                    m[r] = s[r];
                    l[r] = fmaf(l[r], corr, 1.f);
#pragma unroll
                    for (int d = 0; d < 16; ++d) O[r][d] = fmaf(O[r][d], corr, vf[d]);
                }
            }
        }
        __syncthreads();
    }

#pragma unroll
    for (int r = 0; r < 4; ++r) {
        const long grow = (long)(b * SEQ + row0 + r);
        float g = QF[grow * 520 + 512 + h];
        g = 1.f / (1.f + __expf(-g));
        float sc = g / l[r];
        float* ao = &AO[grow * 512 + h * 64 + d0];
#pragma unroll
        for (int d4 = 0; d4 < 4; ++d4) {
            float4 o;
            o.x = O[r][d4 * 4 + 0] * sc; o.y = O[r][d4 * 4 + 1] * sc;
            o.z = O[r][d4 * 4 + 2] * sc; o.w = O[r][d4 * 4 + 3] * sc;
            *(float4*)(ao + d4 * 4) = o;
        }
    }
}

// pos_out = out @ hp_w + hp_b  (8192x512 @ 512x3). One wave per row.
__global__ __launch_bounds__(256) void posout_kernel(
    const float* __restrict__ outb, const float* __restrict__ hpw,
    const float* __restrict__ hpb, float* __restrict__ po)
{
    const int lane = threadIdx.x & 63;
    const long row = (long)blockIdx.x * 4 + (threadIdx.x >> 6);
    float p0 = 0.f, p1 = 0.f, p2 = 0.f;
#pragma unroll
    for (int it = 0; it < 8; ++it) {
        int k = it * 64 + lane;
        float x = outb[row * 512 + k];
        p0 = fmaf(x, hpw[k * 3 + 0], p0);
        p1 = fmaf(x, hpw[k * 3 + 1], p1);
        p2 = fmaf(x, hpw[k * 3 + 2], p2);
    }
#pragma unroll
    for (int o = 32; o >= 1; o >>= 1) {
        p0 += __shfl_xor(p0, o);
        p1 += __shfl_xor(p1, o);
        p2 += __shfl_xor(p2, o);
    }
    if (lane == 0) {
        po[row * 3 + 0] = p0 + hpb[0];
        po[row * 3 + 1] = p1 + hpb[1];
        po[row * 3 + 2] = p2 + hpb[2];
    }
}

// ---------------------------------------------------------------------------
extern "C" void kernel_launch(void* const* d_in, const int* in_sizes, int n_in,
                              void* d_out, int out_size, void* d_ws, size_t ws_size,
                              hipStream_t stream)
{
    const float* expr    = (const float*)d_in[0];
    const float* dtime   = (const float*)d_in[1];
    const float* posf    = (const float*)d_in[2];
    const float* pos_w1  = (const float*)d_in[3];
    const float* pos_b1  = (const float*)d_in[4];
    const float* pos_w2  = (const float*)d_in[5];
    const float* pos_b2  = (const float*)d_in[6];
    const float* expr_w1 = (const float*)d_in[7];
    const float* expr_b1 = (const float*)d_in[8];
    const float* expr_w2 = (const float*)d_in[9];
    const float* expr_b2 = (const float*)d_in[10];
    const float* yy_w    = (const float*)d_in[11];
    const float* yy_b    = (const float*)d_in[12];
    const float* cat_w   = (const float*)d_in[13];
    const float* cat_b   = (const float*)d_in[14];
    const float* q_w     = (const float*)d_in[15];
    const float* q_b     = (const float*)d_in[16];
    const float* k_w     = (const float*)d_in[17];
    const float* k_b     = (const float*)d_in[18];
    const float* v_w     = (const float*)d_in[19];
    const float* v_b     = (const float*)d_in[20];
    const float* o_w     = (const float*)d_in[21];
    const float* o_b     = (const float*)d_in[22];
    const float* qn_w    = (const float*)d_in[23];
    const float* kn_w    = (const float*)d_in[24];
    const float* hp_w    = (const float*)d_in[25];
    const float* hp_b    = (const float*)d_in[26];
    const float* he_w    = (const float*)d_in[27];
    const float* he_b    = (const float*)d_in[28];
    (void)in_sizes; (void)n_in; (void)out_size; (void)ws_size;

    float* ws   = (float*)d_ws;
    float* cat  = ws + OFF_CAT;
    float* te1  = ws + OFF_TE1;
    float* hbuf = ws + OFF_H;
    float* qf   = ws + OFF_QF;
    float* qn   = ws + OFF_QN;
    float* kbuf = ws + OFF_K;
    float* vbuf = ws + OFF_V;
    float* tdt  = ws + OFF_TDT;
    float* ao   = ws + OFF_AO;
    float* outb = ws + OFF_OUT;
    float* dout = (float*)d_out;

    const dim3 blk(256);

    // 1. te1 = relu(expr @ expr_w1 + b1)        [8192x512 @ 512x64]
    sgemm128<1><<<dim3(1, 64), blk, 0, stream>>>(expr, 512, expr_w1, 64, expr_b1,
                                                 te1, 64, 64, 512);
    // 2. cat[:, :512] = te1 @ expr_w2 + b2      [8192x64 @ 64x512]
    sgemm128<0><<<dim3(4, 64), blk, 0, stream>>>(te1, 64, expr_w2, 512, expr_b2,
                                                 cat, 768, 512, 64);
    // 3. pos MLP -> cat[:, 640:768]
    posmlp_kernel<<<dim3(64), dim3(128), 0, stream>>>(posf, pos_w1, pos_b1,
                                                      pos_w2, pos_b2, cat);
    // 4. tdt (also d_out tail)
    tdt_kernel<<<dim3(1), dim3(512), 0, stream>>>(dtime, yy_w, yy_b, tdt,
                                                  dout + DOUT_TDT);
    // 5. cat[:, 512:640] = tdt broadcast
    cattime_kernel<<<dim3(4096), blk, 0, stream>>>(tdt, cat);
    // 6. h = cat @ cat_w + cat_b                [8192x768 @ 768x512]
    sgemm128<0><<<dim3(4, 64), blk, 0, stream>>>(cat, 768, cat_w, 512, cat_b,
                                                 hbuf, 512, 512, 768);
    // 7. qfull = h @ q_w + q_b                  [8192x512 @ 512x520]
    sgemm128<0><<<dim3(5, 64), blk, 0, stream>>>(hbuf, 512, q_w, 520, q_b,
                                                 qf, 520, 520, 512);
    // 8. k = h @ k_w + k_b
    sgemm128<0><<<dim3(4, 64), blk, 0, stream>>>(hbuf, 512, k_w, 512, k_b,
                                                 kbuf, 512, 512, 512);
    // 9. v = h @ v_w + v_b
    sgemm128<0><<<dim3(4, 64), blk, 0, stream>>>(hbuf, 512, v_w, 512, v_b,
                                                 vbuf, 512, 512, 512);
    // 10. Q rmsnorm (+ fold 1/sqrt(64) score scale), qfull(520) -> qn(512)
    rms_kernel<<<dim3(16384), blk, 0, stream>>>(qf, 520, qn, 512, qn_w, 0.125f);
    // 11. K rmsnorm in-place
    rms_kernel<<<dim3(16384), blk, 0, stream>>>(kbuf, 512, kbuf, 512, kn_w, 1.0f);
    // 12. flash attention + gate; ao reuses cat slot
    flash_attn<<<dim3(32, 8), blk, 0, stream>>>(qn, kbuf, vbuf, qf, ao);
    // 13. out = ao @ o_w + o_b; outb reuses h slot
    sgemm128<0><<<dim3(4, 64), blk, 0, stream>>>(ao, 512, o_w, 512, o_b,
                                                 outb, 512, 512, 512);
    // 14. expr_out = out @ he_w + he_b -> d_out
    sgemm128<0><<<dim3(4, 64), blk, 0, stream>>>(outb, 512, he_w, 512, he_b,
                                                 dout + DOUT_EXPR, 512, 512, 512);
    // 15. pos_out = out @ hp_w + hp_b -> d_out
    posout_kernel<<<dim3(2048), blk, 0, stream>>>(outb, hp_w, hp_b,
                                                  dout + DOUT_POS);
}

// Round 2
// 818.694 us; speedup vs baseline: 2.1554x; 2.1554x over previous
//
#include <hip/hip_runtime.h>
#include <math.h>

// Problem constants
#define SEQ   2048
#define NROWS 8192   // B*N
#define NHEAD 8

typedef unsigned short ushort_t;
typedef __attribute__((ext_vector_type(8))) short bf16x8;
typedef __attribute__((ext_vector_type(4))) float f32x4;

// Workspace offsets (in floats)
#define OFF_CAT   0ull            // 8192*768  (first 512 cols reused as AO; last 256 cols hold Vt bf16)
#define OFF_TE1   6291456ull      // 8192*64
#define OFF_H     6815744ull      // 8192*512  (reused as OUT after qkv)
#define OFF_QF    11010048ull     // 8192*520
#define OFF_QN    15269888ull     // bf16 Qn (2097152 floats) + bf16 Kn (2097152 floats)
#define OFF_K     19464192ull     // 8192*512 fp32 K (pre-rms)
#define OFF_V     23658496ull     // 8192*512 fp32 V
#define OFF_TDT   27852800ull     // 512
#define OFF_AO    OFF_CAT
#define OFF_VT    (OFF_CAT + 4194304ull)   // bf16 Vt [32][64][2048] = 4194304 ushorts
#define OFF_OUT   OFF_H

// d_out offsets (floats): (expr_out, pos_out, tdt) flat
#define DOUT_EXPR 0ull
#define DOUT_POS  4194304ull
#define DOUT_TDT  4218880ull

static __device__ __forceinline__ ushort_t f2bf(float f) {
    union { float f; unsigned int u; } v; v.f = f;
    unsigned int r = (v.u + 0x7fffu + ((v.u >> 16) & 1u)) >> 16;
    return (ushort_t)r;
}

// ---------------------------------------------------------------------------
// Generic fp32 GEMM: C[M x N] = A[M x K] @ W[K x N] + bias (optional relu)
// ---------------------------------------------------------------------------
template <int RELU>
__global__ __launch_bounds__(256) void sgemm128(
    const float* __restrict__ A, int lda,
    const float* __restrict__ W, int ldw,
    const float* __restrict__ bias,
    float* __restrict__ C, int ldc,
    int N, int K)
{
    __shared__ __align__(16) float As[16][128];  // As[k][m] (transposed)
    __shared__ __align__(16) float Bs[16][128];  // Bs[k][n]

    const int tid = threadIdx.x;
    const int tx = tid & 15, ty = tid >> 4;
    const long m0 = (long)blockIdx.y * 128;
    const int n0 = blockIdx.x * 128;

    float acc[8][8];
#pragma unroll
    for (int i = 0; i < 8; ++i)
#pragma unroll
        for (int j = 0; j < 8; ++j) acc[i][j] = 0.f;

    const int am = tid >> 1;
    const int ak = (tid & 1) * 8;
    const int bk = tid >> 4;
    const int bn = (tid & 15) * 8;
    const int bcol = n0 + bn;

    for (int k0 = 0; k0 < K; k0 += 16) {
        const float* ap = &A[(m0 + am) * (long)lda + k0 + ak];
        float4 a0 = *(const float4*)ap;
        float4 a1 = *(const float4*)(ap + 4);
        As[ak + 0][am] = a0.x; As[ak + 1][am] = a0.y;
        As[ak + 2][am] = a0.z; As[ak + 3][am] = a0.w;
        As[ak + 4][am] = a1.x; As[ak + 5][am] = a1.y;
        As[ak + 6][am] = a1.z; As[ak + 7][am] = a1.w;

        if (bcol + 8 <= N) {
            const float* wp = &W[(long)(k0 + bk) * ldw + bcol];
            *(float4*)&Bs[bk][bn]     = *(const float4*)wp;
            *(float4*)&Bs[bk][bn + 4] = *(const float4*)(wp + 4);
        } else {
#pragma unroll
            for (int e = 0; e < 8; ++e)
                Bs[bk][bn + e] = (bcol + e < N) ? W[(long)(k0 + bk) * ldw + bcol + e] : 0.f;
        }
        __syncthreads();

#pragma unroll
        for (int kk = 0; kk < 16; ++kk) {
            float a[8], b[8];
            *(float4*)&a[0] = *(const float4*)&As[kk][ty * 8];
            *(float4*)&a[4] = *(const float4*)&As[kk][ty * 8 + 4];
            *(float4*)&b[0] = *(const float4*)&Bs[kk][tx * 8];
            *(float4*)&b[4] = *(const float4*)&Bs[kk][tx * 8 + 4];
#pragma unroll
            for (int i = 0; i < 8; ++i)
#pragma unroll
                for (int j = 0; j < 8; ++j)
                    acc[i][j] = fmaf(a[i], b[j], acc[i][j]);
        }
        __syncthreads();
    }

#pragma unroll
    for (int i = 0; i < 8; ++i) {
        long row = m0 + ty * 8 + i;
#pragma unroll
        for (int j4 = 0; j4 < 2; ++j4) {
            int col = n0 + tx * 8 + j4 * 4;
            if (col < N) {
                float4 v;
                v.x = acc[i][j4 * 4 + 0] + bias[col + 0];
                v.y = acc[i][j4 * 4 + 1] + bias[col + 1];
                v.z = acc[i][j4 * 4 + 2] + bias[col + 2];
                v.w = acc[i][j4 * 4 + 3] + bias[col + 3];
                if (RELU) {
                    v.x = fmaxf(v.x, 0.f); v.y = fmaxf(v.y, 0.f);
                    v.z = fmaxf(v.z, 0.f); v.w = fmaxf(v.w, 0.f);
                }
                *(float4*)&C[row * (long)ldc + col] = v;
            }
        }
    }
}

// ---------------------------------------------------------------------------
// Position MLP -> cat[:, 640:768]
// ---------------------------------------------------------------------------
__global__ __launch_bounds__(128) void posmlp_kernel(
    const float* __restrict__ pos,
    const float* __restrict__ w1, const float* __restrict__ b1,
    const float* __restrict__ w2, const float* __restrict__ b2,
    float* __restrict__ cat)
{
    __shared__ __align__(16) float w1s[256];
    __shared__ __align__(16) float b1s[64];
    __shared__ __align__(16) float w2t[128 * 64];
    __shared__ __align__(16) float b2s[128];

    const int tid = threadIdx.x;
    for (int i = tid; i < 256; i += 128) w1s[i] = w1[i];
    if (tid < 64) b1s[tid] = b1[tid];
    b2s[tid] = b2[tid];
    for (int i = tid; i < 8192; i += 128) {
        int k = i >> 7, o = i & 127;
        w2t[o * 64 + k] = w2[i];
    }
    __syncthreads();

    const long r = (long)blockIdx.x * 128 + tid;
    float px = pos[r * 3 + 0], py = pos[r * 3 + 1], pz = pos[r * 3 + 2];
    float nrm = sqrtf(px * px + py * py + pz * pz);
    float inv = 1.f / (nrm + 1e-7f);
    float pf0 = px * inv, pf1 = py * inv, pf2 = pz * inv, pf3 = nrm;

    float h1[64];
#pragma unroll
    for (int o = 0; o < 64; ++o) {
        float a = b1s[o];
        a = fmaf(pf0, w1s[o], a);
        a = fmaf(pf1, w1s[64 + o], a);
        a = fmaf(pf2, w1s[128 + o], a);
        a = fmaf(pf3, w1s[192 + o], a);
        h1[o] = fmaxf(a, 0.f);
    }
    float* dst = &cat[r * 768 + 640];
    for (int o = 0; o < 128; ++o) {
        float s = b2s[o];
#pragma unroll
        for (int i4 = 0; i4 < 16; ++i4) {
            float4 wv = *(const float4*)&w2t[o * 64 + i4 * 4];
            s = fmaf(h1[i4 * 4 + 0], wv.x, s);
            s = fmaf(h1[i4 * 4 + 1], wv.y, s);
            s = fmaf(h1[i4 * 4 + 2], wv.z, s);
            s = fmaf(h1[i4 * 4 + 3], wv.w, s);
        }
        dst[o] = s;
    }
}

// tdt = diffusion_time @ yy_w + yy_b
__global__ __launch_bounds__(512) void tdt_kernel(
    const float* __restrict__ dt, const float* __restrict__ yyw,
    const float* __restrict__ yyb, float* __restrict__ tdt_ws,
    float* __restrict__ out_tail)
{
    const int t = threadIdx.x;
    const int b = t >> 7, o = t & 127;
    float s = yyb[o];
    for (int k = 0; k < 128; ++k) s = fmaf(dt[b * 128 + k], yyw[k * 128 + o], s);
    tdt_ws[t] = s;
    out_tail[t] = s;
}

// cat[:, 512:640] = tdt[b]
__global__ __launch_bounds__(256) void cattime_kernel(
    const float* __restrict__ tdt, float* __restrict__ cat)
{
    const long idx = (long)blockIdx.x * 256 + threadIdx.x;
    const long r = idx >> 7;
    const int c = (int)(idx & 127);
    const int b = (int)(r >> 11);
    cat[r * 768 + 512 + c] = tdt[b * 128 + c];
}

// Per-(row, head) rmsnorm over HD=64, bf16 output (stride 512). scale folds 1/8.
__global__ __launch_bounds__(256) void rms_bf16_kernel(
    const float* __restrict__ in, int ldi,
    ushort_t* __restrict__ out,
    const float* __restrict__ w, float scale)
{
    const int lane = threadIdx.x & 63;
    const int p = blockIdx.x * 4 + (threadIdx.x >> 6);
    const long row = p >> 3;
    const int h = p & 7;
    float x = in[row * (long)ldi + h * 64 + lane];
    float ss = x * x;
#pragma unroll
    for (int o = 32; o >= 1; o >>= 1) ss += __shfl_xor(ss, o);
    float r = rsqrtf(ss * (1.f / 64.f) + 1e-6f);
    out[row * 512 + h * 64 + lane] = f2bf(w[lane] * x * r * scale);
}

// Vt[bh][d][n] = bf16(V[b*2048+n][h*64+d]); grid (32, 32), block 256
__global__ __launch_bounds__(256) void vt_kernel(
    const float* __restrict__ V, ushort_t* __restrict__ Vt)
{
    __shared__ float t[64][65];
    const int bh = blockIdx.x, b = bh >> 3, h = bh & 7;
    const int n0 = blockIdx.y * 64;
    const int tid = threadIdx.x;
    const int c4 = tid & 15, r = tid >> 4;
#pragma unroll
    for (int i = 0; i < 4; ++i) {
        int rr = r + i * 16;
        float4 v = *(const float4*)&V[(long)(b * SEQ + n0 + rr) * 512 + h * 64 + c4 * 4];
        t[rr][c4 * 4 + 0] = v.x; t[rr][c4 * 4 + 1] = v.y;
        t[rr][c4 * 4 + 2] = v.z; t[rr][c4 * 4 + 3] = v.w;
    }
    __syncthreads();
    const int d = tid >> 2, ch = tid & 3;
#pragma unroll
    for (int i = 0; i < 2; ++i) {
        int cc = ch + i * 4;   // 8-elem chunk of n
        bf16x8 pk;
#pragma unroll
        for (int j = 0; j < 8; ++j) pk[j] = (short)f2bf(t[cc * 8 + j][d]);
        *(bf16x8*)&Vt[((long)(bh * 64 + d)) * SEQ + n0 + cc * 8] = pk;
    }
}

// ---------------------------------------------------------------------------
// Flash attention, bf16 MFMA 16x16x32, online softmax, gate-sigmoid epilogue.
// grid (32 bh, 16), block 256 (4 waves x 32 q-rows). K-tile 64.
// Layouts (m89/m91-verified): A: m=lane&15, k=(lane>>4)*8+j ; B: n=lane&15 ;
// C/D: col=lane&15, row=(lane>>4)*4+reg.
// ---------------------------------------------------------------------------
__global__ __launch_bounds__(256) void flash_attn_mfma(
    const ushort_t* __restrict__ Qn, const ushort_t* __restrict__ Kn,
    const ushort_t* __restrict__ Vt, const float* __restrict__ QF,
    float* __restrict__ AO)
{
    __shared__ __align__(16) ushort_t Ks[64 * 64];      // [kr][d], chunk-swizzled by kr
    __shared__ __align__(16) ushort_t Vs[64 * 64];      // [d][n], chunk-swizzled by d
    __shared__ __align__(16) ushort_t Ps[4][32 * 64];   // per-wave [q][k], swizzled by q

    const int tid = threadIdx.x;
    const int lane = tid & 63;
    const int w = tid >> 6;
    const int lo = lane & 15, hi = lane >> 4;
    const int bh = blockIdx.x, b = bh >> 3, h = bh & 7;
    const int qb = blockIdx.y * 128 + w * 32;

    // Q fragments (held all kernel): q-row = qb + mt*16 + lo, d = ks*32 + hi*8 + j
    bf16x8 qfrag[2][2];
#pragma unroll
    for (int mt = 0; mt < 2; ++mt)
#pragma unroll
        for (int ks = 0; ks < 2; ++ks)
            qfrag[mt][ks] = *(const bf16x8*)&Qn[(b * SEQ + qb + mt * 16 + lo) * 512 +
                                                h * 64 + ks * 32 + hi * 8];

    f32x4 accO[2][4];
    float m_r[2][4], l_r[2][4];
#pragma unroll
    for (int mt = 0; mt < 2; ++mt) {
#pragma unroll
        for (int nt = 0; nt < 4; ++nt) accO[mt][nt] = (f32x4)0.f;
#pragma unroll
        for (int r = 0; r < 4; ++r) { m_r[mt][r] = -INFINITY; l_r[mt][r] = 0.f; }
    }

    for (int kt = 0; kt < 32; ++kt) {
        // ---- stage K and Vt tiles (512 16B-chunks each, 2 per thread) ----
#pragma unroll
        for (int i = 0; i < 2; ++i) {
            int c = tid + i * 256;
            int r = c >> 3, cc = c & 7;
            // K row r (64 bf16), chunk cc
            bf16x8 kv = *(const bf16x8*)&Kn[(b * SEQ + kt * 64 + r) * 512 + h * 64 + cc * 8];
            *(bf16x8*)&Ks[r * 64 + ((cc ^ (r & 7)) * 8)] = kv;
            // Vt row d=r (64 bf16 along n), chunk cc
            bf16x8 vv = *(const bf16x8*)&Vt[((long)(bh * 64 + r)) * SEQ + kt * 64 + cc * 8];
            *(bf16x8*)&Vs[r * 64 + ((cc ^ (r & 7)) * 8)] = vv;
        }
        __syncthreads();

        // ---- QK^T: S[32 q][64 kr] ----
        f32x4 accS[2][4];
#pragma unroll
        for (int mt = 0; mt < 2; ++mt)
#pragma unroll
            for (int nt = 0; nt < 4; ++nt) accS[mt][nt] = (f32x4)0.f;

#pragma unroll
        for (int nt = 0; nt < 4; ++nt) {
            bf16x8 kf[2];
#pragma unroll
            for (int ks = 0; ks < 2; ++ks) {
                int kr = nt * 16 + lo;
                int chunk = (ks * 4 + hi) ^ (kr & 7);
                kf[ks] = *(const bf16x8*)&Ks[kr * 64 + chunk * 8];
            }
#pragma unroll
            for (int mt = 0; mt < 2; ++mt)
#pragma unroll
                for (int ks = 0; ks < 2; ++ks)
                    accS[mt][nt] = __builtin_amdgcn_mfma_f32_16x16x32_bf16(
                        qfrag[mt][ks], kf[ks], accS[mt][nt], 0, 0, 0);
        }

        // ---- online softmax ----
#pragma unroll
        for (int mt = 0; mt < 2; ++mt) {
            float tmax[4];
#pragma unroll
            for (int r = 0; r < 4; ++r)
                tmax[r] = fmaxf(fmaxf(accS[mt][0][r], accS[mt][1][r]),
                                fmaxf(accS[mt][2][r], accS[mt][3][r]));
#pragma unroll
            for (int r = 0; r < 4; ++r) {
#pragma unroll
                for (int d = 1; d <= 8; d <<= 1)
                    tmax[r] = fmaxf(tmax[r], __shfl_xor(tmax[r], d));
            }
#pragma unroll
            for (int r = 0; r < 4; ++r) {
                float mn = fmaxf(m_r[mt][r], tmax[r]);
                float corr = __expf(m_r[mt][r] - mn);   // first tile: exp(-inf)=0
                m_r[mt][r] = mn;
                l_r[mt][r] *= corr;
#pragma unroll
                for (int nt = 0; nt < 4; ++nt) accO[mt][nt][r] *= corr;
            }
#pragma unroll
            for (int nt = 0; nt < 4; ++nt) {
#pragma unroll
                for (int r = 0; r < 4; ++r) {
                    float p = __expf(accS[mt][nt][r] - m_r[mt][r]);
                    l_r[mt][r] += p;
                    int q = mt * 16 + hi * 4 + r;
                    int kcol = nt * 16 + lo;
                    Ps[w][q * 64 + (kcol ^ ((q & 7) * 8))] = f2bf(p);
                }
            }
        }

        // ---- PV: O += P[32 q][64 k] * V[64 k][64 d] ----
#pragma unroll
        for (int kk = 0; kk < 2; ++kk) {
            bf16x8 pf[2];
#pragma unroll
            for (int mt = 0; mt < 2; ++mt) {
                int q = mt * 16 + lo;
                int chunk = (kk * 4 + hi) ^ (q & 7);
                pf[mt] = *(const bf16x8*)&Ps[w][q * 64 + chunk * 8];
            }
#pragma unroll
            for (int nt = 0; nt < 4; ++nt) {
                int d = nt * 16 + lo;
                int chunk = (kk * 4 + hi) ^ (d & 7);
                bf16x8 vf = *(const bf16x8*)&Vs[d * 64 + chunk * 8];
#pragma unroll
                for (int mt = 0; mt < 2; ++mt)
                    accO[mt][nt] = __builtin_amdgcn_mfma_f32_16x16x32_bf16(
                        pf[mt], vf, accO[mt][nt], 0, 0, 0);
            }
        }
        __syncthreads();
    }

    // ---- epilogue: reduce l across the 16-lane row group, gate, store ----
#pragma unroll
    for (int mt = 0; mt < 2; ++mt)
#pragma unroll
        for (int r = 0; r < 4; ++r) {
#pragma unroll
            for (int d = 1; d <= 8; d <<= 1)
                l_r[mt][r] += __shfl_xor(l_r[mt][r], d);
        }

#pragma unroll
    for (int mt = 0; mt < 2; ++mt)
#pragma unroll
        for (int r = 0; r < 4; ++r) {
            int grow = b * SEQ + qb + mt * 16 + hi * 4 + r;
            float g = QF[(long)grow * 520 + 512 + h];
            g = 1.f / (1.f + __expf(-g));
            float sc = g / l_r[mt][r];
#pragma unroll
            for (int nt = 0; nt < 4; ++nt)
                AO[(long)grow * 512 + h * 64 + nt * 16 + lo] = accO[mt][nt][r] * sc;
        }
}

// pos_out = out @ hp_w + hp_b
__global__ __launch_bounds__(256) void posout_kernel(
    const float* __restrict__ outb, const float* __restrict__ hpw,
    const float* __restrict__ hpb, float* __restrict__ po)
{
    const int lane = threadIdx.x & 63;
    const long row = (long)blockIdx.x * 4 + (threadIdx.x >> 6);
    float p0 = 0.f, p1 = 0.f, p2 = 0.f;
#pragma unroll
    for (int it = 0; it < 8; ++it) {
        int k = it * 64 + lane;
        float x = outb[row * 512 + k];
        p0 = fmaf(x, hpw[k * 3 + 0], p0);
        p1 = fmaf(x, hpw[k * 3 + 1], p1);
        p2 = fmaf(x, hpw[k * 3 + 2], p2);
    }
#pragma unroll
    for (int o = 32; o >= 1; o >>= 1) {
        p0 += __shfl_xor(p0, o);
        p1 += __shfl_xor(p1, o);
        p2 += __shfl_xor(p2, o);
    }
    if (lane == 0) {
        po[row * 3 + 0] = p0 + hpb[0];
        po[row * 3 + 1] = p1 + hpb[1];
        po[row * 3 + 2] = p2 + hpb[2];
    }
}

// ---------------------------------------------------------------------------
extern "C" void kernel_launch(void* const* d_in, const int* in_sizes, int n_in,
                              void* d_out, int out_size, void* d_ws, size_t ws_size,
                              hipStream_t stream)
{
    const float* expr    = (const float*)d_in[0];
    const float* dtime   = (const float*)d_in[1];
    const float* posf    = (const float*)d_in[2];
    const float* pos_w1  = (const float*)d_in[3];
    const float* pos_b1  = (const float*)d_in[4];
    const float* pos_w2  = (const float*)d_in[5];
    const float* pos_b2  = (const float*)d_in[6];
    const float* expr_w1 = (const float*)d_in[7];
    const float* expr_b1 = (const float*)d_in[8];
    const float* expr_w2 = (const float*)d_in[9];
    const float* expr_b2 = (const float*)d_in[10];
    const float* yy_w    = (const float*)d_in[11];
    const float* yy_b    = (const float*)d_in[12];
    const float* cat_w   = (const float*)d_in[13];
    const float* cat_b   = (const float*)d_in[14];
    const float* q_w     = (const float*)d_in[15];
    const float* q_b     = (const float*)d_in[16];
    const float* k_w     = (const float*)d_in[17];
    const float* k_b     = (const float*)d_in[18];
    const float* v_w     = (const float*)d_in[19];
    const float* v_b     = (const float*)d_in[20];
    const float* o_w     = (const float*)d_in[21];
    const float* o_b     = (const float*)d_in[22];
    const float* qn_w    = (const float*)d_in[23];
    const float* kn_w    = (const float*)d_in[24];
    const float* hp_w    = (const float*)d_in[25];
    const float* hp_b    = (const float*)d_in[26];
    const float* he_w    = (const float*)d_in[27];
    const float* he_b    = (const float*)d_in[28];
    (void)in_sizes; (void)n_in; (void)out_size; (void)ws_size;

    float* ws   = (float*)d_ws;
    float* cat  = ws + OFF_CAT;
    float* te1  = ws + OFF_TE1;
    float* hbuf = ws + OFF_H;
    float* qf   = ws + OFF_QF;
    float* kbuf = ws + OFF_K;
    float* vbuf = ws + OFF_V;
    float* tdt  = ws + OFF_TDT;
    float* ao   = ws + OFF_AO;
    float* outb = ws + OFF_OUT;
    ushort_t* qn_bf = (ushort_t*)(ws + OFF_QN);
    ushort_t* kn_bf = (ushort_t*)(ws + OFF_QN + 2097152ull);
    ushort_t* vt_bf = (ushort_t*)(ws + OFF_VT);
    float* dout = (float*)d_out;

    const dim3 blk(256);

    // 1. te1 = relu(expr @ expr_w1 + b1)
    sgemm128<1><<<dim3(1, 64), blk, 0, stream>>>(expr, 512, expr_w1, 64, expr_b1,
                                                 te1, 64, 64, 512);
    // 2. cat[:, :512] = te1 @ expr_w2 + b2
    sgemm128<0><<<dim3(4, 64), blk, 0, stream>>>(te1, 64, expr_w2, 512, expr_b2,
                                                 cat, 768, 512, 64);
    // 3. pos MLP -> cat[:, 640:768]
    posmlp_kernel<<<dim3(64), dim3(128), 0, stream>>>(posf, pos_w1, pos_b1,
                                                      pos_w2, pos_b2, cat);
    // 4. tdt
    tdt_kernel<<<dim3(1), dim3(512), 0, stream>>>(dtime, yy_w, yy_b, tdt,
                                                  dout + DOUT_TDT);
    // 5. cat[:, 512:640] = tdt broadcast
    cattime_kernel<<<dim3(4096), blk, 0, stream>>>(tdt, cat);
    // 6. h = cat @ cat_w + cat_b
    sgemm128<0><<<dim3(4, 64), blk, 0, stream>>>(cat, 768, cat_w, 512, cat_b,
                                                 hbuf, 512, 512, 768);
    // 7. qfull = h @ q_w + q_b
    sgemm128<0><<<dim3(5, 64), blk, 0, stream>>>(hbuf, 512, q_w, 520, q_b,
                                                 qf, 520, 520, 512);
    // 8. k = h @ k_w + k_b
    sgemm128<0><<<dim3(4, 64), blk, 0, stream>>>(hbuf, 512, k_w, 512, k_b,
                                                 kbuf, 512, 512, 512);
    // 9. v = h @ v_w + v_b
    sgemm128<0><<<dim3(4, 64), blk, 0, stream>>>(hbuf, 512, v_w, 512, v_b,
                                                 vbuf, 512, 512, 512);
    // 10. Q rmsnorm -> bf16 (folds 1/8 score scale)
    rms_bf16_kernel<<<dim3(16384), blk, 0, stream>>>(qf, 520, qn_bf, qn_w, 0.125f);
    // 11. K rmsnorm -> bf16
    rms_bf16_kernel<<<dim3(16384), blk, 0, stream>>>(kbuf, 512, kn_bf, kn_w, 1.0f);
    // 12. V -> bf16 transposed [bh][d][n]
    vt_kernel<<<dim3(32, 32), blk, 0, stream>>>(vbuf, vt_bf);
    // 13. flash attention (MFMA) + gate; ao reuses cat slot
    flash_attn_mfma<<<dim3(32, 16), blk, 0, stream>>>(qn_bf, kn_bf, vt_bf, qf, ao);
    // 14. out = ao @ o_w + o_b
    sgemm128<0><<<dim3(4, 64), blk, 0, stream>>>(ao, 512, o_w, 512, o_b,
                                                 outb, 512, 512, 512);
    // 15. expr_out = out @ he_w + he_b -> d_out
    sgemm128<0><<<dim3(4, 64), blk, 0, stream>>>(outb, 512, he_w, 512, he_b,
                                                 dout + DOUT_EXPR, 512, 512, 512);
    // 16. pos_out = out @ hp_w + hp_b -> d_out
    posout_kernel<<<dim3(2048), blk, 0, stream>>>(outb, hp_w, hp_b,
                                                  dout + DOUT_POS);
}

// Round 3
// 314.446 us; speedup vs baseline: 5.6118x; 2.6036x over previous
//
#include <hip/hip_runtime.h>
#include <math.h>

// Problem constants
#define SEQ   2048
#define NROWS 8192   // B*N

typedef unsigned short ushort_t;
typedef __attribute__((ext_vector_type(8))) short bf16x8;
typedef __attribute__((ext_vector_type(4))) float f32x4;

// Workspace offsets (ushort units)
#define U_EXPR   0ull            // 8192*512 bf16
#define U_TE1    4194304ull      // 8192*64
#define U_CAT    4718592ull      // 8192*768
#define U_H      11010048ull     // 8192*512
#define U_QKV    15204352ull     // 8192*1544 (q 0-519 | k 520-1031 | v 1032-1543)
#define U_QN     27852800ull     // 8192*512
#define U_KN     32047104ull     // 8192*512
#define U_VT     36241408ull     // 32*64*2048
#define U_AO     40435712ull     // 8192*512
#define U_OUT    44630016ull     // 8192*512
#define U_W1T    48824320ull     // 64*512
#define U_W2T    48857088ull     // 512*64
#define U_CATWT  48889856ull     // 512*768
#define U_QKVWT  49283072ull     // 1544*512
#define U_OWT    50073600ull     // 512*512
#define U_HEWT   50335744ull     // 512*512
#define U_F32    50597888ull     // fp32 region: tdt[512], qkv_bias[1544]

// d_out offsets (floats): (expr_out, pos_out, tdt)
#define DOUT_EXPR 0ull
#define DOUT_POS  4194304ull
#define DOUT_TDT  4218880ull

static __device__ __forceinline__ ushort_t f2bf(float f) {
    union { float f; unsigned int u; } v; v.f = f;
    unsigned int r = (v.u + 0x7fffu + ((v.u >> 16) & 1u)) >> 16;
    return (ushort_t)r;
}
static __device__ __forceinline__ float bf2f(ushort_t u) {
    union { unsigned int u; float f; } v; v.u = ((unsigned int)u) << 16;
    return v.f;
}

// ---------------------------------------------------------------------------
// fp32 -> bf16 bulk convert (n multiple of 2048)
// ---------------------------------------------------------------------------
__global__ __launch_bounds__(256) void f32_to_bf16_kernel(
    const float* __restrict__ src, ushort_t* __restrict__ dst)
{
    long i = ((long)blockIdx.x * 256 + threadIdx.x) * 8;
    float4 a = *(const float4*)&src[i];
    float4 b = *(const float4*)&src[i + 4];
    bf16x8 p;
    p[0] = (short)f2bf(a.x); p[1] = (short)f2bf(a.y);
    p[2] = (short)f2bf(a.z); p[3] = (short)f2bf(a.w);
    p[4] = (short)f2bf(b.x); p[5] = (short)f2bf(b.y);
    p[6] = (short)f2bf(b.z); p[7] = (short)f2bf(b.w);
    *(bf16x8*)&dst[i] = p;
}

// ---------------------------------------------------------------------------
// Weight transpose+convert: W[K][N] fp32 -> Wt[N][K] bf16, 8 segments, 64x64 tiles
// ---------------------------------------------------------------------------
struct WtSeg { const float* src; ushort_t* dst; int K, N, tK, tile0; };
struct WtTable { WtSeg s[8]; };

__global__ __launch_bounds__(256) void wt_transpose(WtTable tab)
{
    __shared__ float t[64][65];
    const int bid = blockIdx.x;
    int si = 0;
#pragma unroll
    for (int i = 1; i < 8; ++i)
        if (bid >= tab.s[i].tile0) si = i;
    const WtSeg sg = tab.s[si];
    const int local = bid - sg.tile0;
    const int k0 = (local % sg.tK) * 64;
    const int n0 = (local / sg.tK) * 64;
    const int tid = threadIdx.x;
#pragma unroll
    for (int i = 0; i < 16; ++i) {
        int e = tid + i * 256;
        int r = e >> 6, c = e & 63;
        float v = 0.f;
        if (k0 + r < sg.K && n0 + c < sg.N)
            v = sg.src[(long)(k0 + r) * sg.N + n0 + c];
        t[r][c] = v;
    }
    __syncthreads();
#pragma unroll
    for (int i = 0; i < 16; ++i) {
        int e = tid + i * 256;
        int rn = e >> 6, ck = e & 63;
        if (n0 + rn < sg.N && k0 + ck < sg.K)
            sg.dst[(long)(n0 + rn) * sg.K + k0 + ck] = f2bf(t[ck][rn]);
    }
}

// fused qkv bias vector
__global__ void gather_bias(const float* __restrict__ qb, const float* __restrict__ kb,
                            const float* __restrict__ vb, float* __restrict__ dst)
{
    int t = blockIdx.x * 256 + threadIdx.x;
    if (t < 520) dst[t] = qb[t];
    else if (t < 1032) dst[t] = kb[t - 520];
    else if (t < 1544) dst[t] = vb[t - 1032];
}

// ---------------------------------------------------------------------------
// bf16 MFMA GEMM: C[M x N] = A[M x K] @ Wt^T + bias; A bf16 [M][lda],
// Wt bf16 [N][ldw] (ldw==K stride), C fp32 or bf16. Tile 128x128, BK=64,
// 512 threads = 8 waves (2m x 4n), wave tile 64x32. Chunk-XOR LDS swizzle.
// M % 128 == 0, K % 64 == 0.
// ---------------------------------------------------------------------------
template <int RELU, int OUT_BF16>
__global__ __launch_bounds__(512) void hgemm(
    const ushort_t* __restrict__ A, int lda,
    const ushort_t* __restrict__ Wt, int ldw,
    const float* __restrict__ bias,
    void* __restrict__ Cv, int ldc,
    int N, int K)
{
    __shared__ __align__(16) ushort_t As[128 * 64];
    __shared__ __align__(16) ushort_t Bs[128 * 64];

    const int tid = threadIdx.x;
    const int lane = tid & 63, w = tid >> 6;
    const int lo = lane & 15, hi = lane >> 4;
    const int wm = w >> 2, wn = w & 3;
    const long m0 = (long)blockIdx.y * 128;
    const int n0 = blockIdx.x * 128;

    f32x4 acc[4][2];
#pragma unroll
    for (int mt = 0; mt < 4; ++mt)
#pragma unroll
        for (int nt = 0; nt < 2; ++nt) acc[mt][nt] = (f32x4)0.f;

    for (int kt = 0; kt < K; kt += 64) {
#pragma unroll
        for (int i = 0; i < 2; ++i) {
            int c = tid + i * 512;          // 0..1023
            int r = c >> 3, ch = c & 7;
            int pch = ((ch ^ (r & 7)) * 8);
            *(bf16x8*)&As[r * 64 + pch] =
                *(const bf16x8*)&A[(m0 + r) * (long)lda + kt + ch * 8];
            bf16x8 bv = (bf16x8)(short)0;
            if (n0 + r < N)
                bv = *(const bf16x8*)&Wt[(long)(n0 + r) * ldw + kt + ch * 8];
            *(bf16x8*)&Bs[r * 64 + pch] = bv;
        }
        __syncthreads();

#pragma unroll
        for (int ks = 0; ks < 2; ++ks) {
            bf16x8 af[4], bfr[2];
#pragma unroll
            for (int mt = 0; mt < 4; ++mt) {
                int m = wm * 64 + mt * 16 + lo;
                af[mt] = *(const bf16x8*)&As[m * 64 + (((ks * 4 + hi) ^ (lo & 7)) * 8)];
            }
#pragma unroll
            for (int nt = 0; nt < 2; ++nt) {
                int n = wn * 32 + nt * 16 + lo;
                bfr[nt] = *(const bf16x8*)&Bs[n * 64 + (((ks * 4 + hi) ^ (lo & 7)) * 8)];
            }
#pragma unroll
            for (int mt = 0; mt < 4; ++mt)
#pragma unroll
                for (int nt = 0; nt < 2; ++nt)
                    acc[mt][nt] = __builtin_amdgcn_mfma_f32_16x16x32_bf16(
                        af[mt], bfr[nt], acc[mt][nt], 0, 0, 0);
        }
        __syncthreads();
    }

#pragma unroll
    for (int mt = 0; mt < 4; ++mt)
#pragma unroll
        for (int nt = 0; nt < 2; ++nt) {
            int col = n0 + wn * 32 + nt * 16 + lo;
            if (col < N) {
                float bv = bias[col];
#pragma unroll
                for (int r = 0; r < 4; ++r) {
                    long row = m0 + wm * 64 + mt * 16 + hi * 4 + r;
                    float v = acc[mt][nt][r] + bv;
                    if (RELU) v = fmaxf(v, 0.f);
                    if (OUT_BF16) ((ushort_t*)Cv)[row * (long)ldc + col] = f2bf(v);
                    else          ((float*)Cv)[row * (long)ldc + col] = v;
                }
            }
        }
}

// ---------------------------------------------------------------------------
// Position MLP -> cat_bf[:, 640:768] (bf16)
// ---------------------------------------------------------------------------
__global__ __launch_bounds__(128) void posmlp_kernel(
    const float* __restrict__ pos,
    const float* __restrict__ w1, const float* __restrict__ b1,
    const float* __restrict__ w2, const float* __restrict__ b2,
    ushort_t* __restrict__ cat)
{
    __shared__ __align__(16) float w1s[256];
    __shared__ __align__(16) float b1s[64];
    __shared__ __align__(16) float w2t[128 * 64];
    __shared__ __align__(16) float b2s[128];

    const int tid = threadIdx.x;
    for (int i = tid; i < 256; i += 128) w1s[i] = w1[i];
    if (tid < 64) b1s[tid] = b1[tid];
    b2s[tid] = b2[tid];
    for (int i = tid; i < 8192; i += 128) {
        int k = i >> 7, o = i & 127;
        w2t[o * 64 + k] = w2[i];
    }
    __syncthreads();

    const long r = (long)blockIdx.x * 128 + tid;
    float px = pos[r * 3 + 0], py = pos[r * 3 + 1], pz = pos[r * 3 + 2];
    float nrm = sqrtf(px * px + py * py + pz * pz);
    float inv = 1.f / (nrm + 1e-7f);
    float pf0 = px * inv, pf1 = py * inv, pf2 = pz * inv, pf3 = nrm;

    float h1[64];
#pragma unroll
    for (int o = 0; o < 64; ++o) {
        float a = b1s[o];
        a = fmaf(pf0, w1s[o], a);
        a = fmaf(pf1, w1s[64 + o], a);
        a = fmaf(pf2, w1s[128 + o], a);
        a = fmaf(pf3, w1s[192 + o], a);
        h1[o] = fmaxf(a, 0.f);
    }
    ushort_t* dst = &cat[r * 768 + 640];
    for (int o = 0; o < 128; ++o) {
        float s = b2s[o];
#pragma unroll
        for (int i4 = 0; i4 < 16; ++i4) {
            float4 wv = *(const float4*)&w2t[o * 64 + i4 * 4];
            s = fmaf(h1[i4 * 4 + 0], wv.x, s);
            s = fmaf(h1[i4 * 4 + 1], wv.y, s);
            s = fmaf(h1[i4 * 4 + 2], wv.z, s);
            s = fmaf(h1[i4 * 4 + 3], wv.w, s);
        }
        dst[o] = f2bf(s);
    }
}

// tdt = diffusion_time @ yy_w + yy_b (fp32, exact)
__global__ __launch_bounds__(512) void tdt_kernel(
    const float* __restrict__ dt, const float* __restrict__ yyw,
    const float* __restrict__ yyb, float* __restrict__ tdt_ws,
    float* __restrict__ out_tail)
{
    const int t = threadIdx.x;
    const int b = t >> 7, o = t & 127;
    float s = yyb[o];
    for (int k = 0; k < 128; ++k) s = fmaf(dt[b * 128 + k], yyw[k * 128 + o], s);
    tdt_ws[t] = s;
    out_tail[t] = s;
}

// cat_bf[:, 512:640] = bf16(tdt[b])
__global__ __launch_bounds__(256) void cattime_kernel(
    const float* __restrict__ tdt, ushort_t* __restrict__ cat)
{
    const long idx = (long)blockIdx.x * 256 + threadIdx.x;
    const long r = idx >> 7;
    const int c = (int)(idx & 127);
    const int b = (int)(r >> 11);
    cat[r * 768 + 512 + c] = f2bf(tdt[b * 128 + c]);
}

// Per-(row, head) rmsnorm over HD=64, bf16 in/out. scale folds 1/8 for Q.
__global__ __launch_bounds__(256) void rms_bf16_kernel(
    const ushort_t* __restrict__ in, int ldi,
    ushort_t* __restrict__ out,
    const float* __restrict__ w, float scale)
{
    const int lane = threadIdx.x & 63;
    const int p = blockIdx.x * 4 + (threadIdx.x >> 6);
    const long row = p >> 3;
    const int h = p & 7;
    float x = bf2f(in[row * (long)ldi + h * 64 + lane]);
    float ss = x * x;
#pragma unroll
    for (int o = 32; o >= 1; o >>= 1) ss += __shfl_xor(ss, o);
    float r = rsqrtf(ss * (1.f / 64.f) + 1e-6f);
    out[row * 512 + h * 64 + lane] = f2bf(w[lane] * x * r * scale);
}

// Vt[bh][d][n] from bf16 V rows (stride ldv); grid (32, 32), block 256
__global__ __launch_bounds__(256) void vt_kernel(
    const ushort_t* __restrict__ V, int ldv, ushort_t* __restrict__ Vt)
{
    __shared__ ushort_t t[64][72];
    const int bh = blockIdx.x, b = bh >> 3, h = bh & 7;
    const int n0 = blockIdx.y * 64;
    const int tid = threadIdx.x;
#pragma unroll
    for (int i = 0; i < 2; ++i) {
        int c = tid + i * 256;
        int r = c >> 3, ch = c & 7;
        *(bf16x8*)&t[r][ch * 8] =
            *(const bf16x8*)&V[(long)(b * SEQ + n0 + r) * ldv + h * 64 + ch * 8];
    }
    __syncthreads();
    const int d = tid >> 2;
#pragma unroll
    for (int i = 0; i < 2; ++i) {
        int cc = (tid & 3) * 2 + i;
        bf16x8 pk;
#pragma unroll
        for (int j = 0; j < 8; ++j) pk[j] = (short)t[cc * 8 + j][d];
        *(bf16x8*)&Vt[((long)(bh * 64 + d)) * SEQ + n0 + cc * 8] = pk;
    }
}

// ---------------------------------------------------------------------------
// Flash attention, bf16 MFMA 16x16x32, online softmax, gate-sigmoid epilogue.
// grid (32 bh, 16), block 256. Gate from bf16 qkv[.,512+h]; AO out bf16.
// ---------------------------------------------------------------------------
__global__ __launch_bounds__(256) void flash_attn_mfma(
    const ushort_t* __restrict__ Qn, const ushort_t* __restrict__ Kn,
    const ushort_t* __restrict__ Vt, const ushort_t* __restrict__ QKV,
    ushort_t* __restrict__ AO)
{
    __shared__ __align__(16) ushort_t Ks[64 * 64];
    __shared__ __align__(16) ushort_t Vs[64 * 64];
    __shared__ __align__(16) ushort_t Ps[4][32 * 64];

    const int tid = threadIdx.x;
    const int lane = tid & 63;
    const int w = tid >> 6;
    const int lo = lane & 15, hi = lane >> 4;
    const int bh = blockIdx.x, b = bh >> 3, h = bh & 7;
    const int qb = blockIdx.y * 128 + w * 32;

    bf16x8 qfrag[2][2];
#pragma unroll
    for (int mt = 0; mt < 2; ++mt)
#pragma unroll
        for (int ks = 0; ks < 2; ++ks)
            qfrag[mt][ks] = *(const bf16x8*)&Qn[(b * SEQ + qb + mt * 16 + lo) * 512 +
                                                h * 64 + ks * 32 + hi * 8];

    f32x4 accO[2][4];
    float m_r[2][4], l_r[2][4];
#pragma unroll
    for (int mt = 0; mt < 2; ++mt) {
#pragma unroll
        for (int nt = 0; nt < 4; ++nt) accO[mt][nt] = (f32x4)0.f;
#pragma unroll
        for (int r = 0; r < 4; ++r) { m_r[mt][r] = -INFINITY; l_r[mt][r] = 0.f; }
    }

    for (int kt = 0; kt < 32; ++kt) {
#pragma unroll
        for (int i = 0; i < 2; ++i) {
            int c = tid + i * 256;
            int r = c >> 3, cc = c & 7;
            bf16x8 kv = *(const bf16x8*)&Kn[(b * SEQ + kt * 64 + r) * 512 + h * 64 + cc * 8];
            *(bf16x8*)&Ks[r * 64 + ((cc ^ (r & 7)) * 8)] = kv;
            bf16x8 vv = *(const bf16x8*)&Vt[((long)(bh * 64 + r)) * SEQ + kt * 64 + cc * 8];
            *(bf16x8*)&Vs[r * 64 + ((cc ^ (r & 7)) * 8)] = vv;
        }
        __syncthreads();

        f32x4 accS[2][4];
#pragma unroll
        for (int mt = 0; mt < 2; ++mt)
#pragma unroll
            for (int nt = 0; nt < 4; ++nt) accS[mt][nt] = (f32x4)0.f;

#pragma unroll
        for (int nt = 0; nt < 4; ++nt) {
            bf16x8 kf[2];
#pragma unroll
            for (int ks = 0; ks < 2; ++ks) {
                int kr = nt * 16 + lo;
                int chunk = (ks * 4 + hi) ^ (kr & 7);
                kf[ks] = *(const bf16x8*)&Ks[kr * 64 + chunk * 8];
            }
#pragma unroll
            for (int mt = 0; mt < 2; ++mt)
#pragma unroll
                for (int ks = 0; ks < 2; ++ks)
                    accS[mt][nt] = __builtin_amdgcn_mfma_f32_16x16x32_bf16(
                        qfrag[mt][ks], kf[ks], accS[mt][nt], 0, 0, 0);
        }

#pragma unroll
        for (int mt = 0; mt < 2; ++mt) {
            float tmax[4];
#pragma unroll
            for (int r = 0; r < 4; ++r)
                tmax[r] = fmaxf(fmaxf(accS[mt][0][r], accS[mt][1][r]),
                                fmaxf(accS[mt][2][r], accS[mt][3][r]));
#pragma unroll
            for (int r = 0; r < 4; ++r) {
#pragma unroll
                for (int d = 1; d <= 8; d <<= 1)
                    tmax[r] = fmaxf(tmax[r], __shfl_xor(tmax[r], d));
            }
#pragma unroll
            for (int r = 0; r < 4; ++r) {
                float mn = fmaxf(m_r[mt][r], tmax[r]);
                float corr = __expf(m_r[mt][r] - mn);
                m_r[mt][r] = mn;
                l_r[mt][r] *= corr;
#pragma unroll
                for (int nt = 0; nt < 4; ++nt) accO[mt][nt][r] *= corr;
            }
#pragma unroll
            for (int nt = 0; nt < 4; ++nt) {
#pragma unroll
                for (int r = 0; r < 4; ++r) {
                    float p = __expf(accS[mt][nt][r] - m_r[mt][r]);
                    l_r[mt][r] += p;
                    int q = mt * 16 + hi * 4 + r;
                    int kcol = nt * 16 + lo;
                    Ps[w][q * 64 + (kcol ^ ((q & 7) * 8))] = f2bf(p);
                }
            }
        }

#pragma unroll
        for (int kk = 0; kk < 2; ++kk) {
            bf16x8 pf[2];
#pragma unroll
            for (int mt = 0; mt < 2; ++mt) {
                int q = mt * 16 + lo;
                int chunk = (kk * 4 + hi) ^ (q & 7);
                pf[mt] = *(const bf16x8*)&Ps[w][q * 64 + chunk * 8];
            }
#pragma unroll
            for (int nt = 0; nt < 4; ++nt) {
                int d = nt * 16 + lo;
                int chunk = (kk * 4 + hi) ^ (d & 7);
                bf16x8 vf = *(const bf16x8*)&Vs[d * 64 + chunk * 8];
#pragma unroll
                for (int mt = 0; mt < 2; ++mt)
                    accO[mt][nt] = __builtin_amdgcn_mfma_f32_16x16x32_bf16(
                        pf[mt], vf, accO[mt][nt], 0, 0, 0);
            }
        }
        __syncthreads();
    }

#pragma unroll
    for (int mt = 0; mt < 2; ++mt)
#pragma unroll
        for (int r = 0; r < 4; ++r) {
#pragma unroll
            for (int d = 1; d <= 8; d <<= 1)
                l_r[mt][r] += __shfl_xor(l_r[mt][r], d);
        }

#pragma unroll
    for (int mt = 0; mt < 2; ++mt)
#pragma unroll
        for (int r = 0; r < 4; ++r) {
            int grow = b * SEQ + qb + mt * 16 + hi * 4 + r;
            float g = bf2f(QKV[(long)grow * 1544 + 512 + h]);
            g = 1.f / (1.f + __expf(-g));
            float sc = g / l_r[mt][r];
#pragma unroll
            for (int nt = 0; nt < 4; ++nt)
                AO[(long)grow * 512 + h * 64 + nt * 16 + lo] = f2bf(accO[mt][nt][r] * sc);
        }
}

// pos_out = out @ hp_w + hp_b (bf16 in, fp32 out)
__global__ __launch_bounds__(256) void posout_kernel(
    const ushort_t* __restrict__ outb, const float* __restrict__ hpw,
    const float* __restrict__ hpb, float* __restrict__ po)
{
    const int lane = threadIdx.x & 63;
    const long row = (long)blockIdx.x * 4 + (threadIdx.x >> 6);
    float p0 = 0.f, p1 = 0.f, p2 = 0.f;
#pragma unroll
    for (int it = 0; it < 8; ++it) {
        int k = it * 64 + lane;
        float x = bf2f(outb[row * 512 + k]);
        p0 = fmaf(x, hpw[k * 3 + 0], p0);
        p1 = fmaf(x, hpw[k * 3 + 1], p1);
        p2 = fmaf(x, hpw[k * 3 + 2], p2);
    }
#pragma unroll
    for (int o = 32; o >= 1; o >>= 1) {
        p0 += __shfl_xor(p0, o);
        p1 += __shfl_xor(p1, o);
        p2 += __shfl_xor(p2, o);
    }
    if (lane == 0) {
        po[row * 3 + 0] = p0 + hpb[0];
        po[row * 3 + 1] = p1 + hpb[1];
        po[row * 3 + 2] = p2 + hpb[2];
    }
}

// ---------------------------------------------------------------------------
extern "C" void kernel_launch(void* const* d_in, const int* in_sizes, int n_in,
                              void* d_out, int out_size, void* d_ws, size_t ws_size,
                              hipStream_t stream)
{
    const float* expr    = (const float*)d_in[0];
    const float* dtime   = (const float*)d_in[1];
    const float* posf    = (const float*)d_in[2];
    const float* pos_w1  = (const float*)d_in[3];
    const float* pos_b1  = (const float*)d_in[4];
    const float* pos_w2  = (const float*)d_in[5];
    const float* pos_b2  = (const float*)d_in[6];
    const float* expr_w1 = (const float*)d_in[7];
    const float* expr_b1 = (const float*)d_in[8];
    const float* expr_w2 = (const float*)d_in[9];
    const float* expr_b2 = (const float*)d_in[10];
    const float* yy_w    = (const float*)d_in[11];
    const float* yy_b    = (const float*)d_in[12];
    const float* cat_w   = (const float*)d_in[13];
    const float* cat_b   = (const float*)d_in[14];
    const float* q_w     = (const float*)d_in[15];
    const float* q_b     = (const float*)d_in[16];
    const float* k_w     = (const float*)d_in[17];
    const float* k_b     = (const float*)d_in[18];
    const float* v_w     = (const float*)d_in[19];
    const float* v_b     = (const float*)d_in[20];
    const float* o_w     = (const float*)d_in[21];
    const float* o_b     = (const float*)d_in[22];
    const float* qn_w    = (const float*)d_in[23];
    const float* kn_w    = (const float*)d_in[24];
    const float* hp_w    = (const float*)d_in[25];
    const float* hp_b    = (const float*)d_in[26];
    const float* he_w    = (const float*)d_in[27];
    const float* he_b    = (const float*)d_in[28];
    (void)in_sizes; (void)n_in; (void)out_size; (void)ws_size;

    ushort_t* wsb    = (ushort_t*)d_ws;
    ushort_t* expr_bf = wsb + U_EXPR;
    ushort_t* te1_bf  = wsb + U_TE1;
    ushort_t* cat_bf  = wsb + U_CAT;
    ushort_t* h_bf    = wsb + U_H;
    ushort_t* qkv_bf  = wsb + U_QKV;
    ushort_t* qn_bf   = wsb + U_QN;
    ushort_t* kn_bf   = wsb + U_KN;
    ushort_t* vt_bf   = wsb + U_VT;
    ushort_t* ao_bf   = wsb + U_AO;
    ushort_t* out_bf  = wsb + U_OUT;
    ushort_t* w1t     = wsb + U_W1T;
    ushort_t* w2t     = wsb + U_W2T;
    ushort_t* cat_wt  = wsb + U_CATWT;
    ushort_t* qkv_wt  = wsb + U_QKVWT;
    ushort_t* o_wt    = wsb + U_OWT;
    ushort_t* he_wt   = wsb + U_HEWT;
    float* tdt        = (float*)(wsb + U_F32);
    float* qkv_bias   = tdt + 512;
    float* dout       = (float*)d_out;

    const dim3 blk(256);
    const dim3 blk512(512);

    // --- prep: conversions / transposes ---
    f32_to_bf16_kernel<<<dim3(2048), blk, 0, stream>>>(expr, expr_bf);

    WtTable tab;
    tab.s[0] = { expr_w1, w1t,              512,  64, 8,   0 };  // 8 tiles
    tab.s[1] = { expr_w2, w2t,               64, 512, 1,   8 };  // 8
    tab.s[2] = { cat_w,   cat_wt,           768, 512, 12, 16 };  // 96
    tab.s[3] = { q_w,     qkv_wt,           512, 520, 8, 112 };  // 72
    tab.s[4] = { k_w,     qkv_wt + 520*512, 512, 512, 8, 184 };  // 64
    tab.s[5] = { v_w,     qkv_wt + 1032*512,512, 512, 8, 248 };  // 64
    tab.s[6] = { o_w,     o_wt,             512, 512, 8, 312 };  // 64
    tab.s[7] = { he_w,    he_wt,            512, 512, 8, 376 };  // 64 -> 440
    wt_transpose<<<dim3(440), blk, 0, stream>>>(tab);
    gather_bias<<<dim3(7), blk, 0, stream>>>(q_b, k_b, v_b, qkv_bias);

    // --- pipeline ---
    // te1 = relu(expr @ expr_w1 + b1)
    hgemm<1, 1><<<dim3(1, 64), blk512, 0, stream>>>(expr_bf, 512, w1t, 512,
                                                    expr_b1, te1_bf, 64, 64, 512);
    // cat[:, :512] = te1 @ expr_w2 + b2
    hgemm<0, 1><<<dim3(4, 64), blk512, 0, stream>>>(te1_bf, 64, w2t, 64,
                                                    expr_b2, cat_bf, 768, 512, 64);
    posmlp_kernel<<<dim3(64), dim3(128), 0, stream>>>(posf, pos_w1, pos_b1,
                                                      pos_w2, pos_b2, cat_bf);
    tdt_kernel<<<dim3(1), dim3(512), 0, stream>>>(dtime, yy_w, yy_b, tdt,
                                                  dout + DOUT_TDT);
    cattime_kernel<<<dim3(4096), blk, 0, stream>>>(tdt, cat_bf);
    // h = cat @ cat_w + cat_b
    hgemm<0, 1><<<dim3(4, 64), blk512, 0, stream>>>(cat_bf, 768, cat_wt, 768,
                                                    cat_b, h_bf, 512, 512, 768);
    // qkv = h @ [q_w|k_w|v_w] + bias   (N = 1544)
    hgemm<0, 1><<<dim3(13, 64), blk512, 0, stream>>>(h_bf, 512, qkv_wt, 512,
                                                     qkv_bias, qkv_bf, 1544, 1544, 512);
    // rmsnorms -> bf16 (Q folds 1/8)
    rms_bf16_kernel<<<dim3(16384), blk, 0, stream>>>(qkv_bf, 1544, qn_bf, qn_w, 0.125f);
    rms_bf16_kernel<<<dim3(16384), blk, 0, stream>>>(qkv_bf + 520, 1544, kn_bf, kn_w, 1.0f);
    // Vt
    vt_kernel<<<dim3(32, 32), blk, 0, stream>>>(qkv_bf + 1032, 1544, vt_bf);
    // attention
    flash_attn_mfma<<<dim3(32, 16), blk, 0, stream>>>(qn_bf, kn_bf, vt_bf, qkv_bf, ao_bf);
    // out = ao @ o_w + o_b
    hgemm<0, 1><<<dim3(4, 64), blk512, 0, stream>>>(ao_bf, 512, o_wt, 512,
                                                    o_b, out_bf, 512, 512, 512);
    // expr_out = out @ he_w + he_b -> d_out (fp32)
    hgemm<0, 0><<<dim3(4, 64), blk512, 0, stream>>>(out_bf, 512, he_wt, 512,
                                                    he_b, dout + DOUT_EXPR, 512, 512, 512);
    posout_kernel<<<dim3(2048), blk, 0, stream>>>(out_bf, hp_w, hp_b,
                                                  dout + DOUT_POS);
}

// Round 4
// 273.262 us; speedup vs baseline: 6.4576x; 1.1507x over previous
//
#include <hip/hip_runtime.h>
#include <math.h>

// Problem constants
#define SEQ   2048
#define NROWS 8192   // B*N

typedef unsigned short ushort_t;
typedef __attribute__((ext_vector_type(8))) short bf16x8;
typedef __attribute__((ext_vector_type(4))) float f32x4;

// Workspace offsets (ushort units)
#define U_EXPR   0ull            // 8192*512 bf16
#define U_TE1    4194304ull      // 8192*64
#define U_CAT    4718592ull      // 8192*768
#define U_H      11010048ull     // 8192*512
#define U_QKV    15204352ull     // 8192*1544 (q 0-519 | k 520-1031 | v 1032-1543)
#define U_QN     27852800ull     // 8192*512
#define U_KN     32047104ull     // 8192*512
#define U_VT     36241408ull     // 32*64*2048
#define U_AO     40435712ull     // 8192*512
#define U_OUT    44630016ull     // 8192*512
#define U_W1T    48824320ull     // 64*512
#define U_W2T    48857088ull     // 512*64
#define U_CATWT  48889856ull     // 512*768
#define U_QKVWT  49283072ull     // 1544*512
#define U_OWT    50073600ull     // 512*512
#define U_HEWT   50335744ull     // 512*512
#define U_F32    50597888ull     // fp32 region: tdt[512], qkv_bias[1544]

// d_out offsets (floats): (expr_out, pos_out, tdt)
#define DOUT_EXPR 0ull
#define DOUT_POS  4194304ull
#define DOUT_TDT  4218880ull

static __device__ __forceinline__ ushort_t f2bf(float f) {
    union { float f; unsigned int u; } v; v.f = f;
    unsigned int r = (v.u + 0x7fffu + ((v.u >> 16) & 1u)) >> 16;
    return (ushort_t)r;
}
static __device__ __forceinline__ float bf2f(ushort_t u) {
    union { unsigned int u; float f; } v; v.u = ((unsigned int)u) << 16;
    return v.f;
}

// ---------------------------------------------------------------------------
// fp32 -> bf16 bulk convert (n multiple of 2048)
// ---------------------------------------------------------------------------
__global__ __launch_bounds__(256) void f32_to_bf16_kernel(
    const float* __restrict__ src, ushort_t* __restrict__ dst)
{
    long i = ((long)blockIdx.x * 256 + threadIdx.x) * 8;
    float4 a = *(const float4*)&src[i];
    float4 b = *(const float4*)&src[i + 4];
    bf16x8 p;
    p[0] = (short)f2bf(a.x); p[1] = (short)f2bf(a.y);
    p[2] = (short)f2bf(a.z); p[3] = (short)f2bf(a.w);
    p[4] = (short)f2bf(b.x); p[5] = (short)f2bf(b.y);
    p[6] = (short)f2bf(b.z); p[7] = (short)f2bf(b.w);
    *(bf16x8*)&dst[i] = p;
}

// ---------------------------------------------------------------------------
// Weight transpose+convert: W[K][N] fp32 -> Wt[N][K] bf16, 8 segments, 64x64 tiles
// ---------------------------------------------------------------------------
struct WtSeg { const float* src; ushort_t* dst; int K, N, tK, tile0; };
struct WtTable { WtSeg s[8]; };

__global__ __launch_bounds__(256) void wt_transpose(WtTable tab)
{
    __shared__ float t[64][65];
    const int bid = blockIdx.x;
    int si = 0;
#pragma unroll
    for (int i = 1; i < 8; ++i)
        if (bid >= tab.s[i].tile0) si = i;
    const WtSeg sg = tab.s[si];
    const int local = bid - sg.tile0;
    const int k0 = (local % sg.tK) * 64;
    const int n0 = (local / sg.tK) * 64;
    const int tid = threadIdx.x;
#pragma unroll
    for (int i = 0; i < 16; ++i) {
        int e = tid + i * 256;
        int r = e >> 6, c = e & 63;
        float v = 0.f;
        if (k0 + r < sg.K && n0 + c < sg.N)
            v = sg.src[(long)(k0 + r) * sg.N + n0 + c];
        t[r][c] = v;
    }
    __syncthreads();
#pragma unroll
    for (int i = 0; i < 16; ++i) {
        int e = tid + i * 256;
        int rn = e >> 6, ck = e & 63;
        if (n0 + rn < sg.N && k0 + ck < sg.K)
            sg.dst[(long)(n0 + rn) * sg.K + k0 + ck] = f2bf(t[ck][rn]);
    }
}

// fused qkv bias vector
__global__ void gather_bias(const float* __restrict__ qb, const float* __restrict__ kb,
                            const float* __restrict__ vb, float* __restrict__ dst)
{
    int t = blockIdx.x * 256 + threadIdx.x;
    if (t < 520) dst[t] = qb[t];
    else if (t < 1032) dst[t] = kb[t - 520];
    else if (t < 1544) dst[t] = vb[t - 1032];
}

// ---------------------------------------------------------------------------
// bf16 MFMA GEMM: C[M x N] = A[M x K] @ Wt^T + bias; tile 128x128, BK=64,
// 512 threads = 8 waves (2m x 4n), wave tile 64x32. Chunk-XOR LDS swizzle.
// ---------------------------------------------------------------------------
template <int RELU, int OUT_BF16>
__global__ __launch_bounds__(512) void hgemm(
    const ushort_t* __restrict__ A, int lda,
    const ushort_t* __restrict__ Wt, int ldw,
    const float* __restrict__ bias,
    void* __restrict__ Cv, int ldc,
    int N, int K)
{
    __shared__ __align__(16) ushort_t As[128 * 64];
    __shared__ __align__(16) ushort_t Bs[128 * 64];

    const int tid = threadIdx.x;
    const int lane = tid & 63, w = tid >> 6;
    const int lo = lane & 15, hi = lane >> 4;
    const int wm = w >> 2, wn = w & 3;
    const long m0 = (long)blockIdx.y * 128;
    const int n0 = blockIdx.x * 128;

    f32x4 acc[4][2];
#pragma unroll
    for (int mt = 0; mt < 4; ++mt)
#pragma unroll
        for (int nt = 0; nt < 2; ++nt) acc[mt][nt] = (f32x4)0.f;

    for (int kt = 0; kt < K; kt += 64) {
#pragma unroll
        for (int i = 0; i < 2; ++i) {
            int c = tid + i * 512;          // 0..1023
            int r = c >> 3, ch = c & 7;
            int pch = ((ch ^ (r & 7)) * 8);
            *(bf16x8*)&As[r * 64 + pch] =
                *(const bf16x8*)&A[(m0 + r) * (long)lda + kt + ch * 8];
            bf16x8 bv = (bf16x8)(short)0;
            if (n0 + r < N)
                bv = *(const bf16x8*)&Wt[(long)(n0 + r) * ldw + kt + ch * 8];
            *(bf16x8*)&Bs[r * 64 + pch] = bv;
        }
        __syncthreads();

#pragma unroll
        for (int ks = 0; ks < 2; ++ks) {
            bf16x8 af[4], bfr[2];
#pragma unroll
            for (int mt = 0; mt < 4; ++mt) {
                int m = wm * 64 + mt * 16 + lo;
                af[mt] = *(const bf16x8*)&As[m * 64 + (((ks * 4 + hi) ^ (lo & 7)) * 8)];
            }
#pragma unroll
            for (int nt = 0; nt < 2; ++nt) {
                int n = wn * 32 + nt * 16 + lo;
                bfr[nt] = *(const bf16x8*)&Bs[n * 64 + (((ks * 4 + hi) ^ (lo & 7)) * 8)];
            }
#pragma unroll
            for (int mt = 0; mt < 4; ++mt)
#pragma unroll
                for (int nt = 0; nt < 2; ++nt)
                    acc[mt][nt] = __builtin_amdgcn_mfma_f32_16x16x32_bf16(
                        af[mt], bfr[nt], acc[mt][nt], 0, 0, 0);
        }
        __syncthreads();
    }

#pragma unroll
    for (int mt = 0; mt < 4; ++mt)
#pragma unroll
        for (int nt = 0; nt < 2; ++nt) {
            int col = n0 + wn * 32 + nt * 16 + lo;
            if (col < N) {
                float bv = bias[col];
#pragma unroll
                for (int r = 0; r < 4; ++r) {
                    long row = m0 + wm * 64 + mt * 16 + hi * 4 + r;
                    float v = acc[mt][nt][r] + bv;
                    if (RELU) v = fmaxf(v, 0.f);
                    if (OUT_BF16) ((ushort_t*)Cv)[row * (long)ldc + col] = f2bf(v);
                    else          ((float*)Cv)[row * (long)ldc + col] = v;
                }
            }
        }
}

// ---------------------------------------------------------------------------
// Position MLP -> cat_bf[:, 640:768] (bf16)
// ---------------------------------------------------------------------------
__global__ __launch_bounds__(128) void posmlp_kernel(
    const float* __restrict__ pos,
    const float* __restrict__ w1, const float* __restrict__ b1,
    const float* __restrict__ w2, const float* __restrict__ b2,
    ushort_t* __restrict__ cat)
{
    __shared__ __align__(16) float w1s[256];
    __shared__ __align__(16) float b1s[64];
    __shared__ __align__(16) float w2t[128 * 64];
    __shared__ __align__(16) float b2s[128];

    const int tid = threadIdx.x;
    for (int i = tid; i < 256; i += 128) w1s[i] = w1[i];
    if (tid < 64) b1s[tid] = b1[tid];
    b2s[tid] = b2[tid];
    for (int i = tid; i < 8192; i += 128) {
        int k = i >> 7, o = i & 127;
        w2t[o * 64 + k] = w2[i];
    }
    __syncthreads();

    const long r = (long)blockIdx.x * 128 + tid;
    float px = pos[r * 3 + 0], py = pos[r * 3 + 1], pz = pos[r * 3 + 2];
    float nrm = sqrtf(px * px + py * py + pz * pz);
    float inv = 1.f / (nrm + 1e-7f);
    float pf0 = px * inv, pf1 = py * inv, pf2 = pz * inv, pf3 = nrm;

    float h1[64];
#pragma unroll
    for (int o = 0; o < 64; ++o) {
        float a = b1s[o];
        a = fmaf(pf0, w1s[o], a);
        a = fmaf(pf1, w1s[64 + o], a);
        a = fmaf(pf2, w1s[128 + o], a);
        a = fmaf(pf3, w1s[192 + o], a);
        h1[o] = fmaxf(a, 0.f);
    }
    ushort_t* dst = &cat[r * 768 + 640];
    for (int o = 0; o < 128; ++o) {
        float s = b2s[o];
#pragma unroll
        for (int i4 = 0; i4 < 16; ++i4) {
            float4 wv = *(const float4*)&w2t[o * 64 + i4 * 4];
            s = fmaf(h1[i4 * 4 + 0], wv.x, s);
            s = fmaf(h1[i4 * 4 + 1], wv.y, s);
            s = fmaf(h1[i4 * 4 + 2], wv.z, s);
            s = fmaf(h1[i4 * 4 + 3], wv.w, s);
        }
        dst[o] = f2bf(s);
    }
}

// tdt = diffusion_time @ yy_w + yy_b (fp32, exact)
__global__ __launch_bounds__(512) void tdt_kernel(
    const float* __restrict__ dt, const float* __restrict__ yyw,
    const float* __restrict__ yyb, float* __restrict__ tdt_ws,
    float* __restrict__ out_tail)
{
    const int t = threadIdx.x;
    const int b = t >> 7, o = t & 127;
    float s = yyb[o];
    for (int k = 0; k < 128; ++k) s = fmaf(dt[b * 128 + k], yyw[k * 128 + o], s);
    tdt_ws[t] = s;
    out_tail[t] = s;
}

// cat_bf[:, 512:640] = bf16(tdt[b])
__global__ __launch_bounds__(256) void cattime_kernel(
    const float* __restrict__ tdt, ushort_t* __restrict__ cat)
{
    const long idx = (long)blockIdx.x * 256 + threadIdx.x;
    const long r = idx >> 7;
    const int c = (int)(idx & 127);
    const int b = (int)(r >> 11);
    cat[r * 768 + 512 + c] = f2bf(tdt[b * 128 + c]);
}

// Per-(row, head) rmsnorm over HD=64, bf16 in/out. scale folds 1/8 for Q.
__global__ __launch_bounds__(256) void rms_bf16_kernel(
    const ushort_t* __restrict__ in, int ldi,
    ushort_t* __restrict__ out,
    const float* __restrict__ w, float scale)
{
    const int lane = threadIdx.x & 63;
    const int p = blockIdx.x * 4 + (threadIdx.x >> 6);
    const long row = p >> 3;
    const int h = p & 7;
    float x = bf2f(in[row * (long)ldi + h * 64 + lane]);
    float ss = x * x;
#pragma unroll
    for (int o = 32; o >= 1; o >>= 1) ss += __shfl_xor(ss, o);
    float r = rsqrtf(ss * (1.f / 64.f) + 1e-6f);
    out[row * 512 + h * 64 + lane] = f2bf(w[lane] * x * r * scale);
}

// Vt[bh][d][n] from bf16 V rows (stride ldv); grid (32, 32), block 256
__global__ __launch_bounds__(256) void vt_kernel(
    const ushort_t* __restrict__ V, int ldv, ushort_t* __restrict__ Vt)
{
    __shared__ ushort_t t[64][72];
    const int bh = blockIdx.x, b = bh >> 3, h = bh & 7;
    const int n0 = blockIdx.y * 64;
    const int tid = threadIdx.x;
#pragma unroll
    for (int i = 0; i < 2; ++i) {
        int c = tid + i * 256;
        int r = c >> 3, ch = c & 7;
        *(bf16x8*)&t[r][ch * 8] =
            *(const bf16x8*)&V[(long)(b * SEQ + n0 + r) * ldv + h * 64 + ch * 8];
    }
    __syncthreads();
    const int d = tid >> 2;
#pragma unroll
    for (int i = 0; i < 2; ++i) {
        int cc = (tid & 3) * 2 + i;
        bf16x8 pk;
#pragma unroll
        for (int j = 0; j < 8; ++j) pk[j] = (short)t[cc * 8 + j][d];
        *(bf16x8*)&Vt[((long)(bh * 64 + d)) * SEQ + n0 + cc * 8] = pk;
    }
}

// ---------------------------------------------------------------------------
// Flash attention, bf16 MFMA 16x16x32.
// Fixed-shift softmax: |scores| <= 8 analytically (rmsnorm'd Q/8, K; unit
// norm weights) so p = exp(s) cannot overflow -> no running max, no rescale.
// Swapped QK^T (mfma(K,Q) = S^T): lane holds 4 consecutive k per q ->
// packed ds_write_b64 P stores via v_cvt_pk_bf16_f32; l reduces with 2 shfls.
// K/V tile register-prefetch hides HBM/L2 latency under MFMA phase.
// grid (32 bh, 16), block 256 (4 waves x 32 q rows). K-tile 64.
// ---------------------------------------------------------------------------
__global__ __launch_bounds__(256) void flash_attn_mfma(
    const ushort_t* __restrict__ Qn, const ushort_t* __restrict__ Kn,
    const ushort_t* __restrict__ Vt, const ushort_t* __restrict__ QKV,
    ushort_t* __restrict__ AO)
{
    __shared__ __align__(16) ushort_t Ks[64 * 64];      // [k_row][d], chunk-swizzled
    __shared__ __align__(16) ushort_t Vs[64 * 64];      // [d][n],    chunk-swizzled
    __shared__ __align__(16) ushort_t Ps[4][32 * 64];   // per-wave [q][k], swizzled

    const int tid = threadIdx.x;
    const int lane = tid & 63;
    const int w = tid >> 6;
    const int lo = lane & 15, hi = lane >> 4;
    const int bh = blockIdx.x, b = bh >> 3, h = bh & 7;
    const int qb = blockIdx.y * 128 + w * 32;

    // Q fragments (B-operand): q = qb + jt*16 + lo, d = ks*32 + hi*8 + j
    bf16x8 qfrag[2][2];
#pragma unroll
    for (int jt = 0; jt < 2; ++jt)
#pragma unroll
        for (int ks = 0; ks < 2; ++ks)
            qfrag[jt][ks] = *(const bf16x8*)&Qn[(b * SEQ + qb + jt * 16 + lo) * 512 +
                                                h * 64 + ks * 32 + hi * 8];

    f32x4 accO[2][4];
#pragma unroll
    for (int mt = 0; mt < 2; ++mt)
#pragma unroll
        for (int nt = 0; nt < 4; ++nt) accO[mt][nt] = (f32x4)0.f;
    float l_part[2] = {0.f, 0.f};

    // staging indices: thread covers 2 (row, chunk) slots
    const int sr0 = tid >> 3, sc0 = tid & 7;            // c = tid
    const int sr1 = (tid + 256) >> 3, sc1 = tid & 7;    // c = tid + 256

    // prefetch tile 0
    bf16x8 kreg0, kreg1, vreg0, vreg1;
    {
        kreg0 = *(const bf16x8*)&Kn[(b * SEQ + sr0) * 512 + h * 64 + sc0 * 8];
        vreg0 = *(const bf16x8*)&Vt[((long)(bh * 64 + sr0)) * SEQ + sc0 * 8];
        kreg1 = *(const bf16x8*)&Kn[(b * SEQ + sr1) * 512 + h * 64 + sc1 * 8];
        vreg1 = *(const bf16x8*)&Vt[((long)(bh * 64 + sr1)) * SEQ + sc1 * 8];
    }

    for (int kt = 0; kt < 32; ++kt) {
        // write staged regs -> LDS
        *(bf16x8*)&Ks[sr0 * 64 + ((sc0 ^ (sr0 & 7)) * 8)] = kreg0;
        *(bf16x8*)&Vs[sr0 * 64 + ((sc0 ^ (sr0 & 7)) * 8)] = vreg0;
        *(bf16x8*)&Ks[sr1 * 64 + ((sc1 ^ (sr1 & 7)) * 8)] = kreg1;
        *(bf16x8*)&Vs[sr1 * 64 + ((sc1 ^ (sr1 & 7)) * 8)] = vreg1;
        __syncthreads();

        // prefetch next tile (in flight during compute)
        if (kt + 1 < 32) {
            int nk = (kt + 1) * 64;
            kreg0 = *(const bf16x8*)&Kn[(b * SEQ + nk + sr0) * 512 + h * 64 + sc0 * 8];
            vreg0 = *(const bf16x8*)&Vt[((long)(bh * 64 + sr0)) * SEQ + nk + sc0 * 8];
            kreg1 = *(const bf16x8*)&Kn[(b * SEQ + nk + sr1) * 512 + h * 64 + sc1 * 8];
            vreg1 = *(const bf16x8*)&Vt[((long)(bh * 64 + sr1)) * SEQ + nk + sc1 * 8];
        }

        // ---- S^T = K · Q^T : accS[it k-tile][jt q-tile], D[i=k][j=q] ----
        f32x4 accS[4][2];
#pragma unroll
        for (int it = 0; it < 4; ++it)
#pragma unroll
            for (int jt = 0; jt < 2; ++jt) accS[it][jt] = (f32x4)0.f;

#pragma unroll
        for (int it = 0; it < 4; ++it) {
            bf16x8 kf[2];
#pragma unroll
            for (int ks = 0; ks < 2; ++ks)
                kf[ks] = *(const bf16x8*)&Ks[(it * 16 + lo) * 64 +
                                             (((ks * 4 + hi) ^ (lo & 7)) * 8)];
#pragma unroll
            for (int jt = 0; jt < 2; ++jt)
#pragma unroll
                for (int ks = 0; ks < 2; ++ks)
                    accS[it][jt] = __builtin_amdgcn_mfma_f32_16x16x32_bf16(
                        kf[ks], qfrag[jt][ks], accS[it][jt], 0, 0, 0);
        }

        // ---- p = exp(s); pack 4 consecutive k as 2 u32; one b64 write ----
#pragma unroll
        for (int it = 0; it < 4; ++it)
#pragma unroll
            for (int jt = 0; jt < 2; ++jt) {
                float p0 = __expf(accS[it][jt][0]);
                float p1 = __expf(accS[it][jt][1]);
                float p2 = __expf(accS[it][jt][2]);
                float p3 = __expf(accS[it][jt][3]);
                l_part[jt] += (p0 + p1) + (p2 + p3);
                unsigned w0, w1;
                asm("v_cvt_pk_bf16_f32 %0, %1, %2" : "=v"(w0) : "v"(p0), "v"(p1));
                asm("v_cvt_pk_bf16_f32 %0, %1, %2" : "=v"(w1) : "v"(p2), "v"(p3));
                int q = jt * 16 + lo;
                int cch = it * 2 + (hi >> 1);
                int off = q * 64 + ((cch ^ (q & 7)) * 8) + (hi & 1) * 4;
                uint2 t; t.x = w0; t.y = w1;
                *(uint2*)&Ps[w][off] = t;
            }

        // ---- O += P[32 q][64 k] · V^T[64 d][64 k] ----
#pragma unroll
        for (int kk = 0; kk < 2; ++kk) {
            bf16x8 pf[2];
#pragma unroll
            for (int mt = 0; mt < 2; ++mt)
                pf[mt] = *(const bf16x8*)&Ps[w][(mt * 16 + lo) * 64 +
                                               (((kk * 4 + hi) ^ (lo & 7)) * 8)];
#pragma unroll
            for (int nt = 0; nt < 4; ++nt) {
                bf16x8 vf = *(const bf16x8*)&Vs[(nt * 16 + lo) * 64 +
                                                (((kk * 4 + hi) ^ (lo & 7)) * 8)];
#pragma unroll
                for (int mt = 0; mt < 2; ++mt)
                    accO[mt][nt] = __builtin_amdgcn_mfma_f32_16x16x32_bf16(
                        pf[mt], vf, accO[mt][nt], 0, 0, 0);
            }
        }
        __syncthreads();
    }

    // ---- l: sum partials across the 4 hi-groups ----
#pragma unroll
    for (int jt = 0; jt < 2; ++jt) {
        l_part[jt] += __shfl_xor(l_part[jt], 16);
        l_part[jt] += __shfl_xor(l_part[jt], 32);
    }

    // ---- epilogue: gate, normalize, store ----
#pragma unroll
    for (int mt = 0; mt < 2; ++mt)
#pragma unroll
        for (int r = 0; r < 4; ++r) {
            float lq = __shfl(l_part[mt], hi * 4 + r);   // lane lo == hi*4+r holds l(q)
            int grow = b * SEQ + qb + mt * 16 + hi * 4 + r;
            float g = bf2f(QKV[(long)grow * 1544 + 512 + h]);
            g = 1.f / (1.f + __expf(-g));
            float sc = g / lq;
#pragma unroll
            for (int nt = 0; nt < 4; ++nt)
                AO[(long)grow * 512 + h * 64 + nt * 16 + lo] = f2bf(accO[mt][nt][r] * sc);
        }
}

// pos_out = out @ hp_w + hp_b (bf16 in, fp32 out)
__global__ __launch_bounds__(256) void posout_kernel(
    const ushort_t* __restrict__ outb, const float* __restrict__ hpw,
    const float* __restrict__ hpb, float* __restrict__ po)
{
    const int lane = threadIdx.x & 63;
    const long row = (long)blockIdx.x * 4 + (threadIdx.x >> 6);
    float p0 = 0.f, p1 = 0.f, p2 = 0.f;
#pragma unroll
    for (int it = 0; it < 8; ++it) {
        int k = it * 64 + lane;
        float x = bf2f(outb[row * 512 + k]);
        p0 = fmaf(x, hpw[k * 3 + 0], p0);
        p1 = fmaf(x, hpw[k * 3 + 1], p1);
        p2 = fmaf(x, hpw[k * 3 + 2], p2);
    }
#pragma unroll
    for (int o = 32; o >= 1; o >>= 1) {
        p0 += __shfl_xor(p0, o);
        p1 += __shfl_xor(p1, o);
        p2 += __shfl_xor(p2, o);
    }
    if (lane == 0) {
        po[row * 3 + 0] = p0 + hpb[0];
        po[row * 3 + 1] = p1 + hpb[1];
        po[row * 3 + 2] = p2 + hpb[2];
    }
}

// ---------------------------------------------------------------------------
extern "C" void kernel_launch(void* const* d_in, const int* in_sizes, int n_in,
                              void* d_out, int out_size, void* d_ws, size_t ws_size,
                              hipStream_t stream)
{
    const float* expr    = (const float*)d_in[0];
    const float* dtime   = (const float*)d_in[1];
    const float* posf    = (const float*)d_in[2];
    const float* pos_w1  = (const float*)d_in[3];
    const float* pos_b1  = (const float*)d_in[4];
    const float* pos_w2  = (const float*)d_in[5];
    const float* pos_b2  = (const float*)d_in[6];
    const float* expr_w1 = (const float*)d_in[7];
    const float* expr_b1 = (const float*)d_in[8];
    const float* expr_w2 = (const float*)d_in[9];
    const float* expr_b2 = (const float*)d_in[10];
    const float* yy_w    = (const float*)d_in[11];
    const float* yy_b    = (const float*)d_in[12];
    const float* cat_w   = (const float*)d_in[13];
    const float* cat_b   = (const float*)d_in[14];
    const float* q_w     = (const float*)d_in[15];
    const float* q_b     = (const float*)d_in[16];
    const float* k_w     = (const float*)d_in[17];
    const float* k_b     = (const float*)d_in[18];
    const float* v_w     = (const float*)d_in[19];
    const float* v_b     = (const float*)d_in[20];
    const float* o_w     = (const float*)d_in[21];
    const float* o_b     = (const float*)d_in[22];
    const float* qn_w    = (const float*)d_in[23];
    const float* kn_w    = (const float*)d_in[24];
    const float* hp_w    = (const float*)d_in[25];
    const float* hp_b    = (const float*)d_in[26];
    const float* he_w    = (const float*)d_in[27];
    const float* he_b    = (const float*)d_in[28];
    (void)in_sizes; (void)n_in; (void)out_size; (void)ws_size;

    ushort_t* wsb    = (ushort_t*)d_ws;
    ushort_t* expr_bf = wsb + U_EXPR;
    ushort_t* te1_bf  = wsb + U_TE1;
    ushort_t* cat_bf  = wsb + U_CAT;
    ushort_t* h_bf    = wsb + U_H;
    ushort_t* qkv_bf  = wsb + U_QKV;
    ushort_t* qn_bf   = wsb + U_QN;
    ushort_t* kn_bf   = wsb + U_KN;
    ushort_t* vt_bf   = wsb + U_VT;
    ushort_t* ao_bf   = wsb + U_AO;
    ushort_t* out_bf  = wsb + U_OUT;
    ushort_t* w1t     = wsb + U_W1T;
    ushort_t* w2t     = wsb + U_W2T;
    ushort_t* cat_wt  = wsb + U_CATWT;
    ushort_t* qkv_wt  = wsb + U_QKVWT;
    ushort_t* o_wt    = wsb + U_OWT;
    ushort_t* he_wt   = wsb + U_HEWT;
    float* tdt        = (float*)(wsb + U_F32);
    float* qkv_bias   = tdt + 512;
    float* dout       = (float*)d_out;

    const dim3 blk(256);
    const dim3 blk512(512);

    // --- prep: conversions / transposes ---
    f32_to_bf16_kernel<<<dim3(2048), blk, 0, stream>>>(expr, expr_bf);

    WtTable tab;
    tab.s[0] = { expr_w1, w1t,              512,  64, 8,   0 };  // 8 tiles
    tab.s[1] = { expr_w2, w2t,               64, 512, 1,   8 };  // 8
    tab.s[2] = { cat_w,   cat_wt,           768, 512, 12, 16 };  // 96
    tab.s[3] = { q_w,     qkv_wt,           512, 520, 8, 112 };  // 72
    tab.s[4] = { k_w,     qkv_wt + 520*512, 512, 512, 8, 184 };  // 64
    tab.s[5] = { v_w,     qkv_wt + 1032*512,512, 512, 8, 248 };  // 64
    tab.s[6] = { o_w,     o_wt,             512, 512, 8, 312 };  // 64
    tab.s[7] = { he_w,    he_wt,            512, 512, 8, 376 };  // 64 -> 440
    wt_transpose<<<dim3(440), blk, 0, stream>>>(tab);
    gather_bias<<<dim3(7), blk, 0, stream>>>(q_b, k_b, v_b, qkv_bias);

    // --- pipeline ---
    hgemm<1, 1><<<dim3(1, 64), blk512, 0, stream>>>(expr_bf, 512, w1t, 512,
                                                    expr_b1, te1_bf, 64, 64, 512);
    hgemm<0, 1><<<dim3(4, 64), blk512, 0, stream>>>(te1_bf, 64, w2t, 64,
                                                    expr_b2, cat_bf, 768, 512, 64);
    posmlp_kernel<<<dim3(64), dim3(128), 0, stream>>>(posf, pos_w1, pos_b1,
                                                      pos_w2, pos_b2, cat_bf);
    tdt_kernel<<<dim3(1), dim3(512), 0, stream>>>(dtime, yy_w, yy_b, tdt,
                                                  dout + DOUT_TDT);
    cattime_kernel<<<dim3(4096), blk, 0, stream>>>(tdt, cat_bf);
    hgemm<0, 1><<<dim3(4, 64), blk512, 0, stream>>>(cat_bf, 768, cat_wt, 768,
                                                    cat_b, h_bf, 512, 512, 768);
    hgemm<0, 1><<<dim3(13, 64), blk512, 0, stream>>>(h_bf, 512, qkv_wt, 512,
                                                     qkv_bias, qkv_bf, 1544, 1544, 512);
    rms_bf16_kernel<<<dim3(16384), blk, 0, stream>>>(qkv_bf, 1544, qn_bf, qn_w, 0.125f);
    rms_bf16_kernel<<<dim3(16384), blk, 0, stream>>>(qkv_bf + 520, 1544, kn_bf, kn_w, 1.0f);
    vt_kernel<<<dim3(32, 32), blk, 0, stream>>>(qkv_bf + 1032, 1544, vt_bf);
    flash_attn_mfma<<<dim3(32, 16), blk, 0, stream>>>(qn_bf, kn_bf, vt_bf, qkv_bf, ao_bf);
    hgemm<0, 1><<<dim3(4, 64), blk512, 0, stream>>>(ao_bf, 512, o_wt, 512,
                                                    o_b, out_bf, 512, 512, 512);
    hgemm<0, 0><<<dim3(4, 64), blk512, 0, stream>>>(out_bf, 512, he_wt, 512,
                                                    he_b, dout + DOUT_EXPR, 512, 512, 512);
    posout_kernel<<<dim3(2048), blk, 0, stream>>>(out_bf, hp_w, hp_b,
                                                  dout + DOUT_POS);
}

// Round 5
// 264.569 us; speedup vs baseline: 6.6698x; 1.0329x over previous
//
#include <hip/hip_runtime.h>
#include <math.h>

// Problem constants
#define SEQ   2048
#define NROWS 8192   // B*N

typedef unsigned short ushort_t;
typedef __attribute__((ext_vector_type(8))) short bf16x8;
typedef __attribute__((ext_vector_type(4))) float f32x4;

// Workspace offsets (ushort units)
#define U_EXPR   0ull            // 8192*512 bf16
#define U_TE1    4194304ull      // 8192*64
#define U_CAT    4718592ull      // 8192*768
#define U_H      11010048ull     // 8192*512
#define U_QKV    15204352ull     // 8192*1544 (q 0-519 | k 520-1031 | v 1032-1543)
#define U_QN     27852800ull     // 8192*512
#define U_KN     32047104ull     // 8192*512
#define U_VT     36241408ull     // 32*64*2048
#define U_AO     40435712ull     // 8192*512
#define U_OUT    44630016ull     // 8192*512
#define U_W1T    48824320ull     // 64*512
#define U_W2T    48857088ull     // 512*64
#define U_CATWT  48889856ull     // 512*768
#define U_QKVWT  49283072ull     // 1544*512
#define U_OWT    50073600ull     // 512*512
#define U_HEWT   50335744ull     // 512*512
#define U_F32    50597888ull     // fp32 region: tdt[512], qkv_bias[1544]

// d_out offsets (floats): (expr_out, pos_out, tdt)
#define DOUT_EXPR 0ull
#define DOUT_POS  4194304ull
#define DOUT_TDT  4218880ull

#define LOG2E 1.44269504088896340736f

static __device__ __forceinline__ ushort_t f2bf(float f) {
    union { float f; unsigned int u; } v; v.f = f;
    unsigned int r = (v.u + 0x7fffu + ((v.u >> 16) & 1u)) >> 16;
    return (ushort_t)r;
}
static __device__ __forceinline__ float bf2f(ushort_t u) {
    union { unsigned int u; float f; } v; v.u = ((unsigned int)u) << 16;
    return v.f;
}

// async global->LDS, 16B per lane; LDS dest = wave-uniform base + lane*16
static __device__ __forceinline__ void gload16(const void* g, void* l) {
    __builtin_amdgcn_global_load_lds(
        (const __attribute__((address_space(1))) void*)g,
        (__attribute__((address_space(3))) void*)l,
        16, 0, 0);
}

// ---------------------------------------------------------------------------
// fp32 -> bf16 bulk convert (n multiple of 2048)
// ---------------------------------------------------------------------------
__global__ __launch_bounds__(256) void f32_to_bf16_kernel(
    const float* __restrict__ src, ushort_t* __restrict__ dst)
{
    long i = ((long)blockIdx.x * 256 + threadIdx.x) * 8;
    float4 a = *(const float4*)&src[i];
    float4 b = *(const float4*)&src[i + 4];
    bf16x8 p;
    p[0] = (short)f2bf(a.x); p[1] = (short)f2bf(a.y);
    p[2] = (short)f2bf(a.z); p[3] = (short)f2bf(a.w);
    p[4] = (short)f2bf(b.x); p[5] = (short)f2bf(b.y);
    p[6] = (short)f2bf(b.z); p[7] = (short)f2bf(b.w);
    *(bf16x8*)&dst[i] = p;
}

// ---------------------------------------------------------------------------
// Weight transpose+convert + qkv bias gather. Blocks [0,440): 64x64 tiles,
// blocks [440,447): bias copy.
// ---------------------------------------------------------------------------
struct WtSeg { const float* src; ushort_t* dst; int K, N, tK, tile0; };
struct WtTable { WtSeg s[8]; };

__global__ __launch_bounds__(256) void wt_transpose(
    WtTable tab, const float* __restrict__ qb, const float* __restrict__ kb,
    const float* __restrict__ vb, float* __restrict__ bias_dst)
{
    const int bid = blockIdx.x;
    const int tid = threadIdx.x;
    if (bid >= 440) {
        int t = (bid - 440) * 256 + tid;
        if (t < 520) bias_dst[t] = qb[t];
        else if (t < 1032) bias_dst[t] = kb[t - 520];
        else if (t < 1544) bias_dst[t] = vb[t - 1032];
        return;
    }
    __shared__ float t[64][65];
    int si = 0;
#pragma unroll
    for (int i = 1; i < 8; ++i)
        if (bid >= tab.s[i].tile0) si = i;
    const WtSeg sg = tab.s[si];
    const int local = bid - sg.tile0;
    const int k0 = (local % sg.tK) * 64;
    const int n0 = (local / sg.tK) * 64;
#pragma unroll
    for (int i = 0; i < 16; ++i) {
        int e = tid + i * 256;
        int r = e >> 6, c = e & 63;
        float v = 0.f;
        if (k0 + r < sg.K && n0 + c < sg.N)
            v = sg.src[(long)(k0 + r) * sg.N + n0 + c];
        t[r][c] = v;
    }
    __syncthreads();
#pragma unroll
    for (int i = 0; i < 16; ++i) {
        int e = tid + i * 256;
        int rn = e >> 6, ck = e & 63;
        if (n0 + rn < sg.N && k0 + ck < sg.K)
            sg.dst[(long)(n0 + rn) * sg.K + k0 + ck] = f2bf(t[ck][rn]);
    }
}

// ---------------------------------------------------------------------------
// bf16 MFMA GEMM: C[M x N] = A[M x K] @ Wt^T + bias; tile 128x128, BK=64,
// 512 threads = 8 waves (2m x 4n), wave tile 64x32.
// Staging via global_load_lds width=16: LINEAR LDS dest, chunk-swizzle applied
// to the per-lane GLOBAL source (rule 21 / m173); reads swizzle identically.
// Tail B-rows (n0+r >= N) read in-bounds d_ws garbage; their acc columns are
// per-lane independent and masked by the col<N store guard.
// ---------------------------------------------------------------------------
template <int RELU, int OUT_BF16>
__global__ __launch_bounds__(512) void hgemm(
    const ushort_t* __restrict__ A, int lda,
    const ushort_t* __restrict__ Wt, int ldw,
    const float* __restrict__ bias,
    void* __restrict__ Cv, int ldc,
    int N, int K)
{
    __shared__ __align__(16) ushort_t As[128 * 64];
    __shared__ __align__(16) ushort_t Bs[128 * 64];

    const int tid = threadIdx.x;
    const int lane = tid & 63, w = tid >> 6;
    const int lo = lane & 15, hi = lane >> 4;
    const int wm = w >> 2, wn = w & 3;
    const long m0 = (long)blockIdx.y * 128;
    const int n0 = blockIdx.x * 128;

    f32x4 acc[4][2];
#pragma unroll
    for (int mt = 0; mt < 4; ++mt)
#pragma unroll
        for (int nt = 0; nt < 2; ++nt) acc[mt][nt] = (f32x4)0.f;

    for (int kt = 0; kt < K; kt += 64) {
#pragma unroll
        for (int i = 0; i < 2; ++i) {
            int c = w * 128 + i * 64 + lane;      // chunk id 0..1023
            int r = c >> 3, ch = c & 7;
            int sch = ch ^ (r & 7);               // inverse-swizzled source chunk
            gload16(&A[(m0 + r) * (long)lda + kt + sch * 8],
                    &As[(w * 128 + i * 64) * 8]);
            gload16(&Wt[(long)(n0 + r) * ldw + kt + sch * 8],
                    &Bs[(w * 128 + i * 64) * 8]);
        }
        __syncthreads();

#pragma unroll
        for (int ks = 0; ks < 2; ++ks) {
            bf16x8 af[4], bfr[2];
#pragma unroll
            for (int mt = 0; mt < 4; ++mt) {
                int m = wm * 64 + mt * 16 + lo;
                af[mt] = *(const bf16x8*)&As[m * 64 + (((ks * 4 + hi) ^ (lo & 7)) * 8)];
            }
#pragma unroll
            for (int nt = 0; nt < 2; ++nt) {
                int n = wn * 32 + nt * 16 + lo;
                bfr[nt] = *(const bf16x8*)&Bs[n * 64 + (((ks * 4 + hi) ^ (lo & 7)) * 8)];
            }
#pragma unroll
            for (int mt = 0; mt < 4; ++mt)
#pragma unroll
                for (int nt = 0; nt < 2; ++nt)
                    acc[mt][nt] = __builtin_amdgcn_mfma_f32_16x16x32_bf16(
                        af[mt], bfr[nt], acc[mt][nt], 0, 0, 0);
        }
        __syncthreads();
    }

#pragma unroll
    for (int mt = 0; mt < 4; ++mt)
#pragma unroll
        for (int nt = 0; nt < 2; ++nt) {
            int col = n0 + wn * 32 + nt * 16 + lo;
            if (col < N) {
                float bv = bias[col];
#pragma unroll
                for (int r = 0; r < 4; ++r) {
                    long row = m0 + wm * 64 + mt * 16 + hi * 4 + r;
                    float v = acc[mt][nt][r] + bv;
                    if (RELU) v = fmaxf(v, 0.f);
                    if (OUT_BF16) ((ushort_t*)Cv)[row * (long)ldc + col] = f2bf(v);
                    else          ((float*)Cv)[row * (long)ldc + col] = v;
                }
            }
        }
}

// ---------------------------------------------------------------------------
// Position MLP -> cat_bf[:, 640:768]; also broadcasts tdt -> cat_bf[:, 512:640]
// (block = 128 rows, all in one batch: b = blockIdx.x >> 4)
// ---------------------------------------------------------------------------
__global__ __launch_bounds__(128) void posmlp_kernel(
    const float* __restrict__ pos,
    const float* __restrict__ w1, const float* __restrict__ b1,
    const float* __restrict__ w2, const float* __restrict__ b2,
    const float* __restrict__ tdt,
    ushort_t* __restrict__ cat)
{
    __shared__ __align__(16) float w1s[256];
    __shared__ __align__(16) float b1s[64];
    __shared__ __align__(16) float w2t[128 * 64];
    __shared__ __align__(16) float b2s[128];
    __shared__ __align__(16) ushort_t tdt_s[128];

    const int tid = threadIdx.x;
    const int b = (int)(blockIdx.x >> 4);
    for (int i = tid; i < 256; i += 128) w1s[i] = w1[i];
    if (tid < 64) b1s[tid] = b1[tid];
    b2s[tid] = b2[tid];
    tdt_s[tid] = f2bf(tdt[b * 128 + tid]);
    for (int i = tid; i < 8192; i += 128) {
        int k = i >> 7, o = i & 127;
        w2t[o * 64 + k] = w2[i];
    }
    __syncthreads();

    const long r = (long)blockIdx.x * 128 + tid;
    float px = pos[r * 3 + 0], py = pos[r * 3 + 1], pz = pos[r * 3 + 2];
    float nrm = sqrtf(px * px + py * py + pz * pz);
    float inv = 1.f / (nrm + 1e-7f);
    float pf0 = px * inv, pf1 = py * inv, pf2 = pz * inv, pf3 = nrm;

    float h1[64];
#pragma unroll
    for (int o = 0; o < 64; ++o) {
        float a = b1s[o];
        a = fmaf(pf0, w1s[o], a);
        a = fmaf(pf1, w1s[64 + o], a);
        a = fmaf(pf2, w1s[128 + o], a);
        a = fmaf(pf3, w1s[192 + o], a);
        h1[o] = fmaxf(a, 0.f);
    }
    ushort_t* dst = &cat[r * 768 + 640];
    for (int o = 0; o < 128; ++o) {
        float s = b2s[o];
#pragma unroll
        for (int i4 = 0; i4 < 16; ++i4) {
            float4 wv = *(const float4*)&w2t[o * 64 + i4 * 4];
            s = fmaf(h1[i4 * 4 + 0], wv.x, s);
            s = fmaf(h1[i4 * 4 + 1], wv.y, s);
            s = fmaf(h1[i4 * 4 + 2], wv.z, s);
            s = fmaf(h1[i4 * 4 + 3], wv.w, s);
        }
        dst[o] = f2bf(s);
    }
    // time broadcast
    ushort_t* tdst = &cat[r * 768 + 512];
#pragma unroll
    for (int i = 0; i < 16; ++i)
        *(bf16x8*)&tdst[i * 8] = *(const bf16x8*)&tdt_s[i * 8];
}

// tdt = diffusion_time @ yy_w + yy_b (fp32, exact)
__global__ __launch_bounds__(512) void tdt_kernel(
    const float* __restrict__ dt, const float* __restrict__ yyw,
    const float* __restrict__ yyb, float* __restrict__ tdt_ws,
    float* __restrict__ out_tail)
{
    const int t = threadIdx.x;
    const int b = t >> 7, o = t & 127;
    float s = yyb[o];
    for (int k = 0; k < 128; ++k) s = fmaf(dt[b * 128 + k], yyw[k * 128 + o], s);
    tdt_ws[t] = s;
    out_tail[t] = s;
}

// Fused Q+K rmsnorm over HD=64, bf16 in/out. Q half folds 0.125*log2(e).
// grid 32768: pid < 65536 -> Q, else K.
__global__ __launch_bounds__(256) void rms2_kernel(
    const ushort_t* __restrict__ qkv,
    ushort_t* __restrict__ qn, ushort_t* __restrict__ kn,
    const float* __restrict__ qw, const float* __restrict__ kw)
{
    const int lane = threadIdx.x & 63;
    int p = blockIdx.x * 4 + (threadIdx.x >> 6);
    const int isK = p >> 16;            // 0 for Q, 1 for K
    p &= 0xffff;
    const long row = p >> 3;
    const int h = p & 7;
    const float* wv = isK ? kw : qw;
    ushort_t* out = isK ? kn : qn;
    const float scale = isK ? 1.0f : 0.125f * LOG2E;
    float x = bf2f(qkv[row * 1544 + isK * 520 + h * 64 + lane]);
    float ss = x * x;
#pragma unroll
    for (int o = 32; o >= 1; o >>= 1) ss += __shfl_xor(ss, o);
    float r = rsqrtf(ss * (1.f / 64.f) + 1e-6f);
    out[row * 512 + h * 64 + lane] = f2bf(wv[lane] * x * r * scale);
}

// Vt[bh][d][n] from bf16 V rows (stride ldv); grid (32, 32), block 256
__global__ __launch_bounds__(256) void vt_kernel(
    const ushort_t* __restrict__ V, int ldv, ushort_t* __restrict__ Vt)
{
    __shared__ ushort_t t[64][72];
    const int bh = blockIdx.x, b = bh >> 3, h = bh & 7;
    const int n0 = blockIdx.y * 64;
    const int tid = threadIdx.x;
#pragma unroll
    for (int i = 0; i < 2; ++i) {
        int c = tid + i * 256;
        int r = c >> 3, ch = c & 7;
        *(bf16x8*)&t[r][ch * 8] =
            *(const bf16x8*)&V[(long)(b * SEQ + n0 + r) * ldv + h * 64 + ch * 8];
    }
    __syncthreads();
    const int d = tid >> 2;
#pragma unroll
    for (int i = 0; i < 2; ++i) {
        int cc = (tid & 3) * 2 + i;
        bf16x8 pk;
#pragma unroll
        for (int j = 0; j < 8; ++j) pk[j] = (short)t[cc * 8 + j][d];
        *(bf16x8*)&Vt[((long)(bh * 64 + d)) * SEQ + n0 + cc * 8] = pk;
    }
}

// ---------------------------------------------------------------------------
// Flash attention, bf16 MFMA 16x16x32, fixed-shift softmax in exp2 domain
// (Q pre-scaled by 0.125*log2e in rms2; |s2| <= 11.55 so exp2 safe).
// Swapped QK^T; packed P writes; K/V register prefetch.
// grid (32 bh, 16), block 256 (4 waves x 32 q rows). K-tile 64.
// ---------------------------------------------------------------------------
__global__ __launch_bounds__(256) void flash_attn_mfma(
    const ushort_t* __restrict__ Qn, const ushort_t* __restrict__ Kn,
    const ushort_t* __restrict__ Vt, const ushort_t* __restrict__ QKV,
    ushort_t* __restrict__ AO)
{
    __shared__ __align__(16) ushort_t Ks[64 * 64];      // [k_row][d], chunk-swizzled
    __shared__ __align__(16) ushort_t Vs[64 * 64];      // [d][n],    chunk-swizzled
    __shared__ __align__(16) ushort_t Ps[4][32 * 64];   // per-wave [q][k], swizzled

    const int tid = threadIdx.x;
    const int lane = tid & 63;
    const int w = tid >> 6;
    const int lo = lane & 15, hi = lane >> 4;
    const int bh = blockIdx.x, b = bh >> 3, h = bh & 7;
    const int qb = blockIdx.y * 128 + w * 32;

    bf16x8 qfrag[2][2];
#pragma unroll
    for (int jt = 0; jt < 2; ++jt)
#pragma unroll
        for (int ks = 0; ks < 2; ++ks)
            qfrag[jt][ks] = *(const bf16x8*)&Qn[(b * SEQ + qb + jt * 16 + lo) * 512 +
                                                h * 64 + ks * 32 + hi * 8];

    f32x4 accO[2][4];
#pragma unroll
    for (int mt = 0; mt < 2; ++mt)
#pragma unroll
        for (int nt = 0; nt < 4; ++nt) accO[mt][nt] = (f32x4)0.f;
    float l_part[2] = {0.f, 0.f};

    const int sr0 = tid >> 3, sc0 = tid & 7;
    const int sr1 = (tid + 256) >> 3, sc1 = tid & 7;

    bf16x8 kreg0, kreg1, vreg0, vreg1;
    {
        kreg0 = *(const bf16x8*)&Kn[(b * SEQ + sr0) * 512 + h * 64 + sc0 * 8];
        vreg0 = *(const bf16x8*)&Vt[((long)(bh * 64 + sr0)) * SEQ + sc0 * 8];
        kreg1 = *(const bf16x8*)&Kn[(b * SEQ + sr1) * 512 + h * 64 + sc1 * 8];
        vreg1 = *(const bf16x8*)&Vt[((long)(bh * 64 + sr1)) * SEQ + sc1 * 8];
    }

    for (int kt = 0; kt < 32; ++kt) {
        *(bf16x8*)&Ks[sr0 * 64 + ((sc0 ^ (sr0 & 7)) * 8)] = kreg0;
        *(bf16x8*)&Vs[sr0 * 64 + ((sc0 ^ (sr0 & 7)) * 8)] = vreg0;
        *(bf16x8*)&Ks[sr1 * 64 + ((sc1 ^ (sr1 & 7)) * 8)] = kreg1;
        *(bf16x8*)&Vs[sr1 * 64 + ((sc1 ^ (sr1 & 7)) * 8)] = vreg1;
        __syncthreads();

        if (kt + 1 < 32) {
            int nk = (kt + 1) * 64;
            kreg0 = *(const bf16x8*)&Kn[(b * SEQ + nk + sr0) * 512 + h * 64 + sc0 * 8];
            vreg0 = *(const bf16x8*)&Vt[((long)(bh * 64 + sr0)) * SEQ + nk + sc0 * 8];
            kreg1 = *(const bf16x8*)&Kn[(b * SEQ + nk + sr1) * 512 + h * 64 + sc1 * 8];
            vreg1 = *(const bf16x8*)&Vt[((long)(bh * 64 + sr1)) * SEQ + nk + sc1 * 8];
        }

        // ---- S^T = K * Q^T ----
        f32x4 accS[4][2];
#pragma unroll
        for (int it = 0; it < 4; ++it)
#pragma unroll
            for (int jt = 0; jt < 2; ++jt) accS[it][jt] = (f32x4)0.f;

#pragma unroll
        for (int it = 0; it < 4; ++it) {
            bf16x8 kf[2];
#pragma unroll
            for (int ks = 0; ks < 2; ++ks)
                kf[ks] = *(const bf16x8*)&Ks[(it * 16 + lo) * 64 +
                                             (((ks * 4 + hi) ^ (lo & 7)) * 8)];
#pragma unroll
            for (int jt = 0; jt < 2; ++jt)
#pragma unroll
                for (int ks = 0; ks < 2; ++ks)
                    accS[it][jt] = __builtin_amdgcn_mfma_f32_16x16x32_bf16(
                        kf[ks], qfrag[jt][ks], accS[it][jt], 0, 0, 0);
        }

        // ---- p = exp2(s'); pack; b64 write ----
#pragma unroll
        for (int it = 0; it < 4; ++it)
#pragma unroll
            for (int jt = 0; jt < 2; ++jt) {
                float p0 = exp2f(accS[it][jt][0]);
                float p1 = exp2f(accS[it][jt][1]);
                float p2 = exp2f(accS[it][jt][2]);
                float p3 = exp2f(accS[it][jt][3]);
                l_part[jt] += (p0 + p1) + (p2 + p3);
                unsigned w0, w1;
                asm("v_cvt_pk_bf16_f32 %0, %1, %2" : "=v"(w0) : "v"(p0), "v"(p1));
                asm("v_cvt_pk_bf16_f32 %0, %1, %2" : "=v"(w1) : "v"(p2), "v"(p3));
                int q = jt * 16 + lo;
                int cch = it * 2 + (hi >> 1);
                int off = q * 64 + ((cch ^ (q & 7)) * 8) + (hi & 1) * 4;
                uint2 t; t.x = w0; t.y = w1;
                *(uint2*)&Ps[w][off] = t;
            }

        // ---- O += P * V^T ----
#pragma unroll
        for (int kk = 0; kk < 2; ++kk) {
            bf16x8 pf[2];
#pragma unroll
            for (int mt = 0; mt < 2; ++mt)
                pf[mt] = *(const bf16x8*)&Ps[w][(mt * 16 + lo) * 64 +
                                               (((kk * 4 + hi) ^ (lo & 7)) * 8)];
#pragma unroll
            for (int nt = 0; nt < 4; ++nt) {
                bf16x8 vf = *(const bf16x8*)&Vs[(nt * 16 + lo) * 64 +
                                                (((kk * 4 + hi) ^ (lo & 7)) * 8)];
#pragma unroll
                for (int mt = 0; mt < 2; ++mt)
                    accO[mt][nt] = __builtin_amdgcn_mfma_f32_16x16x32_bf16(
                        pf[mt], vf, accO[mt][nt], 0, 0, 0);
            }
        }
        __syncthreads();
    }

#pragma unroll
    for (int jt = 0; jt < 2; ++jt) {
        l_part[jt] += __shfl_xor(l_part[jt], 16);
        l_part[jt] += __shfl_xor(l_part[jt], 32);
    }

#pragma unroll
    for (int mt = 0; mt < 2; ++mt)
#pragma unroll
        for (int r = 0; r < 4; ++r) {
            float lq = __shfl(l_part[mt], hi * 4 + r);
            int grow = b * SEQ + qb + mt * 16 + hi * 4 + r;
            float g = bf2f(QKV[(long)grow * 1544 + 512 + h]);
            g = 1.f / (1.f + __expf(-g));
            float sc = g / lq;
#pragma unroll
            for (int nt = 0; nt < 4; ++nt)
                AO[(long)grow * 512 + h * 64 + nt * 16 + lo] = f2bf(accO[mt][nt][r] * sc);
        }
}

// pos_out = out @ hp_w + hp_b (bf16 in, fp32 out)
__global__ __launch_bounds__(256) void posout_kernel(
    const ushort_t* __restrict__ outb, const float* __restrict__ hpw,
    const float* __restrict__ hpb, float* __restrict__ po)
{
    const int lane = threadIdx.x & 63;
    const long row = (long)blockIdx.x * 4 + (threadIdx.x >> 6);
    float p0 = 0.f, p1 = 0.f, p2 = 0.f;
#pragma unroll
    for (int it = 0; it < 8; ++it) {
        int k = it * 64 + lane;
        float x = bf2f(outb[row * 512 + k]);
        p0 = fmaf(x, hpw[k * 3 + 0], p0);
        p1 = fmaf(x, hpw[k * 3 + 1], p1);
        p2 = fmaf(x, hpw[k * 3 + 2], p2);
    }
#pragma unroll
    for (int o = 32; o >= 1; o >>= 1) {
        p0 += __shfl_xor(p0, o);
        p1 += __shfl_xor(p1, o);
        p2 += __shfl_xor(p2, o);
    }
    if (lane == 0) {
        po[row * 3 + 0] = p0 + hpb[0];
        po[row * 3 + 1] = p1 + hpb[1];
        po[row * 3 + 2] = p2 + hpb[2];
    }
}

// ---------------------------------------------------------------------------
extern "C" void kernel_launch(void* const* d_in, const int* in_sizes, int n_in,
                              void* d_out, int out_size, void* d_ws, size_t ws_size,
                              hipStream_t stream)
{
    const float* expr    = (const float*)d_in[0];
    const float* dtime   = (const float*)d_in[1];
    const float* posf    = (const float*)d_in[2];
    const float* pos_w1  = (const float*)d_in[3];
    const float* pos_b1  = (const float*)d_in[4];
    const float* pos_w2  = (const float*)d_in[5];
    const float* pos_b2  = (const float*)d_in[6];
    const float* expr_w1 = (const float*)d_in[7];
    const float* expr_b1 = (const float*)d_in[8];
    const float* expr_w2 = (const float*)d_in[9];
    const float* expr_b2 = (const float*)d_in[10];
    const float* yy_w    = (const float*)d_in[11];
    const float* yy_b    = (const float*)d_in[12];
    const float* cat_w   = (const float*)d_in[13];
    const float* cat_b   = (const float*)d_in[14];
    const float* q_w     = (const float*)d_in[15];
    const float* q_b     = (const float*)d_in[16];
    const float* k_w     = (const float*)d_in[17];
    const float* k_b     = (const float*)d_in[18];
    const float* v_w     = (const float*)d_in[19];
    const float* v_b     = (const float*)d_in[20];
    const float* o_w     = (const float*)d_in[21];
    const float* o_b     = (const float*)d_in[22];
    const float* qn_w    = (const float*)d_in[23];
    const float* kn_w    = (const float*)d_in[24];
    const float* hp_w    = (const float*)d_in[25];
    const float* hp_b    = (const float*)d_in[26];
    const float* he_w    = (const float*)d_in[27];
    const float* he_b    = (const float*)d_in[28];
    (void)in_sizes; (void)n_in; (void)out_size; (void)ws_size;

    ushort_t* wsb    = (ushort_t*)d_ws;
    ushort_t* expr_bf = wsb + U_EXPR;
    ushort_t* te1_bf  = wsb + U_TE1;
    ushort_t* cat_bf  = wsb + U_CAT;
    ushort_t* h_bf    = wsb + U_H;
    ushort_t* qkv_bf  = wsb + U_QKV;
    ushort_t* qn_bf   = wsb + U_QN;
    ushort_t* kn_bf   = wsb + U_KN;
    ushort_t* vt_bf   = wsb + U_VT;
    ushort_t* ao_bf   = wsb + U_AO;
    ushort_t* out_bf  = wsb + U_OUT;
    ushort_t* w1t     = wsb + U_W1T;
    ushort_t* w2t     = wsb + U_W2T;
    ushort_t* cat_wt  = wsb + U_CATWT;
    ushort_t* qkv_wt  = wsb + U_QKVWT;
    ushort_t* o_wt    = wsb + U_OWT;
    ushort_t* he_wt   = wsb + U_HEWT;
    float* tdt        = (float*)(wsb + U_F32);
    float* qkv_bias   = tdt + 512;
    float* dout       = (float*)d_out;

    const dim3 blk(256);
    const dim3 blk512(512);

    // --- prep ---
    f32_to_bf16_kernel<<<dim3(2048), blk, 0, stream>>>(expr, expr_bf);

    WtTable tab;
    tab.s[0] = { expr_w1, w1t,              512,  64, 8,   0 };
    tab.s[1] = { expr_w2, w2t,               64, 512, 1,   8 };
    tab.s[2] = { cat_w,   cat_wt,           768, 512, 12, 16 };
    tab.s[3] = { q_w,     qkv_wt,           512, 520, 8, 112 };
    tab.s[4] = { k_w,     qkv_wt + 520*512, 512, 512, 8, 184 };
    tab.s[5] = { v_w,     qkv_wt + 1032*512,512, 512, 8, 248 };
    tab.s[6] = { o_w,     o_wt,             512, 512, 8, 312 };
    tab.s[7] = { he_w,    he_wt,            512, 512, 8, 376 };
    wt_transpose<<<dim3(447), blk, 0, stream>>>(tab, q_b, k_b, v_b, qkv_bias);

    tdt_kernel<<<dim3(1), dim3(512), 0, stream>>>(dtime, yy_w, yy_b, tdt,
                                                  dout + DOUT_TDT);

    // --- pipeline ---
    hgemm<1, 1><<<dim3(1, 64), blk512, 0, stream>>>(expr_bf, 512, w1t, 512,
                                                    expr_b1, te1_bf, 64, 64, 512);
    hgemm<0, 1><<<dim3(4, 64), blk512, 0, stream>>>(te1_bf, 64, w2t, 64,
                                                    expr_b2, cat_bf, 768, 512, 64);
    posmlp_kernel<<<dim3(64), dim3(128), 0, stream>>>(posf, pos_w1, pos_b1,
                                                      pos_w2, pos_b2, tdt, cat_bf);
    hgemm<0, 1><<<dim3(4, 64), blk512, 0, stream>>>(cat_bf, 768, cat_wt, 768,
                                                    cat_b, h_bf, 512, 512, 768);
    hgemm<0, 1><<<dim3(13, 64), blk512, 0, stream>>>(h_bf, 512, qkv_wt, 512,
                                                     qkv_bias, qkv_bf, 1544, 1544, 512);
    rms2_kernel<<<dim3(32768), blk, 0, stream>>>(qkv_bf, qn_bf, kn_bf, qn_w, kn_w);
    vt_kernel<<<dim3(32, 32), blk, 0, stream>>>(qkv_bf + 1032, 1544, vt_bf);
    flash_attn_mfma<<<dim3(32, 16), blk, 0, stream>>>(qn_bf, kn_bf, vt_bf, qkv_bf, ao_bf);
    hgemm<0, 1><<<dim3(4, 64), blk512, 0, stream>>>(ao_bf, 512, o_wt, 512,
                                                    o_b, out_bf, 512, 512, 512);
    hgemm<0, 0><<<dim3(4, 64), blk512, 0, stream>>>(out_bf, 512, he_wt, 512,
                                                    he_b, dout + DOUT_EXPR, 512, 512, 512);
    posout_kernel<<<dim3(2048), blk, 0, stream>>>(out_bf, hp_w, hp_b,
                                                  dout + DOUT_POS);
}

// Round 7
// 250.275 us; speedup vs baseline: 7.0507x; 1.0571x over previous
//
#include <hip/hip_runtime.h>
#include <math.h>

// Problem constants
#define SEQ   2048
#define NROWS 8192   // B*N

typedef unsigned short ushort_t;
typedef __attribute__((ext_vector_type(8))) short bf16x8;
typedef __attribute__((ext_vector_type(4))) float f32x4;

// Workspace offsets (ushort units)
#define U_EXPR   0ull            // 8192*512
#define U_A192   4194304ull      // 8192*192  ([te1|tp])
#define U_H      5767168ull      // 8192*512
#define U_QKV    9961472ull      // 8192*1544
#define U_QN     22609920ull     // 8192*512
#define U_KN     26804224ull     // 8192*512
#define U_VT     30998528ull     // 32*64*2048
#define U_AO     35192832ull     // 8192*512
#define U_W1T    39387136ull     // 64*512
#define U_W2RAW  39419904ull     // 64*512
#define U_CATWT  39452672ull     // 512*768
#define U_QKVWT  39845888ull     // 1544*512
#define U_OWT    40636416ull     // (free)
#define U_HEWT   40898560ull     // 512*512
#define U_WPRIME 41160704ull     // 512*192
#define U_WOHE   41259008ull     // 512*512
#define U_F32    41521152ull     // fp32 region (8192 floats)
#define U_ORAW   41537536ull     // 512*512 bf16, o_w native layout

// fp32 region layout (float offsets)
#define F_TDT    0
#define F_QKVB   512
#define F_BIASH  2056    // [4][512]
#define F_BIASEO 4104    // [512]
#define F_BIASPO 4616    // [4]
#define F_WHP    4620    // [512][3]

// d_out offsets (floats): (expr_out, pos_out, tdt)
#define DOUT_EXPR 0ull
#define DOUT_POS  4194304ull
#define DOUT_TDT  4218880ull

static __device__ __forceinline__ ushort_t f2bf(float f) {
    union { float f; unsigned int u; } v; v.f = f;
    unsigned int r = (v.u + 0x7fffu + ((v.u >> 16) & 1u)) >> 16;
    return (ushort_t)r;
}
static __device__ __forceinline__ float bf2f(ushort_t u) {
    union { unsigned int u; float f; } v; v.u = ((unsigned int)u) << 16;
    return v.f;
}

// async global->LDS, 16B per lane; LDS dest = wave-uniform base + lane*16
static __device__ __forceinline__ void gload16(const void* g, void* l) {
    __builtin_amdgcn_global_load_lds(
        (const __attribute__((address_space(1))) void*)g,
        (__attribute__((address_space(3))) void*)l,
        16, 0, 0);
}

// ---------------------------------------------------------------------------
// fp32 -> bf16 bulk convert (element count multiple of 2048)
// ---------------------------------------------------------------------------
__global__ __launch_bounds__(256) void f32_to_bf16_kernel(
    const float* __restrict__ src, ushort_t* __restrict__ dst)
{
    long i = ((long)blockIdx.x * 256 + threadIdx.x) * 8;
    float4 a = *(const float4*)&src[i];
    float4 b = *(const float4*)&src[i + 4];
    bf16x8 p;
    p[0] = (short)f2bf(a.x); p[1] = (short)f2bf(a.y);
    p[2] = (short)f2bf(a.z); p[3] = (short)f2bf(a.w);
    p[4] = (short)f2bf(b.x); p[5] = (short)f2bf(b.y);
    p[6] = (short)f2bf(b.z); p[7] = (short)f2bf(b.w);
    *(bf16x8*)&dst[i] = p;
}

// ---------------------------------------------------------------------------
// Weight transpose+convert (6 segments) + qkv bias gather (blocks >= 372)
// ---------------------------------------------------------------------------
struct WtSeg { const float* src; ushort_t* dst; int K, N, tK, tile0; };
struct WtTable { WtSeg s[8]; };

__global__ __launch_bounds__(256) void wt_transpose(
    WtTable tab, const float* __restrict__ qb, const float* __restrict__ kb,
    const float* __restrict__ vb, float* __restrict__ bias_dst)
{
    const int bid = blockIdx.x;
    const int tid = threadIdx.x;
    if (bid >= 372) {
        int t = (bid - 372) * 256 + tid;
        if (t < 520) bias_dst[t] = qb[t];
        else if (t < 1032) bias_dst[t] = kb[t - 520];
        else if (t < 1544) bias_dst[t] = vb[t - 1032];
        return;
    }
    __shared__ float t[64][65];
    int si = 0;
#pragma unroll
    for (int i = 1; i < 8; ++i)
        if (bid >= tab.s[i].tile0) si = i;
    const WtSeg sg = tab.s[si];
    const int local = bid - sg.tile0;
    const int k0 = (local % sg.tK) * 64;
    const int n0 = (local / sg.tK) * 64;
#pragma unroll
    for (int i = 0; i < 16; ++i) {
        int e = tid + i * 256;
        int r = e >> 6, c = e & 63;
        float v = 0.f;
        if (k0 + r < sg.K && n0 + c < sg.N)
            v = sg.src[(long)(k0 + r) * sg.N + n0 + c];
        t[r][c] = v;
    }
    __syncthreads();
#pragma unroll
    for (int i = 0; i < 16; ++i) {
        int e = tid + i * 256;
        int rn = e >> 6, ck = e & 63;
        if (n0 + rn < sg.N && k0 + ck < sg.K)
            sg.dst[(long)(n0 + rn) * sg.K + k0 + ck] = f2bf(t[ck][rn]);
    }
}

// ---------------------------------------------------------------------------
// Bias folding (wave-per-output):
//  wid <  2048 : bias_h[b][n]  = expr_b2.cat_w0[:,n] + tdt[b].cat_w1[:,n] + cat_b[n]
//  wid <  2560 : bias_eo[n]    = o_b.he_w[:,n] + he_b[n]
//  wid <  4096 : whp[k][c]     = o_w[k,:].hp_w[:,c]
//  wid <  4099 : bias_po[c]    = o_b.hp_w[:,c] + hp_b[c]
// ---------------------------------------------------------------------------
__global__ __launch_bounds__(256) void biasfold_kernel(
    const ushort_t* __restrict__ catwt, const ushort_t* __restrict__ hewt,
    const float* __restrict__ expr_b2, const float* __restrict__ tdt,
    const float* __restrict__ cat_b, const float* __restrict__ o_b,
    const float* __restrict__ he_b, const float* __restrict__ o_w,
    const float* __restrict__ hp_w, const float* __restrict__ hp_b,
    float* __restrict__ bias_h, float* __restrict__ bias_eo,
    float* __restrict__ whp, float* __restrict__ bias_po)
{
    const int wid = blockIdx.x * 4 + (threadIdx.x >> 6);
    const int lane = threadIdx.x & 63;
    float s = 0.f;
    if (wid < 2048) {
        int b = wid >> 9, n = wid & 511;
        bf16x8 wv = *(const bf16x8*)&catwt[(long)n * 768 + lane * 8];
        float4 e0 = *(const float4*)&expr_b2[lane * 8];
        float4 e1 = *(const float4*)&expr_b2[lane * 8 + 4];
        s = bf2f((ushort_t)wv[0]) * e0.x + bf2f((ushort_t)wv[1]) * e0.y +
            bf2f((ushort_t)wv[2]) * e0.z + bf2f((ushort_t)wv[3]) * e0.w +
            bf2f((ushort_t)wv[4]) * e1.x + bf2f((ushort_t)wv[5]) * e1.y +
            bf2f((ushort_t)wv[6]) * e1.z + bf2f((ushort_t)wv[7]) * e1.w;
        float2 tt = *(const float2*)&tdt[b * 128 + lane * 2];
        s += bf2f(catwt[(long)n * 768 + 512 + lane * 2]) * tt.x;
        s += bf2f(catwt[(long)n * 768 + 513 + lane * 2]) * tt.y;
#pragma unroll
        for (int o = 32; o >= 1; o >>= 1) s += __shfl_xor(s, o);
        if (lane == 0) bias_h[b * 512 + n] = s + cat_b[n];
    } else if (wid < 2560) {
        int n = wid - 2048;
        bf16x8 wv = *(const bf16x8*)&hewt[(long)n * 512 + lane * 8];
        float4 e0 = *(const float4*)&o_b[lane * 8];
        float4 e1 = *(const float4*)&o_b[lane * 8 + 4];
        s = bf2f((ushort_t)wv[0]) * e0.x + bf2f((ushort_t)wv[1]) * e0.y +
            bf2f((ushort_t)wv[2]) * e0.z + bf2f((ushort_t)wv[3]) * e0.w +
            bf2f((ushort_t)wv[4]) * e1.x + bf2f((ushort_t)wv[5]) * e1.y +
            bf2f((ushort_t)wv[6]) * e1.z + bf2f((ushort_t)wv[7]) * e1.w;
#pragma unroll
        for (int o = 32; o >= 1; o >>= 1) s += __shfl_xor(s, o);
        if (lane == 0) bias_eo[n] = s + he_b[n];
    } else if (wid < 4096) {
        int t = wid - 2560;
        int c = t >> 9, k = t & 511;
#pragma unroll
        for (int i = 0; i < 8; ++i) {
            int j = i * 64 + lane;
            s = fmaf(o_w[(long)k * 512 + j], hp_w[j * 3 + c], s);
        }
#pragma unroll
        for (int o = 32; o >= 1; o >>= 1) s += __shfl_xor(s, o);
        if (lane == 0) whp[k * 3 + c] = s;
    } else if (wid < 4099) {
        int c = wid - 4096;
#pragma unroll
        for (int i = 0; i < 8; ++i) {
            int j = i * 64 + lane;
            s = fmaf(o_b[j], hp_w[j * 3 + c], s);
        }
#pragma unroll
        for (int o = 32; o >= 1; o >>= 1) s += __shfl_xor(s, o);
        if (lane == 0) bias_po[c] = s + hp_b[c];
    }
}

// W'[:, 64:192] = cat_wt[:, 640:768]
__global__ __launch_bounds__(256) void wcopy_kernel(
    const ushort_t* __restrict__ catwt, ushort_t* __restrict__ wprime)
{
    int idx = (blockIdx.x * 256 + threadIdx.x) * 8;   // < 512*128
    int n = idx >> 7, c = idx & 127;
    *(bf16x8*)&wprime[n * 192 + 64 + c] = *(const bf16x8*)&catwt[(long)n * 768 + 640 + c];
}

// ---------------------------------------------------------------------------
// bf16 MFMA GEMM: C[M x N] = A[M x K] @ Wt^T + bias; tile 128x128, BK=64,
// 512 threads = 8 waves (2m x 4n), wave tile 64x32. global_load_lds staging:
// linear LDS dest + inverse-swizzled global source; reads swizzle identically.
// BBSTRIDE!=0: per-batch bias (2048 rows/batch).
// ---------------------------------------------------------------------------
template <int RELU, int OUT_BF16, int HASBIAS, int BBSTRIDE>
__global__ __launch_bounds__(512) void hgemm(
    const ushort_t* __restrict__ A, int lda,
    const ushort_t* __restrict__ Wt, int ldw,
    const float* __restrict__ bias,
    void* __restrict__ Cv, int ldc,
    int N, int K)
{
    __shared__ __align__(16) ushort_t As[128 * 64];
    __shared__ __align__(16) ushort_t Bs[128 * 64];

    const int tid = threadIdx.x;
    const int lane = tid & 63, w = tid >> 6;
    const int lo = lane & 15, hi = lane >> 4;
    const int wm = w >> 2, wn = w & 3;
    const long m0 = (long)blockIdx.y * 128;
    const int n0 = blockIdx.x * 128;

    f32x4 acc[4][2];
#pragma unroll
    for (int mt = 0; mt < 4; ++mt)
#pragma unroll
        for (int nt = 0; nt < 2; ++nt) acc[mt][nt] = (f32x4)0.f;

    for (int kt = 0; kt < K; kt += 64) {
#pragma unroll
        for (int i = 0; i < 2; ++i) {
            int c = w * 128 + i * 64 + lane;
            int r = c >> 3, ch = c & 7;
            int sch = ch ^ (r & 7);
            gload16(&A[(m0 + r) * (long)lda + kt + sch * 8],
                    &As[(w * 128 + i * 64) * 8]);
            gload16(&Wt[(long)(n0 + r) * ldw + kt + sch * 8],
                    &Bs[(w * 128 + i * 64) * 8]);
        }
        __syncthreads();

#pragma unroll
        for (int ks = 0; ks < 2; ++ks) {
            bf16x8 af[4], bfr[2];
#pragma unroll
            for (int mt = 0; mt < 4; ++mt) {
                int m = wm * 64 + mt * 16 + lo;
                af[mt] = *(const bf16x8*)&As[m * 64 + (((ks * 4 + hi) ^ (lo & 7)) * 8)];
            }
#pragma unroll
            for (int nt = 0; nt < 2; ++nt) {
                int n = wn * 32 + nt * 16 + lo;
                bfr[nt] = *(const bf16x8*)&Bs[n * 64 + (((ks * 4 + hi) ^ (lo & 7)) * 8)];
            }
#pragma unroll
            for (int mt = 0; mt < 4; ++mt)
#pragma unroll
                for (int nt = 0; nt < 2; ++nt)
                    acc[mt][nt] = __builtin_amdgcn_mfma_f32_16x16x32_bf16(
                        af[mt], bfr[nt], acc[mt][nt], 0, 0, 0);
        }
        __syncthreads();
    }

#pragma unroll
    for (int mt = 0; mt < 4; ++mt)
#pragma unroll
        for (int nt = 0; nt < 2; ++nt) {
            int col = n0 + wn * 32 + nt * 16 + lo;
            if (col < N) {
                float bv = 0.f;
                if (HASBIAS)
                    bv = BBSTRIDE ? bias[(int)(m0 >> 11) * BBSTRIDE + col] : bias[col];
#pragma unroll
                for (int r = 0; r < 4; ++r) {
                    long row = m0 + wm * 64 + mt * 16 + hi * 4 + r;
                    float v = acc[mt][nt][r] + bv;
                    if (RELU) v = fmaxf(v, 0.f);
                    if (OUT_BF16) ((ushort_t*)Cv)[row * (long)ldc + col] = f2bf(v);
                    else          ((float*)Cv)[row * (long)ldc + col] = v;
                }
            }
        }
}

// ---------------------------------------------------------------------------
// Position MLP -> a192[:, 64:192] (bf16)
// ---------------------------------------------------------------------------
__global__ __launch_bounds__(128) void posmlp_kernel(
    const float* __restrict__ pos,
    const float* __restrict__ w1, const float* __restrict__ b1,
    const float* __restrict__ w2, const float* __restrict__ b2,
    ushort_t* __restrict__ a192)
{
    __shared__ __align__(16) float w1s[256];
    __shared__ __align__(16) float b1s[64];
    __shared__ __align__(16) float w2t[128 * 64];
    __shared__ __align__(16) float b2s[128];

    const int tid = threadIdx.x;
    for (int i = tid; i < 256; i += 128) w1s[i] = w1[i];
    if (tid < 64) b1s[tid] = b1[tid];
    b2s[tid] = b2[tid];
    for (int i = tid; i < 8192; i += 128) {
        int k = i >> 7, o = i & 127;
        w2t[o * 64 + k] = w2[i];
    }
    __syncthreads();

    const long r = (long)blockIdx.x * 128 + tid;
    float px = pos[r * 3 + 0], py = pos[r * 3 + 1], pz = pos[r * 3 + 2];
    float nrm = sqrtf(px * px + py * py + pz * pz);
    float inv = 1.f / (nrm + 1e-7f);
    float pf0 = px * inv, pf1 = py * inv, pf2 = pz * inv, pf3 = nrm;

    float h1[64];
#pragma unroll
    for (int o = 0; o < 64; ++o) {
        float a = b1s[o];
        a = fmaf(pf0, w1s[o], a);
        a = fmaf(pf1, w1s[64 + o], a);
        a = fmaf(pf2, w1s[128 + o], a);
        a = fmaf(pf3, w1s[192 + o], a);
        h1[o] = fmaxf(a, 0.f);
    }
    ushort_t* dst = &a192[r * 192 + 64];
    for (int o = 0; o < 128; ++o) {
        float s = b2s[o];
#pragma unroll
        for (int i4 = 0; i4 < 16; ++i4) {
            float4 wv = *(const float4*)&w2t[o * 64 + i4 * 4];
            s = fmaf(h1[i4 * 4 + 0], wv.x, s);
            s = fmaf(h1[i4 * 4 + 1], wv.y, s);
            s = fmaf(h1[i4 * 4 + 2], wv.z, s);
            s = fmaf(h1[i4 * 4 + 3], wv.w, s);
        }
        dst[o] = f2bf(s);
    }
}

// tdt = diffusion_time @ yy_w + yy_b (fp32, exact)
__global__ __launch_bounds__(512) void tdt_kernel(
    const float* __restrict__ dt, const float* __restrict__ yyw,
    const float* __restrict__ yyb, float* __restrict__ tdt_ws,
    float* __restrict__ out_tail)
{
    const int t = threadIdx.x;
    const int b = t >> 7, o = t & 127;
    float s = yyb[o];
    for (int k = 0; k < 128; ++k) s = fmaf(dt[b * 128 + k], yyw[k * 128 + o], s);
    tdt_ws[t] = s;
    out_tail[t] = s;
}

// Fused Q+K rmsnorm over HD=64, bf16 in/out. Q folds 1/8 score scale.
__global__ __launch_bounds__(256) void rms2_kernel(
    const ushort_t* __restrict__ qkv,
    ushort_t* __restrict__ qn, ushort_t* __restrict__ kn,
    const float* __restrict__ qw, const float* __restrict__ kw)
{
    const int lane = threadIdx.x & 63;
    int p = blockIdx.x * 4 + (threadIdx.x >> 6);
    const int isK = p >> 16;
    p &= 0xffff;
    const long row = p >> 3;
    const int h = p & 7;
    const float* wv = isK ? kw : qw;
    ushort_t* out = isK ? kn : qn;
    const float scale = isK ? 1.0f : 0.125f;
    float x = bf2f(qkv[row * 1544 + isK * 520 + h * 64 + lane]);
    float ss = x * x;
#pragma unroll
    for (int o = 32; o >= 1; o >>= 1) ss += __shfl_xor(ss, o);
    float r = rsqrtf(ss * (1.f / 64.f) + 1e-6f);
    out[row * 512 + h * 64 + lane] = f2bf(wv[lane] * x * r * scale);
}

// Vt[bh][d][n] from bf16 V rows (stride ldv); grid (32, 32), block 256
__global__ __launch_bounds__(256) void vt_kernel(
    const ushort_t* __restrict__ V, int ldv, ushort_t* __restrict__ Vt)
{
    __shared__ ushort_t t[64][72];
    const int bh = blockIdx.x, b = bh >> 3, h = bh & 7;
    const int n0 = blockIdx.y * 64;
    const int tid = threadIdx.x;
#pragma unroll
    for (int i = 0; i < 2; ++i) {
        int c = tid + i * 256;
        int r = c >> 3, ch = c & 7;
        *(bf16x8*)&t[r][ch * 8] =
            *(const bf16x8*)&V[(long)(b * SEQ + n0 + r) * ldv + h * 64 + ch * 8];
    }
    __syncthreads();
    const int d = tid >> 2;
#pragma unroll
    for (int i = 0; i < 2; ++i) {
        int cc = (tid & 3) * 2 + i;
        bf16x8 pk;
#pragma unroll
        for (int j = 0; j < 8; ++j) pk[j] = (short)t[cc * 8 + j][d];
        *(bf16x8*)&Vt[((long)(bh * 64 + d)) * SEQ + n0 + cc * 8] = pk;
    }
}

// ---------------------------------------------------------------------------
// Flash attention, bf16 MFMA 16x16x32 (round-4 measured-good config).
// Fixed-shift softmax (|s| <= 8 analytically); swapped QK^T; packed P writes;
// K/V register prefetch. grid (32 bh, 16), block 256.
// ---------------------------------------------------------------------------
__global__ __launch_bounds__(256) void flash_attn_mfma(
    const ushort_t* __restrict__ Qn, const ushort_t* __restrict__ Kn,
    const ushort_t* __restrict__ Vt, const ushort_t* __restrict__ QKV,
    ushort_t* __restrict__ AO)
{
    __shared__ __align__(16) ushort_t Ks[64 * 64];
    __shared__ __align__(16) ushort_t Vs[64 * 64];
    __shared__ __align__(16) ushort_t Ps[4][32 * 64];

    const int tid = threadIdx.x;
    const int lane = tid & 63;
    const int w = tid >> 6;
    const int lo = lane & 15, hi = lane >> 4;
    const int bh = blockIdx.x, b = bh >> 3, h = bh & 7;
    const int qb = blockIdx.y * 128 + w * 32;

    bf16x8 qfrag[2][2];
#pragma unroll
    for (int jt = 0; jt < 2; ++jt)
#pragma unroll
        for (int ks = 0; ks < 2; ++ks)
            qfrag[jt][ks] = *(const bf16x8*)&Qn[(b * SEQ + qb + jt * 16 + lo) * 512 +
                                                h * 64 + ks * 32 + hi * 8];

    f32x4 accO[2][4];
#pragma unroll
    for (int mt = 0; mt < 2; ++mt)
#pragma unroll
        for (int nt = 0; nt < 4; ++nt) accO[mt][nt] = (f32x4)0.f;
    float l_part[2] = {0.f, 0.f};

    const int sr0 = tid >> 3, sc0 = tid & 7;
    const int sr1 = (tid + 256) >> 3, sc1 = tid & 7;

    bf16x8 kreg0, kreg1, vreg0, vreg1;
    {
        kreg0 = *(const bf16x8*)&Kn[(b * SEQ + sr0) * 512 + h * 64 + sc0 * 8];
        vreg0 = *(const bf16x8*)&Vt[((long)(bh * 64 + sr0)) * SEQ + sc0 * 8];
        kreg1 = *(const bf16x8*)&Kn[(b * SEQ + sr1) * 512 + h * 64 + sc1 * 8];
        vreg1 = *(const bf16x8*)&Vt[((long)(bh * 64 + sr1)) * SEQ + sc1 * 8];
    }

    for (int kt = 0; kt < 32; ++kt) {
        *(bf16x8*)&Ks[sr0 * 64 + ((sc0 ^ (sr0 & 7)) * 8)] = kreg0;
        *(bf16x8*)&Vs[sr0 * 64 + ((sc0 ^ (sr0 & 7)) * 8)] = vreg0;
        *(bf16x8*)&Ks[sr1 * 64 + ((sc1 ^ (sr1 & 7)) * 8)] = kreg1;
        *(bf16x8*)&Vs[sr1 * 64 + ((sc1 ^ (sr1 & 7)) * 8)] = vreg1;
        __syncthreads();

        if (kt + 1 < 32) {
            int nk = (kt + 1) * 64;
            kreg0 = *(const bf16x8*)&Kn[(b * SEQ + nk + sr0) * 512 + h * 64 + sc0 * 8];
            vreg0 = *(const bf16x8*)&Vt[((long)(bh * 64 + sr0)) * SEQ + nk + sc0 * 8];
            kreg1 = *(const bf16x8*)&Kn[(b * SEQ + nk + sr1) * 512 + h * 64 + sc1 * 8];
            vreg1 = *(const bf16x8*)&Vt[((long)(bh * 64 + sr1)) * SEQ + nk + sc1 * 8];
        }

        // ---- S^T = K * Q^T ----
        f32x4 accS[4][2];
#pragma unroll
        for (int it = 0; it < 4; ++it)
#pragma unroll
            for (int jt = 0; jt < 2; ++jt) accS[it][jt] = (f32x4)0.f;

#pragma unroll
        for (int it = 0; it < 4; ++it) {
            bf16x8 kf[2];
#pragma unroll
            for (int ks = 0; ks < 2; ++ks)
                kf[ks] = *(const bf16x8*)&Ks[(it * 16 + lo) * 64 +
                                             (((ks * 4 + hi) ^ (lo & 7)) * 8)];
#pragma unroll
            for (int jt = 0; jt < 2; ++jt)
#pragma unroll
                for (int ks = 0; ks < 2; ++ks)
                    accS[it][jt] = __builtin_amdgcn_mfma_f32_16x16x32_bf16(
                        kf[ks], qfrag[jt][ks], accS[it][jt], 0, 0, 0);
        }

        // ---- p = exp(s); pack; b64 write ----
#pragma unroll
        for (int it = 0; it < 4; ++it)
#pragma unroll
            for (int jt = 0; jt < 2; ++jt) {
                float p0 = __expf(accS[it][jt][0]);
                float p1 = __expf(accS[it][jt][1]);
                float p2 = __expf(accS[it][jt][2]);
                float p3 = __expf(accS[it][jt][3]);
                l_part[jt] += (p0 + p1) + (p2 + p3);
                unsigned w0, w1;
                asm("v_cvt_pk_bf16_f32 %0, %1, %2" : "=v"(w0) : "v"(p0), "v"(p1));
                asm("v_cvt_pk_bf16_f32 %0, %1, %2" : "=v"(w1) : "v"(p2), "v"(p3));
                int q = jt * 16 + lo;
                int cch = it * 2 + (hi >> 1);
                int off = q * 64 + ((cch ^ (q & 7)) * 8) + (hi & 1) * 4;
                uint2 t; t.x = w0; t.y = w1;
                *(uint2*)&Ps[w][off] = t;
            }

        // ---- O += P * V^T ----
#pragma unroll
        for (int kk = 0; kk < 2; ++kk) {
            bf16x8 pf[2];
#pragma unroll
            for (int mt = 0; mt < 2; ++mt)
                pf[mt] = *(const bf16x8*)&Ps[w][(mt * 16 + lo) * 64 +
                                               (((kk * 4 + hi) ^ (lo & 7)) * 8)];
#pragma unroll
            for (int nt = 0; nt < 4; ++nt) {
                bf16x8 vf = *(const bf16x8*)&Vs[(nt * 16 + lo) * 64 +
                                                (((kk * 4 + hi) ^ (lo & 7)) * 8)];
#pragma unroll
                for (int mt = 0; mt < 2; ++mt)
                    accO[mt][nt] = __builtin_amdgcn_mfma_f32_16x16x32_bf16(
                        pf[mt], vf, accO[mt][nt], 0, 0, 0);
            }
        }
        __syncthreads();
    }

#pragma unroll
    for (int jt = 0; jt < 2; ++jt) {
        l_part[jt] += __shfl_xor(l_part[jt], 16);
        l_part[jt] += __shfl_xor(l_part[jt], 32);
    }

#pragma unroll
    for (int mt = 0; mt < 2; ++mt)
#pragma unroll
        for (int r = 0; r < 4; ++r) {
            float lq = __shfl(l_part[mt], hi * 4 + r);
            int grow = b * SEQ + qb + mt * 16 + hi * 4 + r;
            float g = bf2f(QKV[(long)grow * 1544 + 512 + h]);
            g = 1.f / (1.f + __expf(-g));
            float sc = g / lq;
#pragma unroll
            for (int nt = 0; nt < 4; ++nt)
                AO[(long)grow * 512 + h * 64 + nt * 16 + lo] = f2bf(accO[mt][nt][r] * sc);
        }
}

// pos_out = ao @ whp + bias_po (bf16 in, fp32 fold weights)
__global__ __launch_bounds__(256) void posout_kernel(
    const ushort_t* __restrict__ ao, const float* __restrict__ whp,
    const float* __restrict__ bpo, float* __restrict__ po)
{
    const int lane = threadIdx.x & 63;
    const long row = (long)blockIdx.x * 4 + (threadIdx.x >> 6);
    float p0 = 0.f, p1 = 0.f, p2 = 0.f;
#pragma unroll
    for (int it = 0; it < 8; ++it) {
        int k = it * 64 + lane;
        float x = bf2f(ao[row * 512 + k]);
        p0 = fmaf(x, whp[k * 3 + 0], p0);
        p1 = fmaf(x, whp[k * 3 + 1], p1);
        p2 = fmaf(x, whp[k * 3 + 2], p2);
    }
#pragma unroll
    for (int o = 32; o >= 1; o >>= 1) {
        p0 += __shfl_xor(p0, o);
        p1 += __shfl_xor(p1, o);
        p2 += __shfl_xor(p2, o);
    }
    if (lane == 0) {
        po[row * 3 + 0] = p0 + bpo[0];
        po[row * 3 + 1] = p1 + bpo[1];
        po[row * 3 + 2] = p2 + bpo[2];
    }
}

// ---------------------------------------------------------------------------
extern "C" void kernel_launch(void* const* d_in, const int* in_sizes, int n_in,
                              void* d_out, int out_size, void* d_ws, size_t ws_size,
                              hipStream_t stream)
{
    const float* expr    = (const float*)d_in[0];
    const float* dtime   = (const float*)d_in[1];
    const float* posf    = (const float*)d_in[2];
    const float* pos_w1  = (const float*)d_in[3];
    const float* pos_b1  = (const float*)d_in[4];
    const float* pos_w2  = (const float*)d_in[5];
    const float* pos_b2  = (const float*)d_in[6];
    const float* expr_w1 = (const float*)d_in[7];
    const float* expr_b1 = (const float*)d_in[8];
    const float* expr_w2 = (const float*)d_in[9];
    const float* expr_b2 = (const float*)d_in[10];
    const float* yy_w    = (const float*)d_in[11];
    const float* yy_b    = (const float*)d_in[12];
    const float* cat_w   = (const float*)d_in[13];
    const float* cat_b   = (const float*)d_in[14];
    const float* q_w     = (const float*)d_in[15];
    const float* q_b     = (const float*)d_in[16];
    const float* k_w     = (const float*)d_in[17];
    const float* k_b     = (const float*)d_in[18];
    const float* v_w     = (const float*)d_in[19];
    const float* v_b     = (const float*)d_in[20];
    const float* o_w     = (const float*)d_in[21];
    const float* o_b     = (const float*)d_in[22];
    const float* qn_w    = (const float*)d_in[23];
    const float* kn_w    = (const float*)d_in[24];
    const float* hp_w    = (const float*)d_in[25];
    const float* hp_b    = (const float*)d_in[26];
    const float* he_w    = (const float*)d_in[27];
    const float* he_b    = (const float*)d_in[28];
    (void)in_sizes; (void)n_in; (void)out_size; (void)ws_size;

    ushort_t* wsb     = (ushort_t*)d_ws;
    ushort_t* expr_bf = wsb + U_EXPR;
    ushort_t* a192    = wsb + U_A192;
    ushort_t* h_bf    = wsb + U_H;
    ushort_t* qkv_bf  = wsb + U_QKV;
    ushort_t* qn_bf   = wsb + U_QN;
    ushort_t* kn_bf   = wsb + U_KN;
    ushort_t* vt_bf   = wsb + U_VT;
    ushort_t* ao_bf   = wsb + U_AO;
    ushort_t* w1t     = wsb + U_W1T;
    ushort_t* w2raw   = wsb + U_W2RAW;
    ushort_t* cat_wt  = wsb + U_CATWT;
    ushort_t* qkv_wt  = wsb + U_QKVWT;
    ushort_t* he_wt   = wsb + U_HEWT;
    ushort_t* wprime  = wsb + U_WPRIME;
    ushort_t* wohe    = wsb + U_WOHE;
    ushort_t* o_raw   = wsb + U_ORAW;
    float* f32r       = (float*)(wsb + U_F32);
    float* tdt        = f32r + F_TDT;
    float* qkv_bias   = f32r + F_QKVB;
    float* bias_h     = f32r + F_BIASH;
    float* bias_eo    = f32r + F_BIASEO;
    float* bias_po    = f32r + F_BIASPO;
    float* whp        = f32r + F_WHP;
    float* dout       = (float*)d_out;

    const dim3 blk(256);
    const dim3 blk512(512);

    // --- prep: conversions / transposes / folds ---
    f32_to_bf16_kernel<<<dim3(2048), blk, 0, stream>>>(expr, expr_bf);
    f32_to_bf16_kernel<<<dim3(16), blk, 0, stream>>>(expr_w2, w2raw);
    f32_to_bf16_kernel<<<dim3(128), blk, 0, stream>>>(o_w, o_raw);   // native layout

    WtTable tab;
    tab.s[0] = { expr_w1, w1t,              512,  64,  8,      0 };  //   8
    tab.s[1] = { cat_w,   cat_wt,           768, 512, 12,      8 };  //  96
    tab.s[2] = { q_w,     qkv_wt,           512, 520,  8,    104 };  //  72
    tab.s[3] = { k_w,     qkv_wt + 520*512, 512, 512,  8,    176 };  //  64
    tab.s[4] = { v_w,     qkv_wt + 1032*512,512, 512,  8,    240 };  //  64
    tab.s[5] = { he_w,    he_wt,            512, 512,  8,    304 };  //  64 -> 368... bias at 372
    tab.s[6] = { he_w,    he_wt,            512, 512,  8, 100000 };  // dummy
    tab.s[7] = { he_w,    he_wt,            512, 512,  8, 100000 };  // dummy
    wt_transpose<<<dim3(379), blk, 0, stream>>>(tab, q_b, k_b, v_b, qkv_bias);

    tdt_kernel<<<dim3(1), dim3(512), 0, stream>>>(dtime, yy_w, yy_b, tdt,
                                                  dout + DOUT_TDT);
    biasfold_kernel<<<dim3(1025), blk, 0, stream>>>(
        cat_wt, he_wt, expr_b2, tdt, cat_b, o_b, he_b, o_w, hp_w, hp_b,
        bias_h, bias_eo, whp, bias_po);
    // W'[:, :64] = (expr_w2 @ cat_w0)^T rows
    hgemm<0, 1, 0, 0><<<dim3(1, 4), blk512, 0, stream>>>(cat_wt, 768, w2raw, 512,
                                                         nullptr, wprime, 192, 64, 512);
    wcopy_kernel<<<dim3(32), blk, 0, stream>>>(cat_wt, wprime);
    // wohe[n][k] = sum_i he_w[i][n] * o_w[k][i]  (B-operand = NATIVE o_w)
    hgemm<0, 1, 0, 0><<<dim3(4, 4), blk512, 0, stream>>>(he_wt, 512, o_raw, 512,
                                                         nullptr, wohe, 512, 512, 512);

    // --- pipeline ---
    // a192[:, :64] = relu(expr @ expr_w1 + b1)
    hgemm<1, 1, 1, 0><<<dim3(1, 64), blk512, 0, stream>>>(expr_bf, 512, w1t, 512,
                                                          expr_b1, a192, 192, 64, 512);
    // a192[:, 64:192] = pos MLP
    posmlp_kernel<<<dim3(64), dim3(128), 0, stream>>>(posf, pos_w1, pos_b1,
                                                      pos_w2, pos_b2, a192);
    // h = a192 @ W'^T + bias_h[batch]
    hgemm<0, 1, 1, 512><<<dim3(4, 64), blk512, 0, stream>>>(a192, 192, wprime, 192,
                                                            bias_h, h_bf, 512, 512, 192);
    // qkv = h @ [q|k|v] + bias
    hgemm<0, 1, 1, 0><<<dim3(13, 64), blk512, 0, stream>>>(h_bf, 512, qkv_wt, 512,
                                                           qkv_bias, qkv_bf, 1544, 1544, 512);
    rms2_kernel<<<dim3(32768), blk, 0, stream>>>(qkv_bf, qn_bf, kn_bf, qn_w, kn_w);
    vt_kernel<<<dim3(32, 32), blk, 0, stream>>>(qkv_bf + 1032, 1544, vt_bf);
    flash_attn_mfma<<<dim3(32, 16), blk, 0, stream>>>(qn_bf, kn_bf, vt_bf, qkv_bf, ao_bf);
    // expr_out = ao @ wohe^T + bias_eo  (fp32 out)
    hgemm<0, 0, 1, 0><<<dim3(4, 64), blk512, 0, stream>>>(ao_bf, 512, wohe, 512,
                                                          bias_eo, dout + DOUT_EXPR,
                                                          512, 512, 512);
    posout_kernel<<<dim3(2048), blk, 0, stream>>>(ao_bf, whp, bias_po,
                                                  dout + DOUT_POS);
}

// Round 8
// 229.112 us; speedup vs baseline: 7.7020x; 1.0924x over previous
//
#include <hip/hip_runtime.h>
#include <math.h>

// Problem constants
#define SEQ   2048
#define NROWS 8192   // B*N

typedef unsigned short ushort_t;
typedef __attribute__((ext_vector_type(8))) short bf16x8;
typedef __attribute__((ext_vector_type(4))) float f32x4;

// Workspace offsets (ushort units)
#define U_EXPR   0ull            // 8192*512
#define U_A192   4194304ull      // 8192*192  ([te1|tp])
#define U_H      5767168ull      // 8192*512
#define U_QKV    9961472ull      // 8192*1544
#define U_QN     22609920ull     // (unused)
#define U_KN     26804224ull     // 8192*512
#define U_VT     30998528ull     // 32*64*2048
#define U_AO     35192832ull     // 8192*512
#define U_W1T    39387136ull     // 64*512
#define U_W2RAW  39419904ull     // 64*512
#define U_CATWT  39452672ull     // 512*768
#define U_QKVWT  39845888ull     // 1544*512
#define U_HEWT   40898560ull     // 512*512
#define U_WPRIME 41160704ull     // 512*192
#define U_WOHE   41259008ull     // 512*512
#define U_F32    41521152ull     // fp32 region (8192 floats)
#define U_ORAW   41537536ull     // 512*512 bf16, o_w native layout

// fp32 region layout (float offsets)
#define F_TDT    0
#define F_QKVB   512
#define F_BIASH  2056    // [4][512]
#define F_BIASEO 4104    // [512]
#define F_BIASPO 4616    // [4]
#define F_WHP    4620    // [512][3]

// d_out offsets (floats): (expr_out, pos_out, tdt)
#define DOUT_EXPR 0ull
#define DOUT_POS  4194304ull
#define DOUT_TDT  4218880ull

#define LOG2E 1.44269504088896340736f

static __device__ __forceinline__ ushort_t f2bf(float f) {
    union { float f; unsigned int u; } v; v.f = f;
    unsigned int r = (v.u + 0x7fffu + ((v.u >> 16) & 1u)) >> 16;
    return (ushort_t)r;
}
static __device__ __forceinline__ float bf2f(ushort_t u) {
    union { unsigned int u; float f; } v; v.u = ((unsigned int)u) << 16;
    return v.f;
}

// async global->LDS, 16B per lane; LDS dest = wave-uniform base + lane*16
static __device__ __forceinline__ void gload16(const void* g, void* l) {
    __builtin_amdgcn_global_load_lds(
        (const __attribute__((address_space(1))) void*)g,
        (__attribute__((address_space(3))) void*)l,
        16, 0, 0);
}

// ---------------------------------------------------------------------------
// fp32 -> bf16 bulk convert (element count multiple of 2048)
// ---------------------------------------------------------------------------
__global__ __launch_bounds__(256) void f32_to_bf16_kernel(
    const float* __restrict__ src, ushort_t* __restrict__ dst)
{
    long i = ((long)blockIdx.x * 256 + threadIdx.x) * 8;
    float4 a = *(const float4*)&src[i];
    float4 b = *(const float4*)&src[i + 4];
    bf16x8 p;
    p[0] = (short)f2bf(a.x); p[1] = (short)f2bf(a.y);
    p[2] = (short)f2bf(a.z); p[3] = (short)f2bf(a.w);
    p[4] = (short)f2bf(b.x); p[5] = (short)f2bf(b.y);
    p[6] = (short)f2bf(b.z); p[7] = (short)f2bf(b.w);
    *(bf16x8*)&dst[i] = p;
}

// ---------------------------------------------------------------------------
// Weight prep: mode 0 = transpose 64x64 tile (src[K][N] -> dst[n*dstStride+k]),
// mode 1 = convert-copy 16384-elem tile. Blocks >= 402: qkv bias gather.
// ---------------------------------------------------------------------------
struct WtSeg { const float* src; ushort_t* dst; int K, N, tK, tile0, dstStride, mode; };
struct WtTable { WtSeg s[10]; };

__global__ __launch_bounds__(256) void wt_transpose(
    WtTable tab, const float* __restrict__ qb, const float* __restrict__ kb,
    const float* __restrict__ vb, float* __restrict__ bias_dst)
{
    const int bid = blockIdx.x;
    const int tid = threadIdx.x;
    if (bid >= 402) {
        int t = (bid - 402) * 256 + tid;
        if (t < 520) bias_dst[t] = qb[t];
        else if (t < 1032) bias_dst[t] = kb[t - 520];
        else if (t < 1544) bias_dst[t] = vb[t - 1032];
        return;
    }
    int si = 0;
#pragma unroll
    for (int i = 1; i < 10; ++i)
        if (bid >= tab.s[i].tile0) si = i;
    const WtSeg sg = tab.s[si];
    const int local = bid - sg.tile0;

    if (sg.mode == 1) {
        // convert-copy: 16384 contiguous elements per tile, coalesced
        long base = (long)local * 16384;
#pragma unroll
        for (int i = 0; i < 8; ++i) {
            long p = base + i * 2048 + tid * 8;
            float4 a = *(const float4*)&sg.src[p];
            float4 b = *(const float4*)&sg.src[p + 4];
            bf16x8 o;
            o[0] = (short)f2bf(a.x); o[1] = (short)f2bf(a.y);
            o[2] = (short)f2bf(a.z); o[3] = (short)f2bf(a.w);
            o[4] = (short)f2bf(b.x); o[5] = (short)f2bf(b.y);
            o[6] = (short)f2bf(b.z); o[7] = (short)f2bf(b.w);
            *(bf16x8*)&sg.dst[p] = o;
        }
        return;
    }

    __shared__ float t[64][65];
    const int k0 = (local % sg.tK) * 64;
    const int n0 = (local / sg.tK) * 64;
#pragma unroll
    for (int i = 0; i < 16; ++i) {
        int e = tid + i * 256;
        int r = e >> 6, c = e & 63;
        float v = 0.f;
        if (k0 + r < sg.K && n0 + c < sg.N)
            v = sg.src[(long)(k0 + r) * sg.N + n0 + c];
        t[r][c] = v;
    }
    __syncthreads();
#pragma unroll
    for (int i = 0; i < 16; ++i) {
        int e = tid + i * 256;
        int rn = e >> 6, ck = e & 63;
        if (n0 + rn < sg.N && k0 + ck < sg.K)
            sg.dst[(long)(n0 + rn) * sg.dstStride + k0 + ck] = f2bf(t[ck][rn]);
    }
}

// ---------------------------------------------------------------------------
// Bias folding (wave-per-output) — unchanged from round 7.
// ---------------------------------------------------------------------------
__global__ __launch_bounds__(256) void biasfold_kernel(
    const ushort_t* __restrict__ catwt, const ushort_t* __restrict__ hewt,
    const float* __restrict__ expr_b2, const float* __restrict__ tdt,
    const float* __restrict__ cat_b, const float* __restrict__ o_b,
    const float* __restrict__ he_b, const float* __restrict__ o_w,
    const float* __restrict__ hp_w, const float* __restrict__ hp_b,
    float* __restrict__ bias_h, float* __restrict__ bias_eo,
    float* __restrict__ whp, float* __restrict__ bias_po)
{
    const int wid = blockIdx.x * 4 + (threadIdx.x >> 6);
    const int lane = threadIdx.x & 63;
    float s = 0.f;
    if (wid < 2048) {
        int b = wid >> 9, n = wid & 511;
        bf16x8 wv = *(const bf16x8*)&catwt[(long)n * 768 + lane * 8];
        float4 e0 = *(const float4*)&expr_b2[lane * 8];
        float4 e1 = *(const float4*)&expr_b2[lane * 8 + 4];
        s = bf2f((ushort_t)wv[0]) * e0.x + bf2f((ushort_t)wv[1]) * e0.y +
            bf2f((ushort_t)wv[2]) * e0.z + bf2f((ushort_t)wv[3]) * e0.w +
            bf2f((ushort_t)wv[4]) * e1.x + bf2f((ushort_t)wv[5]) * e1.y +
            bf2f((ushort_t)wv[6]) * e1.z + bf2f((ushort_t)wv[7]) * e1.w;
        float2 tt = *(const float2*)&tdt[b * 128 + lane * 2];
        s += bf2f(catwt[(long)n * 768 + 512 + lane * 2]) * tt.x;
        s += bf2f(catwt[(long)n * 768 + 513 + lane * 2]) * tt.y;
#pragma unroll
        for (int o = 32; o >= 1; o >>= 1) s += __shfl_xor(s, o);
        if (lane == 0) bias_h[b * 512 + n] = s + cat_b[n];
    } else if (wid < 2560) {
        int n = wid - 2048;
        bf16x8 wv = *(const bf16x8*)&hewt[(long)n * 512 + lane * 8];
        float4 e0 = *(const float4*)&o_b[lane * 8];
        float4 e1 = *(const float4*)&o_b[lane * 8 + 4];
        s = bf2f((ushort_t)wv[0]) * e0.x + bf2f((ushort_t)wv[1]) * e0.y +
            bf2f((ushort_t)wv[2]) * e0.z + bf2f((ushort_t)wv[3]) * e0.w +
            bf2f((ushort_t)wv[4]) * e1.x + bf2f((ushort_t)wv[5]) * e1.y +
            bf2f((ushort_t)wv[6]) * e1.z + bf2f((ushort_t)wv[7]) * e1.w;
#pragma unroll
        for (int o = 32; o >= 1; o >>= 1) s += __shfl_xor(s, o);
        if (lane == 0) bias_eo[n] = s + he_b[n];
    } else if (wid < 4096) {
        int t = wid - 2560;
        int c = t >> 9, k = t & 511;
#pragma unroll
        for (int i = 0; i < 8; ++i) {
            int j = i * 64 + lane;
            s = fmaf(o_w[(long)k * 512 + j], hp_w[j * 3 + c], s);
        }
#pragma unroll
        for (int o = 32; o >= 1; o >>= 1) s += __shfl_xor(s, o);
        if (lane == 0) whp[k * 3 + c] = s;
    } else if (wid < 4099) {
        int c = wid - 4096;
#pragma unroll
        for (int i = 0; i < 8; ++i) {
            int j = i * 64 + lane;
            s = fmaf(o_b[j], hp_w[j * 3 + c], s);
        }
#pragma unroll
        for (int o = 32; o >= 1; o >>= 1) s += __shfl_xor(s, o);
        if (lane == 0) bias_po[c] = s + hp_b[c];
    }
}

// ---------------------------------------------------------------------------
// bf16 MFMA GEMM — unchanged from round 7 (global_load_lds, swizzled source).
// ---------------------------------------------------------------------------
template <int RELU, int OUT_BF16, int HASBIAS, int BBSTRIDE>
__global__ __launch_bounds__(512) void hgemm(
    const ushort_t* __restrict__ A, int lda,
    const ushort_t* __restrict__ Wt, int ldw,
    const float* __restrict__ bias,
    void* __restrict__ Cv, int ldc,
    int N, int K)
{
    __shared__ __align__(16) ushort_t As[128 * 64];
    __shared__ __align__(16) ushort_t Bs[128 * 64];

    const int tid = threadIdx.x;
    const int lane = tid & 63, w = tid >> 6;
    const int lo = lane & 15, hi = lane >> 4;
    const int wm = w >> 2, wn = w & 3;
    const long m0 = (long)blockIdx.y * 128;
    const int n0 = blockIdx.x * 128;

    f32x4 acc[4][2];
#pragma unroll
    for (int mt = 0; mt < 4; ++mt)
#pragma unroll
        for (int nt = 0; nt < 2; ++nt) acc[mt][nt] = (f32x4)0.f;

    for (int kt = 0; kt < K; kt += 64) {
#pragma unroll
        for (int i = 0; i < 2; ++i) {
            int c = w * 128 + i * 64 + lane;
            int r = c >> 3, ch = c & 7;
            int sch = ch ^ (r & 7);
            gload16(&A[(m0 + r) * (long)lda + kt + sch * 8],
                    &As[(w * 128 + i * 64) * 8]);
            gload16(&Wt[(long)(n0 + r) * ldw + kt + sch * 8],
                    &Bs[(w * 128 + i * 64) * 8]);
        }
        __syncthreads();

#pragma unroll
        for (int ks = 0; ks < 2; ++ks) {
            bf16x8 af[4], bfr[2];
#pragma unroll
            for (int mt = 0; mt < 4; ++mt) {
                int m = wm * 64 + mt * 16 + lo;
                af[mt] = *(const bf16x8*)&As[m * 64 + (((ks * 4 + hi) ^ (lo & 7)) * 8)];
            }
#pragma unroll
            for (int nt = 0; nt < 2; ++nt) {
                int n = wn * 32 + nt * 16 + lo;
                bfr[nt] = *(const bf16x8*)&Bs[n * 64 + (((ks * 4 + hi) ^ (lo & 7)) * 8)];
            }
#pragma unroll
            for (int mt = 0; mt < 4; ++mt)
#pragma unroll
                for (int nt = 0; nt < 2; ++nt)
                    acc[mt][nt] = __builtin_amdgcn_mfma_f32_16x16x32_bf16(
                        af[mt], bfr[nt], acc[mt][nt], 0, 0, 0);
        }
        __syncthreads();
    }

#pragma unroll
    for (int mt = 0; mt < 4; ++mt)
#pragma unroll
        for (int nt = 0; nt < 2; ++nt) {
            int col = n0 + wn * 32 + nt * 16 + lo;
            if (col < N) {
                float bv = 0.f;
                if (HASBIAS)
                    bv = BBSTRIDE ? bias[(int)(m0 >> 11) * BBSTRIDE + col] : bias[col];
#pragma unroll
                for (int r = 0; r < 4; ++r) {
                    long row = m0 + wm * 64 + mt * 16 + hi * 4 + r;
                    float v = acc[mt][nt][r] + bv;
                    if (RELU) v = fmaxf(v, 0.f);
                    if (OUT_BF16) ((ushort_t*)Cv)[row * (long)ldc + col] = f2bf(v);
                    else          ((float*)Cv)[row * (long)ldc + col] = v;
                }
            }
        }
}

// ---------------------------------------------------------------------------
// Position MLP -> a192[:, 64:192] (bf16) — unchanged.
// ---------------------------------------------------------------------------
__global__ __launch_bounds__(128) void posmlp_kernel(
    const float* __restrict__ pos,
    const float* __restrict__ w1, const float* __restrict__ b1,
    const float* __restrict__ w2, const float* __restrict__ b2,
    ushort_t* __restrict__ a192)
{
    __shared__ __align__(16) float w1s[256];
    __shared__ __align__(16) float b1s[64];
    __shared__ __align__(16) float w2t[128 * 64];
    __shared__ __align__(16) float b2s[128];

    const int tid = threadIdx.x;
    for (int i = tid; i < 256; i += 128) w1s[i] = w1[i];
    if (tid < 64) b1s[tid] = b1[tid];
    b2s[tid] = b2[tid];
    for (int i = tid; i < 8192; i += 128) {
        int k = i >> 7, o = i & 127;
        w2t[o * 64 + k] = w2[i];
    }
    __syncthreads();

    const long r = (long)blockIdx.x * 128 + tid;
    float px = pos[r * 3 + 0], py = pos[r * 3 + 1], pz = pos[r * 3 + 2];
    float nrm = sqrtf(px * px + py * py + pz * pz);
    float inv = 1.f / (nrm + 1e-7f);
    float pf0 = px * inv, pf1 = py * inv, pf2 = pz * inv, pf3 = nrm;

    float h1[64];
#pragma unroll
    for (int o = 0; o < 64; ++o) {
        float a = b1s[o];
        a = fmaf(pf0, w1s[o], a);
        a = fmaf(pf1, w1s[64 + o], a);
        a = fmaf(pf2, w1s[128 + o], a);
        a = fmaf(pf3, w1s[192 + o], a);
        h1[o] = fmaxf(a, 0.f);
    }
    ushort_t* dst = &a192[r * 192 + 64];
    for (int o = 0; o < 128; ++o) {
        float s = b2s[o];
#pragma unroll
        for (int i4 = 0; i4 < 16; ++i4) {
            float4 wv = *(const float4*)&w2t[o * 64 + i4 * 4];
            s = fmaf(h1[i4 * 4 + 0], wv.x, s);
            s = fmaf(h1[i4 * 4 + 1], wv.y, s);
            s = fmaf(h1[i4 * 4 + 2], wv.z, s);
            s = fmaf(h1[i4 * 4 + 3], wv.w, s);
        }
        dst[o] = f2bf(s);
    }
}

// tdt = diffusion_time @ yy_w + yy_b (fp32, exact)
__global__ __launch_bounds__(512) void tdt_kernel(
    const float* __restrict__ dt, const float* __restrict__ yyw,
    const float* __restrict__ yyb, float* __restrict__ tdt_ws,
    float* __restrict__ out_tail)
{
    const int t = threadIdx.x;
    const int b = t >> 7, o = t & 127;
    float s = yyb[o];
    for (int k = 0; k < 128; ++k) s = fmaf(dt[b * 128 + k], yyw[k * 128 + o], s);
    tdt_ws[t] = s;
    out_tail[t] = s;
}

// ---------------------------------------------------------------------------
// qkv postprocess: per (bh, 64-row block):
//   kn[row][h*64+d] = rmsnorm(K row) (replaces rms2's K half)
//   Vt[bh][d][n]    = V transpose
// grid (32, 32), block 256.
// ---------------------------------------------------------------------------
__global__ __launch_bounds__(256) void qkvpost_kernel(
    const ushort_t* __restrict__ qkv, const float* __restrict__ knw,
    ushort_t* __restrict__ kn, ushort_t* __restrict__ Vt)
{
    __shared__ ushort_t t[64][72];
    __shared__ float knw_s[64];
    const int bh = blockIdx.x, b = bh >> 3, h = bh & 7;
    const int n0 = blockIdx.y * 64;
    const int tid = threadIdx.x;
    if (tid < 64) knw_s[tid] = knw[tid];
    // V tile -> LDS
#pragma unroll
    for (int i = 0; i < 2; ++i) {
        int c = tid + i * 256;
        int r = c >> 3, ch = c & 7;
        *(bf16x8*)&t[r][ch * 8] =
            *(const bf16x8*)&qkv[(long)(b * SEQ + n0 + r) * 1544 + 1032 + h * 64 + ch * 8];
    }
    __syncthreads();
    // K rmsnorm (8 threads per row; shfl-reduce sumsq within the 8-lane group)
#pragma unroll
    for (int i = 0; i < 2; ++i) {
        int c = tid + i * 256;
        int r = c >> 3, ch = c & 7;
        bf16x8 kv = *(const bf16x8*)&qkv[(long)(b * SEQ + n0 + r) * 1544 + 520 + h * 64 + ch * 8];
        float x[8], ss = 0.f;
#pragma unroll
        for (int j = 0; j < 8; ++j) { x[j] = bf2f((ushort_t)kv[j]); ss = fmaf(x[j], x[j], ss); }
        ss += __shfl_xor(ss, 1);
        ss += __shfl_xor(ss, 2);
        ss += __shfl_xor(ss, 4);
        float invr = rsqrtf(ss * (1.f / 64.f) + 1e-6f);
        bf16x8 o;
#pragma unroll
        for (int j = 0; j < 8; ++j) o[j] = (short)f2bf(x[j] * knw_s[ch * 8 + j] * invr);
        *(bf16x8*)&kn[(long)(b * SEQ + n0 + r) * 512 + h * 64 + ch * 8] = o;
    }
    // V transpose out
    const int d = tid >> 2;
#pragma unroll
    for (int i = 0; i < 2; ++i) {
        int cc = (tid & 3) * 2 + i;
        bf16x8 pk;
#pragma unroll
        for (int j = 0; j < 8; ++j) pk[j] = (short)t[cc * 8 + j][d];
        *(bf16x8*)&Vt[((long)(bh * 64 + d)) * SEQ + n0 + cc * 8] = pk;
    }
}

// ---------------------------------------------------------------------------
// Flash attention, bf16 MFMA 16x16x32.
// Q rmsnorm fused inline (scale folds 0.125*log2e); fixed-shift softmax via
// raw v_exp_f32 (2^x, exp2 domain, |s2| <= 11.55); swapped QK^T; packed P
// writes; K/V register prefetch. grid (32 bh, 16), block 256.
// ---------------------------------------------------------------------------
__global__ __launch_bounds__(256) void flash_attn_mfma(
    const ushort_t* __restrict__ QKV, const ushort_t* __restrict__ Kn,
    const ushort_t* __restrict__ Vt, const float* __restrict__ qnw,
    ushort_t* __restrict__ AO)
{
    __shared__ __align__(16) ushort_t Ks[64 * 64];
    __shared__ __align__(16) ushort_t Vs[64 * 64];
    __shared__ __align__(16) ushort_t Ps[4][32 * 64];

    const int tid = threadIdx.x;
    const int lane = tid & 63;
    const int w = tid >> 6;
    const int lo = lane & 15, hi = lane >> 4;
    const int bh = blockIdx.x, b = bh >> 3, h = bh & 7;
    const int qb = blockIdx.y * 128 + w * 32;

    // ---- Q load + inline rmsnorm (row on lanes {lo, lo+16, lo+32, lo+48}) ----
    bf16x8 qfrag[2][2];
    {
        float qw[2][8];
#pragma unroll
        for (int ks = 0; ks < 2; ++ks)
#pragma unroll
            for (int j = 0; j < 8; ++j)
                qw[ks][j] = qnw[ks * 32 + hi * 8 + j];
#pragma unroll
        for (int jt = 0; jt < 2; ++jt) {
            float qx[2][8], ss = 0.f;
#pragma unroll
            for (int ks = 0; ks < 2; ++ks) {
                bf16x8 q = *(const bf16x8*)&QKV[(long)(b * SEQ + qb + jt * 16 + lo) * 1544 +
                                                h * 64 + ks * 32 + hi * 8];
#pragma unroll
                for (int j = 0; j < 8; ++j) {
                    qx[ks][j] = bf2f((ushort_t)q[j]);
                    ss = fmaf(qx[ks][j], qx[ks][j], ss);
                }
            }
            ss += __shfl_xor(ss, 16);
            ss += __shfl_xor(ss, 32);
            float invr = rsqrtf(ss * (1.f / 64.f) + 1e-6f) * (0.125f * LOG2E);
#pragma unroll
            for (int ks = 0; ks < 2; ++ks) {
                bf16x8 f;
#pragma unroll
                for (int j = 0; j < 8; ++j)
                    f[j] = (short)f2bf(qx[ks][j] * qw[ks][j] * invr);
                qfrag[jt][ks] = f;
            }
        }
    }

    f32x4 accO[2][4];
#pragma unroll
    for (int mt = 0; mt < 2; ++mt)
#pragma unroll
        for (int nt = 0; nt < 4; ++nt) accO[mt][nt] = (f32x4)0.f;
    float l_part[2] = {0.f, 0.f};

    const int sr0 = tid >> 3, sc0 = tid & 7;
    const int sr1 = (tid + 256) >> 3, sc1 = tid & 7;

    bf16x8 kreg0, kreg1, vreg0, vreg1;
    {
        kreg0 = *(const bf16x8*)&Kn[(b * SEQ + sr0) * 512 + h * 64 + sc0 * 8];
        vreg0 = *(const bf16x8*)&Vt[((long)(bh * 64 + sr0)) * SEQ + sc0 * 8];
        kreg1 = *(const bf16x8*)&Kn[(b * SEQ + sr1) * 512 + h * 64 + sc1 * 8];
        vreg1 = *(const bf16x8*)&Vt[((long)(bh * 64 + sr1)) * SEQ + sc1 * 8];
    }

    for (int kt = 0; kt < 32; ++kt) {
        *(bf16x8*)&Ks[sr0 * 64 + ((sc0 ^ (sr0 & 7)) * 8)] = kreg0;
        *(bf16x8*)&Vs[sr0 * 64 + ((sc0 ^ (sr0 & 7)) * 8)] = vreg0;
        *(bf16x8*)&Ks[sr1 * 64 + ((sc1 ^ (sr1 & 7)) * 8)] = kreg1;
        *(bf16x8*)&Vs[sr1 * 64 + ((sc1 ^ (sr1 & 7)) * 8)] = vreg1;
        __syncthreads();

        if (kt + 1 < 32) {
            int nk = (kt + 1) * 64;
            kreg0 = *(const bf16x8*)&Kn[(b * SEQ + nk + sr0) * 512 + h * 64 + sc0 * 8];
            vreg0 = *(const bf16x8*)&Vt[((long)(bh * 64 + sr0)) * SEQ + nk + sc0 * 8];
            kreg1 = *(const bf16x8*)&Kn[(b * SEQ + nk + sr1) * 512 + h * 64 + sc1 * 8];
            vreg1 = *(const bf16x8*)&Vt[((long)(bh * 64 + sr1)) * SEQ + nk + sc1 * 8];
        }

        // ---- S^T = K * Q^T ----
        f32x4 accS[4][2];
#pragma unroll
        for (int it = 0; it < 4; ++it)
#pragma unroll
            for (int jt = 0; jt < 2; ++jt) accS[it][jt] = (f32x4)0.f;

#pragma unroll
        for (int it = 0; it < 4; ++it) {
            bf16x8 kf[2];
#pragma unroll
            for (int ks = 0; ks < 2; ++ks)
                kf[ks] = *(const bf16x8*)&Ks[(it * 16 + lo) * 64 +
                                             (((ks * 4 + hi) ^ (lo & 7)) * 8)];
#pragma unroll
            for (int jt = 0; jt < 2; ++jt)
#pragma unroll
                for (int ks = 0; ks < 2; ++ks)
                    accS[it][jt] = __builtin_amdgcn_mfma_f32_16x16x32_bf16(
                        kf[ks], qfrag[jt][ks], accS[it][jt], 0, 0, 0);
        }

        // ---- p = 2^s (scores pre-scaled by log2e); pack; b64 write ----
#pragma unroll
        for (int it = 0; it < 4; ++it)
#pragma unroll
            for (int jt = 0; jt < 2; ++jt) {
                float p0, p1, p2, p3;
                asm("v_exp_f32 %0, %1" : "=v"(p0) : "v"(accS[it][jt][0]));
                asm("v_exp_f32 %0, %1" : "=v"(p1) : "v"(accS[it][jt][1]));
                asm("v_exp_f32 %0, %1" : "=v"(p2) : "v"(accS[it][jt][2]));
                asm("v_exp_f32 %0, %1" : "=v"(p3) : "v"(accS[it][jt][3]));
                l_part[jt] += (p0 + p1) + (p2 + p3);
                unsigned w0, w1;
                asm("v_cvt_pk_bf16_f32 %0, %1, %2" : "=v"(w0) : "v"(p0), "v"(p1));
                asm("v_cvt_pk_bf16_f32 %0, %1, %2" : "=v"(w1) : "v"(p2), "v"(p3));
                int q = jt * 16 + lo;
                int cch = it * 2 + (hi >> 1);
                int off = q * 64 + ((cch ^ (q & 7)) * 8) + (hi & 1) * 4;
                uint2 t; t.x = w0; t.y = w1;
                *(uint2*)&Ps[w][off] = t;
            }

        // ---- O += P * V^T ----
#pragma unroll
        for (int kk = 0; kk < 2; ++kk) {
            bf16x8 pf[2];
#pragma unroll
            for (int mt = 0; mt < 2; ++mt)
                pf[mt] = *(const bf16x8*)&Ps[w][(mt * 16 + lo) * 64 +
                                               (((kk * 4 + hi) ^ (lo & 7)) * 8)];
#pragma unroll
            for (int nt = 0; nt < 4; ++nt) {
                bf16x8 vf = *(const bf16x8*)&Vs[(nt * 16 + lo) * 64 +
                                                (((kk * 4 + hi) ^ (lo & 7)) * 8)];
#pragma unroll
                for (int mt = 0; mt < 2; ++mt)
                    accO[mt][nt] = __builtin_amdgcn_mfma_f32_16x16x32_bf16(
                        pf[mt], vf, accO[mt][nt], 0, 0, 0);
            }
        }
        __syncthreads();
    }

#pragma unroll
    for (int jt = 0; jt < 2; ++jt) {
        l_part[jt] += __shfl_xor(l_part[jt], 16);
        l_part[jt] += __shfl_xor(l_part[jt], 32);
    }

#pragma unroll
    for (int mt = 0; mt < 2; ++mt)
#pragma unroll
        for (int r = 0; r < 4; ++r) {
            float lq = __shfl(l_part[mt], hi * 4 + r);
            int grow = b * SEQ + qb + mt * 16 + hi * 4 + r;
            float g = bf2f(QKV[(long)grow * 1544 + 512 + h]);
            g = 1.f / (1.f + __expf(-g));
            float sc = g / lq;
#pragma unroll
            for (int nt = 0; nt < 4; ++nt)
                AO[(long)grow * 512 + h * 64 + nt * 16 + lo] = f2bf(accO[mt][nt][r] * sc);
        }
}

// pos_out = ao @ whp + bias_po (bf16 in, fp32 fold weights)
__global__ __launch_bounds__(256) void posout_kernel(
    const ushort_t* __restrict__ ao, const float* __restrict__ whp,
    const float* __restrict__ bpo, float* __restrict__ po)
{
    const int lane = threadIdx.x & 63;
    const long row = (long)blockIdx.x * 4 + (threadIdx.x >> 6);
    float p0 = 0.f, p1 = 0.f, p2 = 0.f;
#pragma unroll
    for (int it = 0; it < 8; ++it) {
        int k = it * 64 + lane;
        float x = bf2f(ao[row * 512 + k]);
        p0 = fmaf(x, whp[k * 3 + 0], p0);
        p1 = fmaf(x, whp[k * 3 + 1], p1);
        p2 = fmaf(x, whp[k * 3 + 2], p2);
    }
#pragma unroll
    for (int o = 32; o >= 1; o >>= 1) {
        p0 += __shfl_xor(p0, o);
        p1 += __shfl_xor(p1, o);
        p2 += __shfl_xor(p2, o);
    }
    if (lane == 0) {
        po[row * 3 + 0] = p0 + bpo[0];
        po[row * 3 + 1] = p1 + bpo[1];
        po[row * 3 + 2] = p2 + bpo[2];
    }
}

// ---------------------------------------------------------------------------
extern "C" void kernel_launch(void* const* d_in, const int* in_sizes, int n_in,
                              void* d_out, int out_size, void* d_ws, size_t ws_size,
                              hipStream_t stream)
{
    const float* expr    = (const float*)d_in[0];
    const float* dtime   = (const float*)d_in[1];
    const float* posf    = (const float*)d_in[2];
    const float* pos_w1  = (const float*)d_in[3];
    const float* pos_b1  = (const float*)d_in[4];
    const float* pos_w2  = (const float*)d_in[5];
    const float* pos_b2  = (const float*)d_in[6];
    const float* expr_w1 = (const float*)d_in[7];
    const float* expr_b1 = (const float*)d_in[8];
    const float* expr_w2 = (const float*)d_in[9];
    const float* expr_b2 = (const float*)d_in[10];
    const float* yy_w    = (const float*)d_in[11];
    const float* yy_b    = (const float*)d_in[12];
    const float* cat_w   = (const float*)d_in[13];
    const float* cat_b   = (const float*)d_in[14];
    const float* q_w     = (const float*)d_in[15];
    const float* q_b     = (const float*)d_in[16];
    const float* k_w     = (const float*)d_in[17];
    const float* k_b     = (const float*)d_in[18];
    const float* v_w     = (const float*)d_in[19];
    const float* v_b     = (const float*)d_in[20];
    const float* o_w     = (const float*)d_in[21];
    const float* o_b     = (const float*)d_in[22];
    const float* qn_w    = (const float*)d_in[23];
    const float* kn_w    = (const float*)d_in[24];
    const float* hp_w    = (const float*)d_in[25];
    const float* hp_b    = (const float*)d_in[26];
    const float* he_w    = (const float*)d_in[27];
    const float* he_b    = (const float*)d_in[28];
    (void)in_sizes; (void)n_in; (void)out_size; (void)ws_size;

    ushort_t* wsb     = (ushort_t*)d_ws;
    ushort_t* expr_bf = wsb + U_EXPR;
    ushort_t* a192    = wsb + U_A192;
    ushort_t* h_bf    = wsb + U_H;
    ushort_t* qkv_bf  = wsb + U_QKV;
    ushort_t* kn_bf   = wsb + U_KN;
    ushort_t* vt_bf   = wsb + U_VT;
    ushort_t* ao_bf   = wsb + U_AO;
    ushort_t* w1t     = wsb + U_W1T;
    ushort_t* w2raw   = wsb + U_W2RAW;
    ushort_t* cat_wt  = wsb + U_CATWT;
    ushort_t* qkv_wt  = wsb + U_QKVWT;
    ushort_t* he_wt   = wsb + U_HEWT;
    ushort_t* wprime  = wsb + U_WPRIME;
    ushort_t* wohe    = wsb + U_WOHE;
    ushort_t* o_raw   = wsb + U_ORAW;
    float* f32r       = (float*)(wsb + U_F32);
    float* tdt        = f32r + F_TDT;
    float* qkv_bias   = f32r + F_QKVB;
    float* bias_h     = f32r + F_BIASH;
    float* bias_eo    = f32r + F_BIASEO;
    float* bias_po    = f32r + F_BIASPO;
    float* whp        = f32r + F_WHP;
    float* dout       = (float*)d_out;

    const dim3 blk(256);
    const dim3 blk512(512);

    // --- prep: conversions / transposes / folds ---
    f32_to_bf16_kernel<<<dim3(2048), blk, 0, stream>>>(expr, expr_bf);

    WtTable tab;
    //            src              dst               K    N   tK tile0 dstS mode
    tab.s[0] = { expr_w1,          w1t,             512,  64,  8,   0, 512, 0 };  //   8
    tab.s[1] = { cat_w,            cat_wt,          768, 512, 12,   8, 768, 0 };  //  96
    tab.s[2] = { q_w,              qkv_wt,          512, 520,  8, 104, 512, 0 };  //  72
    tab.s[3] = { k_w,              qkv_wt + 520*512,512, 512,  8, 176, 512, 0 };  //  64
    tab.s[4] = { v_w,              qkv_wt +1032*512,512, 512,  8, 240, 512, 0 };  //  64
    tab.s[5] = { he_w,             he_wt,           512, 512,  8, 304, 512, 0 };  //  64
    tab.s[6] = { cat_w + 640*512,  wprime + 64,     128, 512,  2, 368, 192, 0 };  //  16
    tab.s[7] = { expr_w2,          w2raw,             0,   0,  0, 384,   0, 1 };  //   2 (32768 el)
    tab.s[8] = { o_w,              o_raw,             0,   0,  0, 386,   0, 1 };  //  16 (262144 el)
    tab.s[9] = { o_w,              o_raw,             0,   0,  0, 100000, 0, 1 }; // dummy
    wt_transpose<<<dim3(409), blk, 0, stream>>>(tab, q_b, k_b, v_b, qkv_bias);

    tdt_kernel<<<dim3(1), dim3(512), 0, stream>>>(dtime, yy_w, yy_b, tdt,
                                                  dout + DOUT_TDT);
    biasfold_kernel<<<dim3(1025), blk, 0, stream>>>(
        cat_wt, he_wt, expr_b2, tdt, cat_b, o_b, he_b, o_w, hp_w, hp_b,
        bias_h, bias_eo, whp, bias_po);
    // W'[:, :64] = (expr_w2 @ cat_w0)^T rows
    hgemm<0, 1, 0, 0><<<dim3(1, 4), blk512, 0, stream>>>(cat_wt, 768, w2raw, 512,
                                                         nullptr, wprime, 192, 64, 512);
    // wohe[n][k] = sum_i he_w[i][n] * o_w[k][i]  (B-operand = NATIVE o_w)
    hgemm<0, 1, 0, 0><<<dim3(4, 4), blk512, 0, stream>>>(he_wt, 512, o_raw, 512,
                                                         nullptr, wohe, 512, 512, 512);

    // --- pipeline ---
    // a192[:, :64] = relu(expr @ expr_w1 + b1)
    hgemm<1, 1, 1, 0><<<dim3(1, 64), blk512, 0, stream>>>(expr_bf, 512, w1t, 512,
                                                          expr_b1, a192, 192, 64, 512);
    // a192[:, 64:192] = pos MLP
    posmlp_kernel<<<dim3(64), dim3(128), 0, stream>>>(posf, pos_w1, pos_b1,
                                                      pos_w2, pos_b2, a192);
    // h = a192 @ W'^T + bias_h[batch]
    hgemm<0, 1, 1, 512><<<dim3(4, 64), blk512, 0, stream>>>(a192, 192, wprime, 192,
                                                            bias_h, h_bf, 512, 512, 192);
    // qkv = h @ [q|k|v] + bias
    hgemm<0, 1, 1, 0><<<dim3(13, 64), blk512, 0, stream>>>(h_bf, 512, qkv_wt, 512,
                                                           qkv_bias, qkv_bf, 1544, 1544, 512);
    // K rmsnorm + V transpose (one pass over qkv)
    qkvpost_kernel<<<dim3(32, 32), blk, 0, stream>>>(qkv_bf, kn_w, kn_bf, vt_bf);
    // attention (Q rmsnorm fused inline)
    flash_attn_mfma<<<dim3(32, 16), blk, 0, stream>>>(qkv_bf, kn_bf, vt_bf, qn_w, ao_bf);
    // expr_out = ao @ wohe^T + bias_eo  (fp32 out)
    hgemm<0, 0, 1, 0><<<dim3(4, 64), blk512, 0, stream>>>(ao_bf, 512, wohe, 512,
                                                          bias_eo, dout + DOUT_EXPR,
                                                          512, 512, 512);
    posout_kernel<<<dim3(2048), blk, 0, stream>>>(ao_bf, whp, bias_po,
                                                  dout + DOUT_POS);
}

// Round 9
// 214.882 us; speedup vs baseline: 8.2120x; 1.0662x over previous
//
#include <hip/hip_runtime.h>
#include <math.h>

// Problem constants
#define SEQ   2048
#define NROWS 8192   // B*N

typedef unsigned short ushort_t;
typedef __attribute__((ext_vector_type(8))) short bf16x8;
typedef __attribute__((ext_vector_type(4))) float f32x4;

// Workspace offsets (ushort units)
#define U_EXPR   0ull            // 8192*512
#define U_A192   4194304ull      // 8192*192  ([te1|tp])
#define U_H      5767168ull      // 8192*512
#define U_QKV    9961472ull      // 8192*1544
#define U_KN     26804224ull     // 8192*512
#define U_VT     30998528ull     // 32*64*2048
#define U_AO     35192832ull     // 8192*512
#define U_W1T    39387136ull     // 64*512
#define U_W2RAW  39419904ull     // 64*512
#define U_CATWT  39452672ull     // 512*768
#define U_QKVWT  39845888ull     // 1544*512
#define U_HEWT   40898560ull     // 512*512
#define U_WPRIME 41160704ull     // 512*192
#define U_WOHE   41259008ull     // 512*512
#define U_F32    41521152ull     // fp32 region (8192 floats)
#define U_ORAW   41537536ull     // 512*512 bf16, o_w native layout

// fp32 region layout (float offsets)
#define F_TDT    0
#define F_QKVB   512
#define F_BIASH  2056    // [4][512]
#define F_BIASEO 4104    // [512]
#define F_BIASPO 4616    // [4]
#define F_WHP    4620    // [512][3]

// d_out offsets (floats): (expr_out, pos_out, tdt)
#define DOUT_EXPR 0ull
#define DOUT_POS  4194304ull
#define DOUT_TDT  4218880ull

#define LOG2E 1.44269504088896340736f

static __device__ __forceinline__ ushort_t f2bf(float f) {
    union { float f; unsigned int u; } v; v.f = f;
    unsigned int r = (v.u + 0x7fffu + ((v.u >> 16) & 1u)) >> 16;
    return (ushort_t)r;
}
static __device__ __forceinline__ float bf2f(ushort_t u) {
    union { unsigned int u; float f; } v; v.u = ((unsigned int)u) << 16;
    return v.f;
}

// async global->LDS, 16B per lane; LDS dest = wave-uniform base + lane*16
static __device__ __forceinline__ void gload16(const void* g, void* l) {
    __builtin_amdgcn_global_load_lds(
        (const __attribute__((address_space(1))) void*)g,
        (__attribute__((address_space(3))) void*)l,
        16, 0, 0);
}

// ---------------------------------------------------------------------------
// Weight prep: mode 0 = transpose 64x64 tile (src[K][N] -> dst[n*dstStride+k]),
// mode 1 = convert-copy 16384-elem tile. Blocks >= 658: qkv bias gather.
// ---------------------------------------------------------------------------
struct WtSeg { const float* src; ushort_t* dst; int K, N, tK, tile0, dstStride, mode; };
struct WtTable { WtSeg s[10]; };

__global__ __launch_bounds__(256) void wt_transpose(
    WtTable tab, const float* __restrict__ qb, const float* __restrict__ kb,
    const float* __restrict__ vb, float* __restrict__ bias_dst)
{
    const int bid = blockIdx.x;
    const int tid = threadIdx.x;
    if (bid >= 658) {
        int t = (bid - 658) * 256 + tid;
        if (t < 520) bias_dst[t] = qb[t];
        else if (t < 1032) bias_dst[t] = kb[t - 520];
        else if (t < 1544) bias_dst[t] = vb[t - 1032];
        return;
    }
    int si = 0;
#pragma unroll
    for (int i = 1; i < 10; ++i)
        if (bid >= tab.s[i].tile0) si = i;
    const WtSeg sg = tab.s[si];
    const int local = bid - sg.tile0;

    if (sg.mode == 1) {
        long base = (long)local * 16384;
#pragma unroll
        for (int i = 0; i < 8; ++i) {
            long p = base + i * 2048 + tid * 8;
            float4 a = *(const float4*)&sg.src[p];
            float4 b = *(const float4*)&sg.src[p + 4];
            bf16x8 o;
            o[0] = (short)f2bf(a.x); o[1] = (short)f2bf(a.y);
            o[2] = (short)f2bf(a.z); o[3] = (short)f2bf(a.w);
            o[4] = (short)f2bf(b.x); o[5] = (short)f2bf(b.y);
            o[6] = (short)f2bf(b.z); o[7] = (short)f2bf(b.w);
            *(bf16x8*)&sg.dst[p] = o;
        }
        return;
    }

    __shared__ float t[64][65];
    const int k0 = (local % sg.tK) * 64;
    const int n0 = (local / sg.tK) * 64;
#pragma unroll
    for (int i = 0; i < 16; ++i) {
        int e = tid + i * 256;
        int r = e >> 6, c = e & 63;
        float v = 0.f;
        if (k0 + r < sg.K && n0 + c < sg.N)
            v = sg.src[(long)(k0 + r) * sg.N + n0 + c];
        t[r][c] = v;
    }
    __syncthreads();
#pragma unroll
    for (int i = 0; i < 16; ++i) {
        int e = tid + i * 256;
        int rn = e >> 6, ck = e & 63;
        if (n0 + rn < sg.N && k0 + ck < sg.K)
            sg.dst[(long)(n0 + rn) * sg.dstStride + k0 + ck] = f2bf(t[ck][rn]);
    }
}

// ---------------------------------------------------------------------------
// Bias folding (wave-per-output) — unchanged.
// ---------------------------------------------------------------------------
__global__ __launch_bounds__(256) void biasfold_kernel(
    const ushort_t* __restrict__ catwt, const ushort_t* __restrict__ hewt,
    const float* __restrict__ expr_b2, const float* __restrict__ tdt,
    const float* __restrict__ cat_b, const float* __restrict__ o_b,
    const float* __restrict__ he_b, const float* __restrict__ o_w,
    const float* __restrict__ hp_w, const float* __restrict__ hp_b,
    float* __restrict__ bias_h, float* __restrict__ bias_eo,
    float* __restrict__ whp, float* __restrict__ bias_po)
{
    const int wid = blockIdx.x * 4 + (threadIdx.x >> 6);
    const int lane = threadIdx.x & 63;
    float s = 0.f;
    if (wid < 2048) {
        int b = wid >> 9, n = wid & 511;
        bf16x8 wv = *(const bf16x8*)&catwt[(long)n * 768 + lane * 8];
        float4 e0 = *(const float4*)&expr_b2[lane * 8];
        float4 e1 = *(const float4*)&expr_b2[lane * 8 + 4];
        s = bf2f((ushort_t)wv[0]) * e0.x + bf2f((ushort_t)wv[1]) * e0.y +
            bf2f((ushort_t)wv[2]) * e0.z + bf2f((ushort_t)wv[3]) * e0.w +
            bf2f((ushort_t)wv[4]) * e1.x + bf2f((ushort_t)wv[5]) * e1.y +
            bf2f((ushort_t)wv[6]) * e1.z + bf2f((ushort_t)wv[7]) * e1.w;
        float2 tt = *(const float2*)&tdt[b * 128 + lane * 2];
        s += bf2f(catwt[(long)n * 768 + 512 + lane * 2]) * tt.x;
        s += bf2f(catwt[(long)n * 768 + 513 + lane * 2]) * tt.y;
#pragma unroll
        for (int o = 32; o >= 1; o >>= 1) s += __shfl_xor(s, o);
        if (lane == 0) bias_h[b * 512 + n] = s + cat_b[n];
    } else if (wid < 2560) {
        int n = wid - 2048;
        bf16x8 wv = *(const bf16x8*)&hewt[(long)n * 512 + lane * 8];
        float4 e0 = *(const float4*)&o_b[lane * 8];
        float4 e1 = *(const float4*)&o_b[lane * 8 + 4];
        s = bf2f((ushort_t)wv[0]) * e0.x + bf2f((ushort_t)wv[1]) * e0.y +
            bf2f((ushort_t)wv[2]) * e0.z + bf2f((ushort_t)wv[3]) * e0.w +
            bf2f((ushort_t)wv[4]) * e1.x + bf2f((ushort_t)wv[5]) * e1.y +
            bf2f((ushort_t)wv[6]) * e1.z + bf2f((ushort_t)wv[7]) * e1.w;
#pragma unroll
        for (int o = 32; o >= 1; o >>= 1) s += __shfl_xor(s, o);
        if (lane == 0) bias_eo[n] = s + he_b[n];
    } else if (wid < 4096) {
        int t = wid - 2560;
        int c = t >> 9, k = t & 511;
#pragma unroll
        for (int i = 0; i < 8; ++i) {
            int j = i * 64 + lane;
            s = fmaf(o_w[(long)k * 512 + j], hp_w[j * 3 + c], s);
        }
#pragma unroll
        for (int o = 32; o >= 1; o >>= 1) s += __shfl_xor(s, o);
        if (lane == 0) whp[k * 3 + c] = s;
    } else if (wid < 4099) {
        int c = wid - 4096;
#pragma unroll
        for (int i = 0; i < 8; ++i) {
            int j = i * 64 + lane;
            s = fmaf(o_b[j], hp_w[j * 3 + c], s);
        }
#pragma unroll
        for (int o = 32; o >= 1; o >>= 1) s += __shfl_xor(s, o);
        if (lane == 0) bias_po[c] = s + hp_b[c];
    }
}

// ---------------------------------------------------------------------------
// bf16 MFMA GEMM — unchanged (global_load_lds, swizzled source).
// ---------------------------------------------------------------------------
template <int RELU, int OUT_BF16, int HASBIAS, int BBSTRIDE>
__global__ __launch_bounds__(512) void hgemm(
    const ushort_t* __restrict__ A, int lda,
    const ushort_t* __restrict__ Wt, int ldw,
    const float* __restrict__ bias,
    void* __restrict__ Cv, int ldc,
    int N, int K)
{
    __shared__ __align__(16) ushort_t As[128 * 64];
    __shared__ __align__(16) ushort_t Bs[128 * 64];

    const int tid = threadIdx.x;
    const int lane = tid & 63, w = tid >> 6;
    const int lo = lane & 15, hi = lane >> 4;
    const int wm = w >> 2, wn = w & 3;
    const long m0 = (long)blockIdx.y * 128;
    const int n0 = blockIdx.x * 128;

    f32x4 acc[4][2];
#pragma unroll
    for (int mt = 0; mt < 4; ++mt)
#pragma unroll
        for (int nt = 0; nt < 2; ++nt) acc[mt][nt] = (f32x4)0.f;

    for (int kt = 0; kt < K; kt += 64) {
#pragma unroll
        for (int i = 0; i < 2; ++i) {
            int c = w * 128 + i * 64 + lane;
            int r = c >> 3, ch = c & 7;
            int sch = ch ^ (r & 7);
            gload16(&A[(m0 + r) * (long)lda + kt + sch * 8],
                    &As[(w * 128 + i * 64) * 8]);
            gload16(&Wt[(long)(n0 + r) * ldw + kt + sch * 8],
                    &Bs[(w * 128 + i * 64) * 8]);
        }
        __syncthreads();

#pragma unroll
        for (int ks = 0; ks < 2; ++ks) {
            bf16x8 af[4], bfr[2];
#pragma unroll
            for (int mt = 0; mt < 4; ++mt) {
                int m = wm * 64 + mt * 16 + lo;
                af[mt] = *(const bf16x8*)&As[m * 64 + (((ks * 4 + hi) ^ (lo & 7)) * 8)];
            }
#pragma unroll
            for (int nt = 0; nt < 2; ++nt) {
                int n = wn * 32 + nt * 16 + lo;
                bfr[nt] = *(const bf16x8*)&Bs[n * 64 + (((ks * 4 + hi) ^ (lo & 7)) * 8)];
            }
#pragma unroll
            for (int mt = 0; mt < 4; ++mt)
#pragma unroll
                for (int nt = 0; nt < 2; ++nt)
                    acc[mt][nt] = __builtin_amdgcn_mfma_f32_16x16x32_bf16(
                        af[mt], bfr[nt], acc[mt][nt], 0, 0, 0);
        }
        __syncthreads();
    }

#pragma unroll
    for (int mt = 0; mt < 4; ++mt)
#pragma unroll
        for (int nt = 0; nt < 2; ++nt) {
            int col = n0 + wn * 32 + nt * 16 + lo;
            if (col < N) {
                float bv = 0.f;
                if (HASBIAS)
                    bv = BBSTRIDE ? bias[(int)(m0 >> 11) * BBSTRIDE + col] : bias[col];
#pragma unroll
                for (int r = 0; r < 4; ++r) {
                    long row = m0 + wm * 64 + mt * 16 + hi * 4 + r;
                    float v = acc[mt][nt][r] + bv;
                    if (RELU) v = fmaxf(v, 0.f);
                    if (OUT_BF16) ((ushort_t*)Cv)[row * (long)ldc + col] = f2bf(v);
                    else          ((float*)Cv)[row * (long)ldc + col] = v;
                }
            }
        }
}

// ---------------------------------------------------------------------------
// Position MLP -> a192[:, 64:192] (bf16) — unchanged.
// ---------------------------------------------------------------------------
__global__ __launch_bounds__(128) void posmlp_kernel(
    const float* __restrict__ pos,
    const float* __restrict__ w1, const float* __restrict__ b1,
    const float* __restrict__ w2, const float* __restrict__ b2,
    ushort_t* __restrict__ a192)
{
    __shared__ __align__(16) float w1s[256];
    __shared__ __align__(16) float b1s[64];
    __shared__ __align__(16) float w2t[128 * 64];
    __shared__ __align__(16) float b2s[128];

    const int tid = threadIdx.x;
    for (int i = tid; i < 256; i += 128) w1s[i] = w1[i];
    if (tid < 64) b1s[tid] = b1[tid];
    b2s[tid] = b2[tid];
    for (int i = tid; i < 8192; i += 128) {
        int k = i >> 7, o = i & 127;
        w2t[o * 64 + k] = w2[i];
    }
    __syncthreads();

    const long r = (long)blockIdx.x * 128 + tid;
    float px = pos[r * 3 + 0], py = pos[r * 3 + 1], pz = pos[r * 3 + 2];
    float nrm = sqrtf(px * px + py * py + pz * pz);
    float inv = 1.f / (nrm + 1e-7f);
    float pf0 = px * inv, pf1 = py * inv, pf2 = pz * inv, pf3 = nrm;

    float h1[64];
#pragma unroll
    for (int o = 0; o < 64; ++o) {
        float a = b1s[o];
        a = fmaf(pf0, w1s[o], a);
        a = fmaf(pf1, w1s[64 + o], a);
        a = fmaf(pf2, w1s[128 + o], a);
        a = fmaf(pf3, w1s[192 + o], a);
        h1[o] = fmaxf(a, 0.f);
    }
    ushort_t* dst = &a192[r * 192 + 64];
    for (int o = 0; o < 128; ++o) {
        float s = b2s[o];
#pragma unroll
        for (int i4 = 0; i4 < 16; ++i4) {
            float4 wv = *(const float4*)&w2t[o * 64 + i4 * 4];
            s = fmaf(h1[i4 * 4 + 0], wv.x, s);
            s = fmaf(h1[i4 * 4 + 1], wv.y, s);
            s = fmaf(h1[i4 * 4 + 2], wv.z, s);
            s = fmaf(h1[i4 * 4 + 3], wv.w, s);
        }
        dst[o] = f2bf(s);
    }
}

// tdt = diffusion_time @ yy_w + yy_b (fp32, exact)
__global__ __launch_bounds__(512) void tdt_kernel(
    const float* __restrict__ dt, const float* __restrict__ yyw,
    const float* __restrict__ yyb, float* __restrict__ tdt_ws,
    float* __restrict__ out_tail)
{
    const int t = threadIdx.x;
    const int b = t >> 7, o = t & 127;
    float s = yyb[o];
    for (int k = 0; k < 128; ++k) s = fmaf(dt[b * 128 + k], yyw[k * 128 + o], s);
    tdt_ws[t] = s;
    out_tail[t] = s;
}

// ---------------------------------------------------------------------------
// qkv postprocess: K rmsnorm + V transpose — unchanged.
// ---------------------------------------------------------------------------
__global__ __launch_bounds__(256) void qkvpost_kernel(
    const ushort_t* __restrict__ qkv, const float* __restrict__ knw,
    ushort_t* __restrict__ kn, ushort_t* __restrict__ Vt)
{
    __shared__ ushort_t t[64][72];
    __shared__ float knw_s[64];
    const int bh = blockIdx.x, b = bh >> 3, h = bh & 7;
    const int n0 = blockIdx.y * 64;
    const int tid = threadIdx.x;
    if (tid < 64) knw_s[tid] = knw[tid];
#pragma unroll
    for (int i = 0; i < 2; ++i) {
        int c = tid + i * 256;
        int r = c >> 3, ch = c & 7;
        *(bf16x8*)&t[r][ch * 8] =
            *(const bf16x8*)&qkv[(long)(b * SEQ + n0 + r) * 1544 + 1032 + h * 64 + ch * 8];
    }
    __syncthreads();
#pragma unroll
    for (int i = 0; i < 2; ++i) {
        int c = tid + i * 256;
        int r = c >> 3, ch = c & 7;
        bf16x8 kv = *(const bf16x8*)&qkv[(long)(b * SEQ + n0 + r) * 1544 + 520 + h * 64 + ch * 8];
        float x[8], ss = 0.f;
#pragma unroll
        for (int j = 0; j < 8; ++j) { x[j] = bf2f((ushort_t)kv[j]); ss = fmaf(x[j], x[j], ss); }
        ss += __shfl_xor(ss, 1);
        ss += __shfl_xor(ss, 2);
        ss += __shfl_xor(ss, 4);
        float invr = rsqrtf(ss * (1.f / 64.f) + 1e-6f);
        bf16x8 o;
#pragma unroll
        for (int j = 0; j < 8; ++j) o[j] = (short)f2bf(x[j] * knw_s[ch * 8 + j] * invr);
        *(bf16x8*)&kn[(long)(b * SEQ + n0 + r) * 512 + h * 64 + ch * 8] = o;
    }
    const int d = tid >> 2;
#pragma unroll
    for (int i = 0; i < 2; ++i) {
        int cc = (tid & 3) * 2 + i;
        bf16x8 pk;
#pragma unroll
        for (int j = 0; j < 8; ++j) pk[j] = (short)t[cc * 8 + j][d];
        *(bf16x8*)&Vt[((long)(bh * 64 + d)) * SEQ + n0 + cc * 8] = pk;
    }
}

// ---------------------------------------------------------------------------
// Flash attention, bf16 MFMA 16x16x32.
// Double-buffered K/V LDS, ONE barrier per K-tile: iter kt writes prefetched
// regs(t+1) into buf[nxt] (its readers finished pre-barrier), issues global
// prefetch t+2 (covered by compute), computes on buf[cur], barriers.
// Q rmsnorm fused inline (scale folds 0.125*log2e); softmax via raw
// v_exp_f32 in exp2 domain; swapped QK^T; packed P writes.
// grid (32 bh, 16), block 256 (4 waves x 32 q rows). LDS 48KB.
// ---------------------------------------------------------------------------
__global__ __launch_bounds__(256) void flash_attn_mfma(
    const ushort_t* __restrict__ QKV, const ushort_t* __restrict__ Kn,
    const ushort_t* __restrict__ Vt, const float* __restrict__ qnw,
    ushort_t* __restrict__ AO)
{
    __shared__ __align__(16) ushort_t Ks[2][64 * 64];
    __shared__ __align__(16) ushort_t Vs[2][64 * 64];
    __shared__ __align__(16) ushort_t Ps[4][32 * 64];

    const int tid = threadIdx.x;
    const int lane = tid & 63;
    const int w = tid >> 6;
    const int lo = lane & 15, hi = lane >> 4;
    const int bh = blockIdx.x, b = bh >> 3, h = bh & 7;
    const int qb = blockIdx.y * 128 + w * 32;

    // ---- Q load + inline rmsnorm ----
    bf16x8 qfrag[2][2];
    {
        float qw[2][8];
#pragma unroll
        for (int ks = 0; ks < 2; ++ks)
#pragma unroll
            for (int j = 0; j < 8; ++j)
                qw[ks][j] = qnw[ks * 32 + hi * 8 + j];
#pragma unroll
        for (int jt = 0; jt < 2; ++jt) {
            float qx[2][8], ss = 0.f;
#pragma unroll
            for (int ks = 0; ks < 2; ++ks) {
                bf16x8 q = *(const bf16x8*)&QKV[(long)(b * SEQ + qb + jt * 16 + lo) * 1544 +
                                                h * 64 + ks * 32 + hi * 8];
#pragma unroll
                for (int j = 0; j < 8; ++j) {
                    qx[ks][j] = bf2f((ushort_t)q[j]);
                    ss = fmaf(qx[ks][j], qx[ks][j], ss);
                }
            }
            ss += __shfl_xor(ss, 16);
            ss += __shfl_xor(ss, 32);
            float invr = rsqrtf(ss * (1.f / 64.f) + 1e-6f) * (0.125f * LOG2E);
#pragma unroll
            for (int ks = 0; ks < 2; ++ks) {
                bf16x8 f;
#pragma unroll
                for (int j = 0; j < 8; ++j)
                    f[j] = (short)f2bf(qx[ks][j] * qw[ks][j] * invr);
                qfrag[jt][ks] = f;
            }
        }
    }

    f32x4 accO[2][4];
#pragma unroll
    for (int mt = 0; mt < 2; ++mt)
#pragma unroll
        for (int nt = 0; nt < 4; ++nt) accO[mt][nt] = (f32x4)0.f;
    float l_part[2] = {0.f, 0.f};

    const int sr0 = tid >> 3, sc0 = tid & 7;
    const int sr1 = (tid + 256) >> 3, sc1 = tid & 7;
    const int wo0 = sr0 * 64 + ((sc0 ^ (sr0 & 7)) * 8);
    const int wo1 = sr1 * 64 + ((sc1 ^ (sr1 & 7)) * 8);

    bf16x8 kreg0, kreg1, vreg0, vreg1;
    // prologue: tile 0 -> buf0; prefetch tile 1
    kreg0 = *(const bf16x8*)&Kn[(b * SEQ + sr0) * 512 + h * 64 + sc0 * 8];
    vreg0 = *(const bf16x8*)&Vt[((long)(bh * 64 + sr0)) * SEQ + sc0 * 8];
    kreg1 = *(const bf16x8*)&Kn[(b * SEQ + sr1) * 512 + h * 64 + sc1 * 8];
    vreg1 = *(const bf16x8*)&Vt[((long)(bh * 64 + sr1)) * SEQ + sc1 * 8];
    *(bf16x8*)&Ks[0][wo0] = kreg0;
    *(bf16x8*)&Vs[0][wo0] = vreg0;
    *(bf16x8*)&Ks[0][wo1] = kreg1;
    *(bf16x8*)&Vs[0][wo1] = vreg1;
    kreg0 = *(const bf16x8*)&Kn[(b * SEQ + 64 + sr0) * 512 + h * 64 + sc0 * 8];
    vreg0 = *(const bf16x8*)&Vt[((long)(bh * 64 + sr0)) * SEQ + 64 + sc0 * 8];
    kreg1 = *(const bf16x8*)&Kn[(b * SEQ + 64 + sr1) * 512 + h * 64 + sc1 * 8];
    vreg1 = *(const bf16x8*)&Vt[((long)(bh * 64 + sr1)) * SEQ + 64 + sc1 * 8];
    __syncthreads();

    auto step = [&](int kt, int cur, int nxt) {
        // write regs (tile kt+1) -> buf[nxt]; its readers finished pre-barrier
        if (kt + 1 < 32) {
            *(bf16x8*)&Ks[nxt][wo0] = kreg0;
            *(bf16x8*)&Vs[nxt][wo0] = vreg0;
            *(bf16x8*)&Ks[nxt][wo1] = kreg1;
            *(bf16x8*)&Vs[nxt][wo1] = vreg1;
        }
        // prefetch tile kt+2 (lands during compute)
        if (kt + 2 < 32) {
            int nk = (kt + 2) * 64;
            kreg0 = *(const bf16x8*)&Kn[(b * SEQ + nk + sr0) * 512 + h * 64 + sc0 * 8];
            vreg0 = *(const bf16x8*)&Vt[((long)(bh * 64 + sr0)) * SEQ + nk + sc0 * 8];
            kreg1 = *(const bf16x8*)&Kn[(b * SEQ + nk + sr1) * 512 + h * 64 + sc1 * 8];
            vreg1 = *(const bf16x8*)&Vt[((long)(bh * 64 + sr1)) * SEQ + nk + sc1 * 8];
        }

        // ---- S^T = K * Q^T on buf[cur] ----
        f32x4 accS[4][2];
#pragma unroll
        for (int it = 0; it < 4; ++it)
#pragma unroll
            for (int jt = 0; jt < 2; ++jt) accS[it][jt] = (f32x4)0.f;

#pragma unroll
        for (int it = 0; it < 4; ++it) {
            bf16x8 kf[2];
#pragma unroll
            for (int ks = 0; ks < 2; ++ks)
                kf[ks] = *(const bf16x8*)&Ks[cur][(it * 16 + lo) * 64 +
                                                 (((ks * 4 + hi) ^ (lo & 7)) * 8)];
#pragma unroll
            for (int jt = 0; jt < 2; ++jt)
#pragma unroll
                for (int ks = 0; ks < 2; ++ks)
                    accS[it][jt] = __builtin_amdgcn_mfma_f32_16x16x32_bf16(
                        kf[ks], qfrag[jt][ks], accS[it][jt], 0, 0, 0);
        }

        // ---- p = 2^s; pack; b64 write ----
#pragma unroll
        for (int it = 0; it < 4; ++it)
#pragma unroll
            for (int jt = 0; jt < 2; ++jt) {
                float p0, p1, p2, p3;
                asm("v_exp_f32 %0, %1" : "=v"(p0) : "v"(accS[it][jt][0]));
                asm("v_exp_f32 %0, %1" : "=v"(p1) : "v"(accS[it][jt][1]));
                asm("v_exp_f32 %0, %1" : "=v"(p2) : "v"(accS[it][jt][2]));
                asm("v_exp_f32 %0, %1" : "=v"(p3) : "v"(accS[it][jt][3]));
                l_part[jt] += (p0 + p1) + (p2 + p3);
                unsigned w0, w1;
                asm("v_cvt_pk_bf16_f32 %0, %1, %2" : "=v"(w0) : "v"(p0), "v"(p1));
                asm("v_cvt_pk_bf16_f32 %0, %1, %2" : "=v"(w1) : "v"(p2), "v"(p3));
                int q = jt * 16 + lo;
                int cch = it * 2 + (hi >> 1);
                int off = q * 64 + ((cch ^ (q & 7)) * 8) + (hi & 1) * 4;
                uint2 t; t.x = w0; t.y = w1;
                *(uint2*)&Ps[w][off] = t;
            }

        // ---- O += P * V^T on buf[cur] ----
#pragma unroll
        for (int kk = 0; kk < 2; ++kk) {
            bf16x8 pf[2];
#pragma unroll
            for (int mt = 0; mt < 2; ++mt)
                pf[mt] = *(const bf16x8*)&Ps[w][(mt * 16 + lo) * 64 +
                                               (((kk * 4 + hi) ^ (lo & 7)) * 8)];
#pragma unroll
            for (int nt = 0; nt < 4; ++nt) {
                bf16x8 vf = *(const bf16x8*)&Vs[cur][(nt * 16 + lo) * 64 +
                                                    (((kk * 4 + hi) ^ (lo & 7)) * 8)];
#pragma unroll
                for (int mt = 0; mt < 2; ++mt)
                    accO[mt][nt] = __builtin_amdgcn_mfma_f32_16x16x32_bf16(
                        pf[mt], vf, accO[mt][nt], 0, 0, 0);
            }
        }
        __syncthreads();
    };

    for (int kt = 0; kt < 32; kt += 2) {
        step(kt, 0, 1);
        step(kt + 1, 1, 0);
    }

#pragma unroll
    for (int jt = 0; jt < 2; ++jt) {
        l_part[jt] += __shfl_xor(l_part[jt], 16);
        l_part[jt] += __shfl_xor(l_part[jt], 32);
    }

#pragma unroll
    for (int mt = 0; mt < 2; ++mt)
#pragma unroll
        for (int r = 0; r < 4; ++r) {
            float lq = __shfl(l_part[mt], hi * 4 + r);
            int grow = b * SEQ + qb + mt * 16 + hi * 4 + r;
            float g = bf2f(QKV[(long)grow * 1544 + 512 + h]);
            g = 1.f / (1.f + __expf(-g));
            float sc = g / lq;
#pragma unroll
            for (int nt = 0; nt < 4; ++nt)
                AO[(long)grow * 512 + h * 64 + nt * 16 + lo] = f2bf(accO[mt][nt][r] * sc);
        }
}

// pos_out = ao @ whp + bias_po (bf16 in, fp32 fold weights)
__global__ __launch_bounds__(256) void posout_kernel(
    const ushort_t* __restrict__ ao, const float* __restrict__ whp,
    const float* __restrict__ bpo, float* __restrict__ po)
{
    const int lane = threadIdx.x & 63;
    const long row = (long)blockIdx.x * 4 + (threadIdx.x >> 6);
    float p0 = 0.f, p1 = 0.f, p2 = 0.f;
#pragma unroll
    for (int it = 0; it < 8; ++it) {
        int k = it * 64 + lane;
        float x = bf2f(ao[row * 512 + k]);
        p0 = fmaf(x, whp[k * 3 + 0], p0);
        p1 = fmaf(x, whp[k * 3 + 1], p1);
        p2 = fmaf(x, whp[k * 3 + 2], p2);
    }
#pragma unroll
    for (int o = 32; o >= 1; o >>= 1) {
        p0 += __shfl_xor(p0, o);
        p1 += __shfl_xor(p1, o);
        p2 += __shfl_xor(p2, o);
    }
    if (lane == 0) {
        po[row * 3 + 0] = p0 + bpo[0];
        po[row * 3 + 1] = p1 + bpo[1];
        po[row * 3 + 2] = p2 + bpo[2];
    }
}

// ---------------------------------------------------------------------------
extern "C" void kernel_launch(void* const* d_in, const int* in_sizes, int n_in,
                              void* d_out, int out_size, void* d_ws, size_t ws_size,
                              hipStream_t stream)
{
    const float* expr    = (const float*)d_in[0];
    const float* dtime   = (const float*)d_in[1];
    const float* posf    = (const float*)d_in[2];
    const float* pos_w1  = (const float*)d_in[3];
    const float* pos_b1  = (const float*)d_in[4];
    const float* pos_w2  = (const float*)d_in[5];
    const float* pos_b2  = (const float*)d_in[6];
    const float* expr_w1 = (const float*)d_in[7];
    const float* expr_b1 = (const float*)d_in[8];
    const float* expr_w2 = (const float*)d_in[9];
    const float* expr_b2 = (const float*)d_in[10];
    const float* yy_w    = (const float*)d_in[11];
    const float* yy_b    = (const float*)d_in[12];
    const float* cat_w   = (const float*)d_in[13];
    const float* cat_b   = (const float*)d_in[14];
    const float* q_w     = (const float*)d_in[15];
    const float* q_b     = (const float*)d_in[16];
    const float* k_w     = (const float*)d_in[17];
    const float* k_b     = (const float*)d_in[18];
    const float* v_w     = (const float*)d_in[19];
    const float* v_b     = (const float*)d_in[20];
    const float* o_w     = (const float*)d_in[21];
    const float* o_b     = (const float*)d_in[22];
    const float* qn_w    = (const float*)d_in[23];
    const float* kn_w    = (const float*)d_in[24];
    const float* hp_w    = (const float*)d_in[25];
    const float* hp_b    = (const float*)d_in[26];
    const float* he_w    = (const float*)d_in[27];
    const float* he_b    = (const float*)d_in[28];
    (void)in_sizes; (void)n_in; (void)out_size; (void)ws_size;

    ushort_t* wsb     = (ushort_t*)d_ws;
    ushort_t* expr_bf = wsb + U_EXPR;
    ushort_t* a192    = wsb + U_A192;
    ushort_t* h_bf    = wsb + U_H;
    ushort_t* qkv_bf  = wsb + U_QKV;
    ushort_t* kn_bf   = wsb + U_KN;
    ushort_t* vt_bf   = wsb + U_VT;
    ushort_t* ao_bf   = wsb + U_AO;
    ushort_t* w1t     = wsb + U_W1T;
    ushort_t* w2raw   = wsb + U_W2RAW;
    ushort_t* cat_wt  = wsb + U_CATWT;
    ushort_t* qkv_wt  = wsb + U_QKVWT;
    ushort_t* he_wt   = wsb + U_HEWT;
    ushort_t* wprime  = wsb + U_WPRIME;
    ushort_t* wohe    = wsb + U_WOHE;
    ushort_t* o_raw   = wsb + U_ORAW;
    float* f32r       = (float*)(wsb + U_F32);
    float* tdt        = f32r + F_TDT;
    float* qkv_bias   = f32r + F_QKVB;
    float* bias_h     = f32r + F_BIASH;
    float* bias_eo    = f32r + F_BIASEO;
    float* bias_po    = f32r + F_BIASPO;
    float* whp        = f32r + F_WHP;
    float* dout       = (float*)d_out;

    const dim3 blk(256);
    const dim3 blk512(512);

    // --- prep: all converts/transposes in ONE kernel ---
    WtTable tab;
    //            src              dst               K    N   tK tile0 dstS mode
    tab.s[0] = { expr_w1,          w1t,             512,  64,  8,   0, 512, 0 };  //   8
    tab.s[1] = { cat_w,            cat_wt,          768, 512, 12,   8, 768, 0 };  //  96
    tab.s[2] = { q_w,              qkv_wt,          512, 520,  8, 104, 512, 0 };  //  72
    tab.s[3] = { k_w,              qkv_wt + 520*512,512, 512,  8, 176, 512, 0 };  //  64
    tab.s[4] = { v_w,              qkv_wt +1032*512,512, 512,  8, 240, 512, 0 };  //  64
    tab.s[5] = { he_w,             he_wt,           512, 512,  8, 304, 512, 0 };  //  64
    tab.s[6] = { cat_w + 640*512,  wprime + 64,     128, 512,  2, 368, 192, 0 };  //  16
    tab.s[7] = { expr_w2,          w2raw,             0,   0,  0, 384,   0, 1 };  //   2
    tab.s[8] = { o_w,              o_raw,             0,   0,  0, 386,   0, 1 };  //  16
    tab.s[9] = { expr,             expr_bf,           0,   0,  0, 402,   0, 1 };  // 256 -> 658
    wt_transpose<<<dim3(665), blk, 0, stream>>>(tab, q_b, k_b, v_b, qkv_bias);

    tdt_kernel<<<dim3(1), dim3(512), 0, stream>>>(dtime, yy_w, yy_b, tdt,
                                                  dout + DOUT_TDT);
    biasfold_kernel<<<dim3(1025), blk, 0, stream>>>(
        cat_wt, he_wt, expr_b2, tdt, cat_b, o_b, he_b, o_w, hp_w, hp_b,
        bias_h, bias_eo, whp, bias_po);
    // W'[:, :64] = (expr_w2 @ cat_w0)^T rows
    hgemm<0, 1, 0, 0><<<dim3(1, 4), blk512, 0, stream>>>(cat_wt, 768, w2raw, 512,
                                                         nullptr, wprime, 192, 64, 512);
    // wohe[n][k] = sum_i he_w[i][n] * o_w[k][i]  (B-operand = NATIVE o_w)
    hgemm<0, 1, 0, 0><<<dim3(4, 4), blk512, 0, stream>>>(he_wt, 512, o_raw, 512,
                                                         nullptr, wohe, 512, 512, 512);

    // --- pipeline ---
    hgemm<1, 1, 1, 0><<<dim3(1, 64), blk512, 0, stream>>>(expr_bf, 512, w1t, 512,
                                                          expr_b1, a192, 192, 64, 512);
    posmlp_kernel<<<dim3(64), dim3(128), 0, stream>>>(posf, pos_w1, pos_b1,
                                                      pos_w2, pos_b2, a192);
    hgemm<0, 1, 1, 512><<<dim3(4, 64), blk512, 0, stream>>>(a192, 192, wprime, 192,
                                                            bias_h, h_bf, 512, 512, 192);
    hgemm<0, 1, 1, 0><<<dim3(13, 64), blk512, 0, stream>>>(h_bf, 512, qkv_wt, 512,
                                                           qkv_bias, qkv_bf, 1544, 1544, 512);
    qkvpost_kernel<<<dim3(32, 32), blk, 0, stream>>>(qkv_bf, kn_w, kn_bf, vt_bf);
    flash_attn_mfma<<<dim3(32, 16), blk, 0, stream>>>(qkv_bf, kn_bf, vt_bf, qn_w, ao_bf);
    hgemm<0, 0, 1, 0><<<dim3(4, 64), blk512, 0, stream>>>(ao_bf, 512, wohe, 512,
                                                          bias_eo, dout + DOUT_EXPR,
                                                          512, 512, 512);
    posout_kernel<<<dim3(2048), blk, 0, stream>>>(ao_bf, whp, bias_po,
                                                  dout + DOUT_POS);
}

// Round 10
// 169.364 us; speedup vs baseline: 10.4191x; 1.2688x over previous
//
#include <hip/hip_runtime.h>
#include <math.h>

// Problem constants
#define SEQ   2048
#define NROWS 8192   // B*N

typedef unsigned short ushort_t;
typedef __attribute__((ext_vector_type(8))) short bf16x8;
typedef __attribute__((ext_vector_type(4))) float f32x4;

// Workspace offsets (ushort units)
#define U_EXPR   0ull            // 8192*512
#define U_A192   4194304ull      // 8192*192  ([te1|tp])
#define U_H      5767168ull      // 8192*512
#define U_QKV    9961472ull      // 8192*1544
#define U_KN     26804224ull     // 8192*512
#define U_VT     30998528ull     // 32*64*2048
#define U_AO     35192832ull     // 8192*512
#define U_W1T    39387136ull     // 64*512
#define U_W2RAW  39419904ull     // 64*512
#define U_CATWT  39452672ull     // 512*768
#define U_QKVWT  39845888ull     // 1544*512
#define U_HEWT   40898560ull     // 512*512
#define U_WPRIME 41160704ull     // 512*192
#define U_WOHE   41259008ull     // 512*512
#define U_F32    41521152ull     // fp32 region (8192 floats)
#define U_ORAW   41537536ull     // 512*512 bf16, o_w native layout

// fp32 region layout (float offsets)
#define F_TDT    0
#define F_QKVB   512
#define F_BIASH  2056    // [4][512]
#define F_BIASEO 4104    // [512]
#define F_BIASPO 4616    // [4]
#define F_WHP    4620    // [512][3]

// d_out offsets (floats): (expr_out, pos_out, tdt)
#define DOUT_EXPR 0ull
#define DOUT_POS  4194304ull
#define DOUT_TDT  4218880ull

#define LOG2E 1.44269504088896340736f

static __device__ __forceinline__ ushort_t f2bf(float f) {
    union { float f; unsigned int u; } v; v.f = f;
    unsigned int r = (v.u + 0x7fffu + ((v.u >> 16) & 1u)) >> 16;
    return (ushort_t)r;
}
static __device__ __forceinline__ float bf2f(ushort_t u) {
    union { unsigned int u; float f; } v; v.u = ((unsigned int)u) << 16;
    return v.f;
}

// async global->LDS, 16B per lane; LDS dest = wave-uniform base + lane*16
static __device__ __forceinline__ void gload16(const void* g, void* l) {
    __builtin_amdgcn_global_load_lds(
        (const __attribute__((address_space(1))) void*)g,
        (__attribute__((address_space(3))) void*)l,
        16, 0, 0);
}

// ---------------------------------------------------------------------------
// Weight prep: mode 0 = transpose 64x64 tile (src[K][N] -> dst[n*dstStride+k]),
// mode 1 = convert-copy 16384-elem tile. Blocks >= 658: qkv bias gather.
// ---------------------------------------------------------------------------
struct WtSeg { const float* src; ushort_t* dst; int K, N, tK, tile0, dstStride, mode; };
struct WtTable { WtSeg s[10]; };

__global__ __launch_bounds__(256) void wt_transpose(
    WtTable tab, const float* __restrict__ qb, const float* __restrict__ kb,
    const float* __restrict__ vb, float* __restrict__ bias_dst)
{
    const int bid = blockIdx.x;
    const int tid = threadIdx.x;
    if (bid >= 658) {
        int t = (bid - 658) * 256 + tid;
        if (t < 520) bias_dst[t] = qb[t];
        else if (t < 1032) bias_dst[t] = kb[t - 520];
        else if (t < 1544) bias_dst[t] = vb[t - 1032];
        return;
    }
    int si = 0;
#pragma unroll
    for (int i = 1; i < 10; ++i)
        if (bid >= tab.s[i].tile0) si = i;
    const WtSeg sg = tab.s[si];
    const int local = bid - sg.tile0;

    if (sg.mode == 1) {
        long base = (long)local * 16384;
#pragma unroll
        for (int i = 0; i < 8; ++i) {
            long p = base + i * 2048 + tid * 8;
            float4 a = *(const float4*)&sg.src[p];
            float4 b = *(const float4*)&sg.src[p + 4];
            bf16x8 o;
            o[0] = (short)f2bf(a.x); o[1] = (short)f2bf(a.y);
            o[2] = (short)f2bf(a.z); o[3] = (short)f2bf(a.w);
            o[4] = (short)f2bf(b.x); o[5] = (short)f2bf(b.y);
            o[6] = (short)f2bf(b.z); o[7] = (short)f2bf(b.w);
            *(bf16x8*)&sg.dst[p] = o;
        }
        return;
    }

    __shared__ float t[64][65];
    const int k0 = (local % sg.tK) * 64;
    const int n0 = (local / sg.tK) * 64;
#pragma unroll
    for (int i = 0; i < 16; ++i) {
        int e = tid + i * 256;
        int r = e >> 6, c = e & 63;
        float v = 0.f;
        if (k0 + r < sg.K && n0 + c < sg.N)
            v = sg.src[(long)(k0 + r) * sg.N + n0 + c];
        t[r][c] = v;
    }
    __syncthreads();
#pragma unroll
    for (int i = 0; i < 16; ++i) {
        int e = tid + i * 256;
        int rn = e >> 6, ck = e & 63;
        if (n0 + rn < sg.N && k0 + ck < sg.K)
            sg.dst[(long)(n0 + rn) * sg.dstStride + k0 + ck] = f2bf(t[ck][rn]);
    }
}

// ---------------------------------------------------------------------------
// Bias folding (wave-per-output) — unchanged.
// ---------------------------------------------------------------------------
__global__ __launch_bounds__(256) void biasfold_kernel(
    const ushort_t* __restrict__ catwt, const ushort_t* __restrict__ hewt,
    const float* __restrict__ expr_b2, const float* __restrict__ tdt,
    const float* __restrict__ cat_b, const float* __restrict__ o_b,
    const float* __restrict__ he_b, const float* __restrict__ o_w,
    const float* __restrict__ hp_w, const float* __restrict__ hp_b,
    float* __restrict__ bias_h, float* __restrict__ bias_eo,
    float* __restrict__ whp, float* __restrict__ bias_po)
{
    const int wid = blockIdx.x * 4 + (threadIdx.x >> 6);
    const int lane = threadIdx.x & 63;
    float s = 0.f;
    if (wid < 2048) {
        int b = wid >> 9, n = wid & 511;
        bf16x8 wv = *(const bf16x8*)&catwt[(long)n * 768 + lane * 8];
        float4 e0 = *(const float4*)&expr_b2[lane * 8];
        float4 e1 = *(const float4*)&expr_b2[lane * 8 + 4];
        s = bf2f((ushort_t)wv[0]) * e0.x + bf2f((ushort_t)wv[1]) * e0.y +
            bf2f((ushort_t)wv[2]) * e0.z + bf2f((ushort_t)wv[3]) * e0.w +
            bf2f((ushort_t)wv[4]) * e1.x + bf2f((ushort_t)wv[5]) * e1.y +
            bf2f((ushort_t)wv[6]) * e1.z + bf2f((ushort_t)wv[7]) * e1.w;
        float2 tt = *(const float2*)&tdt[b * 128 + lane * 2];
        s += bf2f(catwt[(long)n * 768 + 512 + lane * 2]) * tt.x;
        s += bf2f(catwt[(long)n * 768 + 513 + lane * 2]) * tt.y;
#pragma unroll
        for (int o = 32; o >= 1; o >>= 1) s += __shfl_xor(s, o);
        if (lane == 0) bias_h[b * 512 + n] = s + cat_b[n];
    } else if (wid < 2560) {
        int n = wid - 2048;
        bf16x8 wv = *(const bf16x8*)&hewt[(long)n * 512 + lane * 8];
        float4 e0 = *(const float4*)&o_b[lane * 8];
        float4 e1 = *(const float4*)&o_b[lane * 8 + 4];
        s = bf2f((ushort_t)wv[0]) * e0.x + bf2f((ushort_t)wv[1]) * e0.y +
            bf2f((ushort_t)wv[2]) * e0.z + bf2f((ushort_t)wv[3]) * e0.w +
            bf2f((ushort_t)wv[4]) * e1.x + bf2f((ushort_t)wv[5]) * e1.y +
            bf2f((ushort_t)wv[6]) * e1.z + bf2f((ushort_t)wv[7]) * e1.w;
#pragma unroll
        for (int o = 32; o >= 1; o >>= 1) s += __shfl_xor(s, o);
        if (lane == 0) bias_eo[n] = s + he_b[n];
    } else if (wid < 4096) {
        int t = wid - 2560;
        int c = t >> 9, k = t & 511;
#pragma unroll
        for (int i = 0; i < 8; ++i) {
            int j = i * 64 + lane;
            s = fmaf(o_w[(long)k * 512 + j], hp_w[j * 3 + c], s);
        }
#pragma unroll
        for (int o = 32; o >= 1; o >>= 1) s += __shfl_xor(s, o);
        if (lane == 0) whp[k * 3 + c] = s;
    } else if (wid < 4099) {
        int c = wid - 4096;
#pragma unroll
        for (int i = 0; i < 8; ++i) {
            int j = i * 64 + lane;
            s = fmaf(o_b[j], hp_w[j * 3 + c], s);
        }
#pragma unroll
        for (int o = 32; o >= 1; o >>= 1) s += __shfl_xor(s, o);
        if (lane == 0) bias_po[c] = s + hp_b[c];
    }
}

// ---------------------------------------------------------------------------
// bf16 MFMA GEMM — unchanged (global_load_lds, swizzled source).
// ---------------------------------------------------------------------------
template <int RELU, int OUT_BF16, int HASBIAS, int BBSTRIDE>
__global__ __launch_bounds__(512) void hgemm(
    const ushort_t* __restrict__ A, int lda,
    const ushort_t* __restrict__ Wt, int ldw,
    const float* __restrict__ bias,
    void* __restrict__ Cv, int ldc,
    int N, int K)
{
    __shared__ __align__(16) ushort_t As[128 * 64];
    __shared__ __align__(16) ushort_t Bs[128 * 64];

    const int tid = threadIdx.x;
    const int lane = tid & 63, w = tid >> 6;
    const int lo = lane & 15, hi = lane >> 4;
    const int wm = w >> 2, wn = w & 3;
    const long m0 = (long)blockIdx.y * 128;
    const int n0 = blockIdx.x * 128;

    f32x4 acc[4][2];
#pragma unroll
    for (int mt = 0; mt < 4; ++mt)
#pragma unroll
        for (int nt = 0; nt < 2; ++nt) acc[mt][nt] = (f32x4)0.f;

    for (int kt = 0; kt < K; kt += 64) {
#pragma unroll
        for (int i = 0; i < 2; ++i) {
            int c = w * 128 + i * 64 + lane;
            int r = c >> 3, ch = c & 7;
            int sch = ch ^ (r & 7);
            gload16(&A[(m0 + r) * (long)lda + kt + sch * 8],
                    &As[(w * 128 + i * 64) * 8]);
            gload16(&Wt[(long)(n0 + r) * ldw + kt + sch * 8],
                    &Bs[(w * 128 + i * 64) * 8]);
        }
        __syncthreads();

#pragma unroll
        for (int ks = 0; ks < 2; ++ks) {
            bf16x8 af[4], bfr[2];
#pragma unroll
            for (int mt = 0; mt < 4; ++mt) {
                int m = wm * 64 + mt * 16 + lo;
                af[mt] = *(const bf16x8*)&As[m * 64 + (((ks * 4 + hi) ^ (lo & 7)) * 8)];
            }
#pragma unroll
            for (int nt = 0; nt < 2; ++nt) {
                int n = wn * 32 + nt * 16 + lo;
                bfr[nt] = *(const bf16x8*)&Bs[n * 64 + (((ks * 4 + hi) ^ (lo & 7)) * 8)];
            }
#pragma unroll
            for (int mt = 0; mt < 4; ++mt)
#pragma unroll
                for (int nt = 0; nt < 2; ++nt)
                    acc[mt][nt] = __builtin_amdgcn_mfma_f32_16x16x32_bf16(
                        af[mt], bfr[nt], acc[mt][nt], 0, 0, 0);
        }
        __syncthreads();
    }

#pragma unroll
    for (int mt = 0; mt < 4; ++mt)
#pragma unroll
        for (int nt = 0; nt < 2; ++nt) {
            int col = n0 + wn * 32 + nt * 16 + lo;
            if (col < N) {
                float bv = 0.f;
                if (HASBIAS)
                    bv = BBSTRIDE ? bias[(int)(m0 >> 11) * BBSTRIDE + col] : bias[col];
#pragma unroll
                for (int r = 0; r < 4; ++r) {
                    long row = m0 + wm * 64 + mt * 16 + hi * 4 + r;
                    float v = acc[mt][nt][r] + bv;
                    if (RELU) v = fmaxf(v, 0.f);
                    if (OUT_BF16) ((ushort_t*)Cv)[row * (long)ldc + col] = f2bf(v);
                    else          ((float*)Cv)[row * (long)ldc + col] = v;
                }
            }
        }
}

// ---------------------------------------------------------------------------
// Position MLP -> a192[:, 64:192] (bf16).
// Parallelized: grid 256 x 256 threads; 32 rows/block, 8 threads/row, each
// thread computes 16 outputs o = chunk + 8j. w2t stored [128][72] so the 8
// per-wave chunk addresses land 8 banks apart (2-way aliasing = free, m136).
// ---------------------------------------------------------------------------
__global__ __launch_bounds__(256) void posmlp_kernel(
    const float* __restrict__ pos,
    const float* __restrict__ w1, const float* __restrict__ b1,
    const float* __restrict__ w2, const float* __restrict__ b2,
    ushort_t* __restrict__ a192)
{
    __shared__ __align__(16) float w1s[256];
    __shared__ __align__(16) float b1s[64];
    __shared__ __align__(16) float w2t[128 * 72];
    __shared__ __align__(16) float b2s[128];

    const int tid = threadIdx.x;
    w1s[tid] = w1[tid];
    if (tid < 64) b1s[tid] = b1[tid];
    if (tid < 128) b2s[tid] = b2[tid];
    for (int i = tid; i < 8192; i += 256) {
        int k = i >> 7, o = i & 127;
        w2t[o * 72 + k] = w2[i];
    }
    __syncthreads();

    const long r = (long)blockIdx.x * 32 + (tid >> 3);
    const int chunk = tid & 7;
    float px = pos[r * 3 + 0], py = pos[r * 3 + 1], pz = pos[r * 3 + 2];
    float nrm = sqrtf(px * px + py * py + pz * pz);
    float inv = 1.f / (nrm + 1e-7f);
    float pf0 = px * inv, pf1 = py * inv, pf2 = pz * inv, pf3 = nrm;

    float h1[64];
#pragma unroll
    for (int o = 0; o < 64; ++o) {
        float a = b1s[o];
        a = fmaf(pf0, w1s[o], a);
        a = fmaf(pf1, w1s[64 + o], a);
        a = fmaf(pf2, w1s[128 + o], a);
        a = fmaf(pf3, w1s[192 + o], a);
        h1[o] = fmaxf(a, 0.f);
    }
    ushort_t* dst = &a192[r * 192 + 64];
#pragma unroll
    for (int j = 0; j < 16; ++j) {
        int o = chunk + 8 * j;
        float s = b2s[o];
#pragma unroll
        for (int i4 = 0; i4 < 16; ++i4) {
            float4 wv = *(const float4*)&w2t[o * 72 + i4 * 4];
            s = fmaf(h1[i4 * 4 + 0], wv.x, s);
            s = fmaf(h1[i4 * 4 + 1], wv.y, s);
            s = fmaf(h1[i4 * 4 + 2], wv.z, s);
            s = fmaf(h1[i4 * 4 + 3], wv.w, s);
        }
        dst[o] = f2bf(s);
    }
}

// tdt = diffusion_time @ yy_w + yy_b (fp32, exact)
__global__ __launch_bounds__(512) void tdt_kernel(
    const float* __restrict__ dt, const float* __restrict__ yyw,
    const float* __restrict__ yyb, float* __restrict__ tdt_ws,
    float* __restrict__ out_tail)
{
    const int t = threadIdx.x;
    const int b = t >> 7, o = t & 127;
    float s = yyb[o];
    for (int k = 0; k < 128; ++k) s = fmaf(dt[b * 128 + k], yyw[k * 128 + o], s);
    tdt_ws[t] = s;
    out_tail[t] = s;
}

// ---------------------------------------------------------------------------
// qkv postprocess: K rmsnorm + V transpose — unchanged.
// ---------------------------------------------------------------------------
__global__ __launch_bounds__(256) void qkvpost_kernel(
    const ushort_t* __restrict__ qkv, const float* __restrict__ knw,
    ushort_t* __restrict__ kn, ushort_t* __restrict__ Vt)
{
    __shared__ ushort_t t[64][72];
    __shared__ float knw_s[64];
    const int bh = blockIdx.x, b = bh >> 3, h = bh & 7;
    const int n0 = blockIdx.y * 64;
    const int tid = threadIdx.x;
    if (tid < 64) knw_s[tid] = knw[tid];
#pragma unroll
    for (int i = 0; i < 2; ++i) {
        int c = tid + i * 256;
        int r = c >> 3, ch = c & 7;
        *(bf16x8*)&t[r][ch * 8] =
            *(const bf16x8*)&qkv[(long)(b * SEQ + n0 + r) * 1544 + 1032 + h * 64 + ch * 8];
    }
    __syncthreads();
#pragma unroll
    for (int i = 0; i < 2; ++i) {
        int c = tid + i * 256;
        int r = c >> 3, ch = c & 7;
        bf16x8 kv = *(const bf16x8*)&qkv[(long)(b * SEQ + n0 + r) * 1544 + 520 + h * 64 + ch * 8];
        float x[8], ss = 0.f;
#pragma unroll
        for (int j = 0; j < 8; ++j) { x[j] = bf2f((ushort_t)kv[j]); ss = fmaf(x[j], x[j], ss); }
        ss += __shfl_xor(ss, 1);
        ss += __shfl_xor(ss, 2);
        ss += __shfl_xor(ss, 4);
        float invr = rsqrtf(ss * (1.f / 64.f) + 1e-6f);
        bf16x8 o;
#pragma unroll
        for (int j = 0; j < 8; ++j) o[j] = (short)f2bf(x[j] * knw_s[ch * 8 + j] * invr);
        *(bf16x8*)&kn[(long)(b * SEQ + n0 + r) * 512 + h * 64 + ch * 8] = o;
    }
    const int d = tid >> 2;
#pragma unroll
    for (int i = 0; i < 2; ++i) {
        int cc = (tid & 3) * 2 + i;
        bf16x8 pk;
#pragma unroll
        for (int j = 0; j < 8; ++j) pk[j] = (short)t[cc * 8 + j][d];
        *(bf16x8*)&Vt[((long)(bh * 64 + d)) * SEQ + n0 + cc * 8] = pk;
    }
}

// ---------------------------------------------------------------------------
// Flash attention, bf16 MFMA 16x16x32 — unchanged (double-buffered, 1 barrier
// per K-tile, inline Q rmsnorm, exp2-domain softmax, packed P writes).
// ---------------------------------------------------------------------------
__global__ __launch_bounds__(256) void flash_attn_mfma(
    const ushort_t* __restrict__ QKV, const ushort_t* __restrict__ Kn,
    const ushort_t* __restrict__ Vt, const float* __restrict__ qnw,
    ushort_t* __restrict__ AO)
{
    __shared__ __align__(16) ushort_t Ks[2][64 * 64];
    __shared__ __align__(16) ushort_t Vs[2][64 * 64];
    __shared__ __align__(16) ushort_t Ps[4][32 * 64];

    const int tid = threadIdx.x;
    const int lane = tid & 63;
    const int w = tid >> 6;
    const int lo = lane & 15, hi = lane >> 4;
    const int bh = blockIdx.x, b = bh >> 3, h = bh & 7;
    const int qb = blockIdx.y * 128 + w * 32;

    bf16x8 qfrag[2][2];
    {
        float qw[2][8];
#pragma unroll
        for (int ks = 0; ks < 2; ++ks)
#pragma unroll
            for (int j = 0; j < 8; ++j)
                qw[ks][j] = qnw[ks * 32 + hi * 8 + j];
#pragma unroll
        for (int jt = 0; jt < 2; ++jt) {
            float qx[2][8], ss = 0.f;
#pragma unroll
            for (int ks = 0; ks < 2; ++ks) {
                bf16x8 q = *(const bf16x8*)&QKV[(long)(b * SEQ + qb + jt * 16 + lo) * 1544 +
                                                h * 64 + ks * 32 + hi * 8];
#pragma unroll
                for (int j = 0; j < 8; ++j) {
                    qx[ks][j] = bf2f((ushort_t)q[j]);
                    ss = fmaf(qx[ks][j], qx[ks][j], ss);
                }
            }
            ss += __shfl_xor(ss, 16);
            ss += __shfl_xor(ss, 32);
            float invr = rsqrtf(ss * (1.f / 64.f) + 1e-6f) * (0.125f * LOG2E);
#pragma unroll
            for (int ks = 0; ks < 2; ++ks) {
                bf16x8 f;
#pragma unroll
                for (int j = 0; j < 8; ++j)
                    f[j] = (short)f2bf(qx[ks][j] * qw[ks][j] * invr);
                qfrag[jt][ks] = f;
            }
        }
    }

    f32x4 accO[2][4];
#pragma unroll
    for (int mt = 0; mt < 2; ++mt)
#pragma unroll
        for (int nt = 0; nt < 4; ++nt) accO[mt][nt] = (f32x4)0.f;
    float l_part[2] = {0.f, 0.f};

    const int sr0 = tid >> 3, sc0 = tid & 7;
    const int sr1 = (tid + 256) >> 3, sc1 = tid & 7;
    const int wo0 = sr0 * 64 + ((sc0 ^ (sr0 & 7)) * 8);
    const int wo1 = sr1 * 64 + ((sc1 ^ (sr1 & 7)) * 8);

    bf16x8 kreg0, kreg1, vreg0, vreg1;
    kreg0 = *(const bf16x8*)&Kn[(b * SEQ + sr0) * 512 + h * 64 + sc0 * 8];
    vreg0 = *(const bf16x8*)&Vt[((long)(bh * 64 + sr0)) * SEQ + sc0 * 8];
    kreg1 = *(const bf16x8*)&Kn[(b * SEQ + sr1) * 512 + h * 64 + sc1 * 8];
    vreg1 = *(const bf16x8*)&Vt[((long)(bh * 64 + sr1)) * SEQ + sc1 * 8];
    *(bf16x8*)&Ks[0][wo0] = kreg0;
    *(bf16x8*)&Vs[0][wo0] = vreg0;
    *(bf16x8*)&Ks[0][wo1] = kreg1;
    *(bf16x8*)&Vs[0][wo1] = vreg1;
    kreg0 = *(const bf16x8*)&Kn[(b * SEQ + 64 + sr0) * 512 + h * 64 + sc0 * 8];
    vreg0 = *(const bf16x8*)&Vt[((long)(bh * 64 + sr0)) * SEQ + 64 + sc0 * 8];
    kreg1 = *(const bf16x8*)&Kn[(b * SEQ + 64 + sr1) * 512 + h * 64 + sc1 * 8];
    vreg1 = *(const bf16x8*)&Vt[((long)(bh * 64 + sr1)) * SEQ + 64 + sc1 * 8];
    __syncthreads();

    auto step = [&](int kt, int cur, int nxt) {
        if (kt + 1 < 32) {
            *(bf16x8*)&Ks[nxt][wo0] = kreg0;
            *(bf16x8*)&Vs[nxt][wo0] = vreg0;
            *(bf16x8*)&Ks[nxt][wo1] = kreg1;
            *(bf16x8*)&Vs[nxt][wo1] = vreg1;
        }
        if (kt + 2 < 32) {
            int nk = (kt + 2) * 64;
            kreg0 = *(const bf16x8*)&Kn[(b * SEQ + nk + sr0) * 512 + h * 64 + sc0 * 8];
            vreg0 = *(const bf16x8*)&Vt[((long)(bh * 64 + sr0)) * SEQ + nk + sc0 * 8];
            kreg1 = *(const bf16x8*)&Kn[(b * SEQ + nk + sr1) * 512 + h * 64 + sc1 * 8];
            vreg1 = *(const bf16x8*)&Vt[((long)(bh * 64 + sr1)) * SEQ + nk + sc1 * 8];
        }

        f32x4 accS[4][2];
#pragma unroll
        for (int it = 0; it < 4; ++it)
#pragma unroll
            for (int jt = 0; jt < 2; ++jt) accS[it][jt] = (f32x4)0.f;

#pragma unroll
        for (int it = 0; it < 4; ++it) {
            bf16x8 kf[2];
#pragma unroll
            for (int ks = 0; ks < 2; ++ks)
                kf[ks] = *(const bf16x8*)&Ks[cur][(it * 16 + lo) * 64 +
                                                 (((ks * 4 + hi) ^ (lo & 7)) * 8)];
#pragma unroll
            for (int jt = 0; jt < 2; ++jt)
#pragma unroll
                for (int ks = 0; ks < 2; ++ks)
                    accS[it][jt] = __builtin_amdgcn_mfma_f32_16x16x32_bf16(
                        kf[ks], qfrag[jt][ks], accS[it][jt], 0, 0, 0);
        }

#pragma unroll
        for (int it = 0; it < 4; ++it)
#pragma unroll
            for (int jt = 0; jt < 2; ++jt) {
                float p0, p1, p2, p3;
                asm("v_exp_f32 %0, %1" : "=v"(p0) : "v"(accS[it][jt][0]));
                asm("v_exp_f32 %0, %1" : "=v"(p1) : "v"(accS[it][jt][1]));
                asm("v_exp_f32 %0, %1" : "=v"(p2) : "v"(accS[it][jt][2]));
                asm("v_exp_f32 %0, %1" : "=v"(p3) : "v"(accS[it][jt][3]));
                l_part[jt] += (p0 + p1) + (p2 + p3);
                unsigned w0, w1;
                asm("v_cvt_pk_bf16_f32 %0, %1, %2" : "=v"(w0) : "v"(p0), "v"(p1));
                asm("v_cvt_pk_bf16_f32 %0, %1, %2" : "=v"(w1) : "v"(p2), "v"(p3));
                int q = jt * 16 + lo;
                int cch = it * 2 + (hi >> 1);
                int off = q * 64 + ((cch ^ (q & 7)) * 8) + (hi & 1) * 4;
                uint2 t; t.x = w0; t.y = w1;
                *(uint2*)&Ps[w][off] = t;
            }

#pragma unroll
        for (int kk = 0; kk < 2; ++kk) {
            bf16x8 pf[2];
#pragma unroll
            for (int mt = 0; mt < 2; ++mt)
                pf[mt] = *(const bf16x8*)&Ps[w][(mt * 16 + lo) * 64 +
                                               (((kk * 4 + hi) ^ (lo & 7)) * 8)];
#pragma unroll
            for (int nt = 0; nt < 4; ++nt) {
                bf16x8 vf = *(const bf16x8*)&Vs[cur][(nt * 16 + lo) * 64 +
                                                    (((kk * 4 + hi) ^ (lo & 7)) * 8)];
#pragma unroll
                for (int mt = 0; mt < 2; ++mt)
                    accO[mt][nt] = __builtin_amdgcn_mfma_f32_16x16x32_bf16(
                        pf[mt], vf, accO[mt][nt], 0, 0, 0);
            }
        }
        __syncthreads();
    };

    for (int kt = 0; kt < 32; kt += 2) {
        step(kt, 0, 1);
        step(kt + 1, 1, 0);
    }

#pragma unroll
    for (int jt = 0; jt < 2; ++jt) {
        l_part[jt] += __shfl_xor(l_part[jt], 16);
        l_part[jt] += __shfl_xor(l_part[jt], 32);
    }

#pragma unroll
    for (int mt = 0; mt < 2; ++mt)
#pragma unroll
        for (int r = 0; r < 4; ++r) {
            float lq = __shfl(l_part[mt], hi * 4 + r);
            int grow = b * SEQ + qb + mt * 16 + hi * 4 + r;
            float g = bf2f(QKV[(long)grow * 1544 + 512 + h]);
            g = 1.f / (1.f + __expf(-g));
            float sc = g / lq;
#pragma unroll
            for (int nt = 0; nt < 4; ++nt)
                AO[(long)grow * 512 + h * 64 + nt * 16 + lo] = f2bf(accO[mt][nt][r] * sc);
        }
}

// pos_out = ao @ whp + bias_po (bf16 in, fp32 fold weights)
__global__ __launch_bounds__(256) void posout_kernel(
    const ushort_t* __restrict__ ao, const float* __restrict__ whp,
    const float* __restrict__ bpo, float* __restrict__ po)
{
    const int lane = threadIdx.x & 63;
    const long row = (long)blockIdx.x * 4 + (threadIdx.x >> 6);
    float p0 = 0.f, p1 = 0.f, p2 = 0.f;
#pragma unroll
    for (int it = 0; it < 8; ++it) {
        int k = it * 64 + lane;
        float x = bf2f(ao[row * 512 + k]);
        p0 = fmaf(x, whp[k * 3 + 0], p0);
        p1 = fmaf(x, whp[k * 3 + 1], p1);
        p2 = fmaf(x, whp[k * 3 + 2], p2);
    }
#pragma unroll
    for (int o = 32; o >= 1; o >>= 1) {
        p0 += __shfl_xor(p0, o);
        p1 += __shfl_xor(p1, o);
        p2 += __shfl_xor(p2, o);
    }
    if (lane == 0) {
        po[row * 3 + 0] = p0 + bpo[0];
        po[row * 3 + 1] = p1 + bpo[1];
        po[row * 3 + 2] = p2 + bpo[2];
    }
}

// ---------------------------------------------------------------------------
extern "C" void kernel_launch(void* const* d_in, const int* in_sizes, int n_in,
                              void* d_out, int out_size, void* d_ws, size_t ws_size,
                              hipStream_t stream)
{
    const float* expr    = (const float*)d_in[0];
    const float* dtime   = (const float*)d_in[1];
    const float* posf    = (const float*)d_in[2];
    const float* pos_w1  = (const float*)d_in[3];
    const float* pos_b1  = (const float*)d_in[4];
    const float* pos_w2  = (const float*)d_in[5];
    const float* pos_b2  = (const float*)d_in[6];
    const float* expr_w1 = (const float*)d_in[7];
    const float* expr_b1 = (const float*)d_in[8];
    const float* expr_w2 = (const float*)d_in[9];
    const float* expr_b2 = (const float*)d_in[10];
    const float* yy_w    = (const float*)d_in[11];
    const float* yy_b    = (const float*)d_in[12];
    const float* cat_w   = (const float*)d_in[13];
    const float* cat_b   = (const float*)d_in[14];
    const float* q_w     = (const float*)d_in[15];
    const float* q_b     = (const float*)d_in[16];
    const float* k_w     = (const float*)d_in[17];
    const float* k_b     = (const float*)d_in[18];
    const float* v_w     = (const float*)d_in[19];
    const float* v_b     = (const float*)d_in[20];
    const float* o_w     = (const float*)d_in[21];
    const float* o_b     = (const float*)d_in[22];
    const float* qn_w    = (const float*)d_in[23];
    const float* kn_w    = (const float*)d_in[24];
    const float* hp_w    = (const float*)d_in[25];
    const float* hp_b    = (const float*)d_in[26];
    const float* he_w    = (const float*)d_in[27];
    const float* he_b    = (const float*)d_in[28];
    (void)in_sizes; (void)n_in; (void)out_size; (void)ws_size;

    ushort_t* wsb     = (ushort_t*)d_ws;
    ushort_t* expr_bf = wsb + U_EXPR;
    ushort_t* a192    = wsb + U_A192;
    ushort_t* h_bf    = wsb + U_H;
    ushort_t* qkv_bf  = wsb + U_QKV;
    ushort_t* kn_bf   = wsb + U_KN;
    ushort_t* vt_bf   = wsb + U_VT;
    ushort_t* ao_bf   = wsb + U_AO;
    ushort_t* w1t     = wsb + U_W1T;
    ushort_t* w2raw   = wsb + U_W2RAW;
    ushort_t* cat_wt  = wsb + U_CATWT;
    ushort_t* qkv_wt  = wsb + U_QKVWT;
    ushort_t* he_wt   = wsb + U_HEWT;
    ushort_t* wprime  = wsb + U_WPRIME;
    ushort_t* wohe    = wsb + U_WOHE;
    ushort_t* o_raw   = wsb + U_ORAW;
    float* f32r       = (float*)(wsb + U_F32);
    float* tdt        = f32r + F_TDT;
    float* qkv_bias   = f32r + F_QKVB;
    float* bias_h     = f32r + F_BIASH;
    float* bias_eo    = f32r + F_BIASEO;
    float* bias_po    = f32r + F_BIASPO;
    float* whp        = f32r + F_WHP;
    float* dout       = (float*)d_out;

    const dim3 blk(256);
    const dim3 blk512(512);

    // --- prep: all converts/transposes in ONE kernel ---
    WtTable tab;
    //            src              dst               K    N   tK tile0 dstS mode
    tab.s[0] = { expr_w1,          w1t,             512,  64,  8,   0, 512, 0 };  //   8
    tab.s[1] = { cat_w,            cat_wt,          768, 512, 12,   8, 768, 0 };  //  96
    tab.s[2] = { q_w,              qkv_wt,          512, 520,  8, 104, 512, 0 };  //  72
    tab.s[3] = { k_w,              qkv_wt + 520*512,512, 512,  8, 176, 512, 0 };  //  64
    tab.s[4] = { v_w,              qkv_wt +1032*512,512, 512,  8, 240, 512, 0 };  //  64
    tab.s[5] = { he_w,             he_wt,           512, 512,  8, 304, 512, 0 };  //  64
    tab.s[6] = { cat_w + 640*512,  wprime + 64,     128, 512,  2, 368, 192, 0 };  //  16
    tab.s[7] = { expr_w2,          w2raw,             0,   0,  0, 384,   0, 1 };  //   2
    tab.s[8] = { o_w,              o_raw,             0,   0,  0, 386,   0, 1 };  //  16
    tab.s[9] = { expr,             expr_bf,           0,   0,  0, 402,   0, 1 };  // 256 -> 658
    wt_transpose<<<dim3(665), blk, 0, stream>>>(tab, q_b, k_b, v_b, qkv_bias);

    tdt_kernel<<<dim3(1), dim3(512), 0, stream>>>(dtime, yy_w, yy_b, tdt,
                                                  dout + DOUT_TDT);
    biasfold_kernel<<<dim3(1025), blk, 0, stream>>>(
        cat_wt, he_wt, expr_b2, tdt, cat_b, o_b, he_b, o_w, hp_w, hp_b,
        bias_h, bias_eo, whp, bias_po);
    // W'[:, :64] = (expr_w2 @ cat_w0)^T rows
    hgemm<0, 1, 0, 0><<<dim3(1, 4), blk512, 0, stream>>>(cat_wt, 768, w2raw, 512,
                                                         nullptr, wprime, 192, 64, 512);
    // wohe[n][k] = sum_i he_w[i][n] * o_w[k][i]  (B-operand = NATIVE o_w)
    hgemm<0, 1, 0, 0><<<dim3(4, 4), blk512, 0, stream>>>(he_wt, 512, o_raw, 512,
                                                         nullptr, wohe, 512, 512, 512);

    // --- pipeline ---
    hgemm<1, 1, 1, 0><<<dim3(1, 64), blk512, 0, stream>>>(expr_bf, 512, w1t, 512,
                                                          expr_b1, a192, 192, 64, 512);
    posmlp_kernel<<<dim3(256), blk, 0, stream>>>(posf, pos_w1, pos_b1,
                                                 pos_w2, pos_b2, a192);
    hgemm<0, 1, 1, 512><<<dim3(4, 64), blk512, 0, stream>>>(a192, 192, wprime, 192,
                                                            bias_h, h_bf, 512, 512, 192);
    hgemm<0, 1, 1, 0><<<dim3(13, 64), blk512, 0, stream>>>(h_bf, 512, qkv_wt, 512,
                                                           qkv_bias, qkv_bf, 1544, 1544, 512);
    qkvpost_kernel<<<dim3(32, 32), blk, 0, stream>>>(qkv_bf, kn_w, kn_bf, vt_bf);
    flash_attn_mfma<<<dim3(32, 16), blk, 0, stream>>>(qkv_bf, kn_bf, vt_bf, qn_w, ao_bf);
    hgemm<0, 0, 1, 0><<<dim3(4, 64), blk512, 0, stream>>>(ao_bf, 512, wohe, 512,
                                                          bias_eo, dout + DOUT_EXPR,
                                                          512, 512, 512);
    posout_kernel<<<dim3(2048), blk, 0, stream>>>(ao_bf, whp, bias_po,
                                                  dout + DOUT_POS);
}